// Round 5
// baseline (561.645 us; speedup 1.0000x reference)
//
#include <hip/hip_runtime.h>
#include <cstdint>

typedef __bf16 bf16_t;
typedef bf16_t bf16x8 __attribute__((ext_vector_type(8)));
typedef bf16_t bf16x4 __attribute__((ext_vector_type(4)));
typedef float  f32x4  __attribute__((ext_vector_type(4)));

#define DEVI static __device__ __forceinline__

DEVI void async_ld16(const bf16_t* g, bf16_t* l) {
  __builtin_amdgcn_global_load_lds((const __attribute__((address_space(1))) void*)g,
                                   (__attribute__((address_space(3))) void*)l, 16, 0, 0);
}

// ---------------------------------------------------------------------------
// Fused prep: all weight transposes + bf16 converts + bias packs, one dispatch.
// ---------------------------------------------------------------------------
struct PrepArgs {
  const float *WqS, *WkS, *WvS, *WqX, *WkX, *WvX, *Wo, *W1, *W2, *x, *enc;
  const float *bqS, *bkS, *bvS, *bkX, *bvX;
  bf16_t *WqkvST, *WqXT, *WkvXT, *WoT, *W1T, *W2T, *xb, *encb;
  float *bqkv, *bkvx;
};

__global__ __launch_bounds__(256)
void k_prep(PrepArgs a)
{
  __shared__ float tile[32][33];
  const int blk = blockIdx.x, tid = threadIdx.x;
  const int tx = tid & 31, ty = tid >> 5;

  const float* src = nullptr;
  bf16_t* dst = nullptr;
  int srcLd = 0, dstLd = 0, m0 = 0, n0 = 0;
  bool do_tr = false;

  if (blk < 6144) {
    int j = blk >> 10, q = blk & 1023;
    src = j == 0 ? a.WqS : j == 1 ? a.WkS : j == 2 ? a.WvS : j == 3 ? a.WqX : j == 4 ? a.WkX : a.WvX;
    dst = j == 0 ? a.WqkvST : j == 1 ? a.WqkvST + 1048576 : j == 2 ? a.WqkvST + 2097152
        : j == 3 ? a.WqXT : j == 4 ? a.WkvXT : a.WkvXT + 1048576;
    int batch = q >> 6, rem = q & 63;
    src += (long)batch * 65536; dst += (long)batch * 65536;
    srcLd = 64; dstLd = 1024;
    n0 = (rem & 1) * 32; m0 = (rem >> 1) * 32;
    do_tr = true;
  } else if (blk < 7168) {
    int q = blk - 6144;
    src = a.Wo; dst = a.WoT; srcLd = 1024; dstLd = 1024;
    m0 = (q >> 5) * 32; n0 = (q & 31) * 32; do_tr = true;
  } else if (blk < 11264) {
    int q = blk - 7168;
    src = a.W1; dst = a.W1T; srcLd = 4096; dstLd = 1024;
    m0 = (q >> 7) * 32; n0 = (q & 127) * 32; do_tr = true;
  } else if (blk < 15360) {
    int q = blk - 11264;
    src = a.W2; dst = a.W2T; srcLd = 1024; dstLd = 4096;
    m0 = (q >> 5) * 32; n0 = (q & 31) * 32; do_tr = true;
  } else if (blk < 16384) {
    long base = (long)(blk - 15360) * 4096 + tid * 4;
#pragma unroll
    for (int u = 0; u < 4; u++) {
      float4 v = *(const float4*)(a.x + base + u * 1024);
      bf16x4 o; o[0] = (bf16_t)v.x; o[1] = (bf16_t)v.y; o[2] = (bf16_t)v.z; o[3] = (bf16_t)v.w;
      *(bf16x4*)(a.xb + base + u * 1024) = o;
    }
    return;
  } else if (blk < 17408) {
    long base = (long)(blk - 16384) * 4096 + tid * 4;
#pragma unroll
    for (int u = 0; u < 4; u++) {
      float4 v = *(const float4*)(a.enc + base + u * 1024);
      bf16x4 o; o[0] = (bf16_t)v.x; o[1] = (bf16_t)v.y; o[2] = (bf16_t)v.z; o[3] = (bf16_t)v.w;
      *(bf16x4*)(a.encb + base + u * 1024) = o;
    }
    return;
  } else {
    int gi = (blk - 17408) * 1024 + tid * 4;
#pragma unroll
    for (int j = 0; j < 4; j++) {
      int i = gi + j;
      if (i < 1024)      a.bqkv[i] = a.bqS[i];
      else if (i < 2048) a.bqkv[i] = a.bkS[i - 1024];
      else if (i < 3072) a.bqkv[i] = a.bvS[i - 2048];
      else if (i < 4096) a.bkvx[i - 3072] = a.bkX[i - 3072];
      else if (i < 5120) a.bkvx[i - 3072] = a.bvX[i - 4096];
    }
    return;
  }

  if (do_tr) {
#pragma unroll
    for (int i = 0; i < 4; i++)
      tile[ty + i * 8][tx] = src[(long)(m0 + ty + i * 8) * srcLd + n0 + tx];
    __syncthreads();
#pragma unroll
    for (int i = 0; i < 4; i++)
      dst[(long)(n0 + ty + i * 8) * dstLd + m0 + tx] = (bf16_t)tile[tx][ty + i * 8];
  }
}

// ---------------------------------------------------------------------------
// GEMM 128x128 tile, BK=32, 2-phase double-buffered global_load_lds.
// (Known-good core — do not re-pipeline (m131-m141); do not shrink tile
//  (64^2 measured 126us vs 77us). At 2-3 blk/CU the cross-block wave overlap
//  already hides the barrier drain (m139 null at 128^2) — leave as is.)
// ---------------------------------------------------------------------------
template<int OUT_MODE, int RELU, int VOFF>
__global__ __launch_bounds__(256, 2)
void k_gemm(const bf16_t* __restrict__ A, int lda,
            const bf16_t* __restrict__ Bt, int ldb,
            const float* __restrict__ bias,
            bf16_t* __restrict__ C, int ldc,
            bf16_t* __restrict__ Vt,
            bf16_t* __restrict__ p0, bf16_t* __restrict__ p1,
            bf16_t* __restrict__ p2, bf16_t* __restrict__ p3,
            int Ktot, int nx)
{
  __shared__ bf16_t As[2][128 * 32];
  __shared__ bf16_t Bs[2][128 * 32];
  const int tid  = threadIdx.x;
  const int wave = tid >> 6, lane = tid & 63;
  const int quad = lane >> 4, m16 = lane & 15;

  int lin = blockIdx.x;
  int perx = gridDim.x >> 3;
  int t = (lin & 7) * perx + (lin >> 3);
  const int bcol = (t % nx) * 128, brow = (t / nx) * 128;
  const int wr = (wave >> 1) * 64, wc = (wave & 1) * 64;

  const int Kper = Ktot / gridDim.z;
  const int k0 = blockIdx.z * Kper;

  f32x4 acc[4][4];
#pragma unroll
  for (int i = 0; i < 4; i++)
#pragma unroll
    for (int j = 0; j < 4; j++) acc[i][j] = (f32x4){0.f, 0.f, 0.f, 0.f};

  auto stage = [&](int kt, int buf) {
#pragma unroll
    for (int i = 0; i < 2; i++) {
      int rg = wave * 2 + i;
      async_ld16(A  + (long)(brow + rg * 16 + m16) * lda + kt + quad * 8, As[buf] + rg * 512);
      async_ld16(Bt + (long)(bcol + rg * 16 + m16) * ldb + kt + quad * 8, Bs[buf] + rg * 512);
    }
  };

  stage(k0, 0);
  __syncthreads();

  const int nIter = Kper >> 5;
  for (int it = 0; it < nIter; it++) {
    const int cur = it & 1;
    if (it + 1 < nIter) stage(k0 + (it + 1) * 32, cur ^ 1);

    bf16x8 af[4], bfr[4];
#pragma unroll
    for (int tt = 0; tt < 4; tt++) {
      af[tt]  = *(const bf16x8*)(As[cur] + ((wr + tt * 16) >> 4) * 512 + quad * 128 + m16 * 8);
      bfr[tt] = *(const bf16x8*)(Bs[cur] + ((wc + tt * 16) >> 4) * 512 + quad * 128 + m16 * 8);
    }
#pragma unroll
    for (int i = 0; i < 4; i++)
#pragma unroll
      for (int j = 0; j < 4; j++)
        acc[i][j] = __builtin_amdgcn_mfma_f32_16x16x32_bf16(af[i], bfr[j], acc[i][j], 0, 0, 0);

    __syncthreads();
  }

  if (OUT_MODE == 1) {
    bf16_t* P = blockIdx.z == 0 ? p0 : blockIdx.z == 1 ? p1 : blockIdx.z == 2 ? p2 : p3;
#pragma unroll
    for (int i = 0; i < 4; i++)
#pragma unroll
      for (int j = 0; j < 4; j++) {
        int col = bcol + wc + j * 16 + m16;
#pragma unroll
        for (int r = 0; r < 4; r++) {
          int row = brow + wr + i * 16 + quad * 4 + r;
          P[(long)row * ldc + col] = (bf16_t)acc[i][j][r];
        }
      }
  } else {
#pragma unroll
    for (int i = 0; i < 4; i++)
#pragma unroll
      for (int j = 0; j < 4; j++) {
        int col = bcol + wc + j * 16 + m16;
        float bv = bias[col];
        if (VOFF && col >= VOFF) {
          int hh = (col - VOFF) >> 6, dd = col & 63;
          int row0 = brow + wr + i * 16 + quad * 4;
          int bb = row0 >> 10, seq = row0 & 1023;
          bf16x4 pk;
#pragma unroll
          for (int r = 0; r < 4; r++) pk[r] = (bf16_t)(acc[i][j][r] + bv);
          *(bf16x4*)(Vt + (long)(bb * 16 + hh) * 65536 + dd * 1024 + seq) = pk;
        } else {
#pragma unroll
          for (int r = 0; r < 4; r++) {
            int row = brow + wr + i * 16 + quad * 4 + r;
            float v = acc[i][j][r] + bv;
            if (RELU) v = v > 0.f ? v : 0.f;
            C[(long)row * ldc + col] = (bf16_t)v;
          }
        }
      }
  }
}

// ---------------------------------------------------------------------------
// GEMM 256x256 tile, BK=32, TRIPLE-buffered LDS + COUNTED vmcnt (T4):
// at 1 blk/CU all 8 waves hit the same barrier, so __syncthreads()' implicit
// vmcnt(0) drained the whole prefetch queue each K-step (the 2-phase ceiling,
// m233). Now: prologue stages tiles 0,1; per iter `s_waitcnt vmcnt(4)` drains
// only the 4 oldest loads (= current tile; m135 in-order retire), raw
// s_barrier, sched_barrier(0) pin, then stage tile t+2 into buf (t+2)%3.
// Race-safety: buf(t+2)%3's last readers are iter t-1 ds_reads, complete
// before each wave's MFMAs (lgkmcnt) which precede its barrier-t arrival;
// stage is pinned after the barrier. Tail: vmcnt(0) on the last iter.
// (512,2): VGPR cap 256 — (512,4) spilled acc to scratch (round-3, 260MB
// scratch writes). LDS 96KB -> 1 blk/CU. Used for FFN1 + FFN2 only.
// ---------------------------------------------------------------------------
template<int OUT_MODE, int RELU, int VOFF>
__global__ __launch_bounds__(512, 2)
void k_gemm256(const bf16_t* __restrict__ A, int lda,
               const bf16_t* __restrict__ Bt, int ldb,
               const float* __restrict__ bias,
               bf16_t* __restrict__ C, int ldc,
               bf16_t* __restrict__ Vt,
               bf16_t* __restrict__ p0, bf16_t* __restrict__ p1,
               bf16_t* __restrict__ p2, bf16_t* __restrict__ p3,
               int Ktot, int nx)
{
  __shared__ bf16_t As[3][256 * 32];
  __shared__ bf16_t Bs[3][256 * 32];
  const int tid  = threadIdx.x;
  const int wave = tid >> 6, lane = tid & 63;
  const int quad = lane >> 4, m16 = lane & 15;

  int lin = blockIdx.x;
  int perx = gridDim.x >> 3;
  int t = (lin & 7) * perx + (lin >> 3);
  const int bcol = (t % nx) * 256, brow = (t / nx) * 256;
  const int wr = (wave >> 2) * 128, wc = (wave & 3) * 64;

  const int Kper = Ktot / gridDim.z;
  const int k0 = blockIdx.z * Kper;

  f32x4 acc[8][4];
#pragma unroll
  for (int i = 0; i < 8; i++)
#pragma unroll
    for (int j = 0; j < 4; j++) acc[i][j] = (f32x4){0.f, 0.f, 0.f, 0.f};

  // 16 A-groups + 16 B-groups of 16 rows x 32 cols; wave w stages groups
  // {2w, 2w+1} of each: exactly 4 async 16B loads per wave per stage.
  auto stage = [&](int kt, int buf) {
#pragma unroll
    for (int i = 0; i < 2; i++) {
      int rg = wave * 2 + i;
      async_ld16(A  + (long)(brow + rg * 16 + m16) * lda + kt + quad * 8, As[buf] + rg * 512);
      async_ld16(Bt + (long)(bcol + rg * 16 + m16) * ldb + kt + quad * 8, Bs[buf] + rg * 512);
    }
  };

  const int nIter = Kper >> 5;
  stage(k0, 0);
  if (1 < nIter) stage(k0 + 32, 1);

  for (int it = 0; it < nIter; it++) {
    // counted wait: keep next tile's 4 loads in flight (never vmcnt(0) mid-loop)
    if (it + 1 < nIter) {
      asm volatile("s_waitcnt vmcnt(4)" ::: "memory");
    } else {
      asm volatile("s_waitcnt vmcnt(0)" ::: "memory");
    }
    __builtin_amdgcn_s_barrier();
    __builtin_amdgcn_sched_barrier(0);

    if (it + 2 < nIter) stage(k0 + (it + 2) * 32, (it + 2) % 3);

    const bf16_t* Ac = As[it % 3];
    const bf16_t* Bc = Bs[it % 3];
    bf16x8 af[8], bfr[4];
#pragma unroll
    for (int tt = 0; tt < 8; tt++)
      af[tt]  = *(const bf16x8*)(Ac + ((wr + tt * 16) >> 4) * 512 + quad * 128 + m16 * 8);
#pragma unroll
    for (int j = 0; j < 4; j++)
      bfr[j] = *(const bf16x8*)(Bc + ((wc + j * 16) >> 4) * 512 + quad * 128 + m16 * 8);
#pragma unroll
    for (int i = 0; i < 8; i++)
#pragma unroll
      for (int j = 0; j < 4; j++)
        acc[i][j] = __builtin_amdgcn_mfma_f32_16x16x32_bf16(af[i], bfr[j], acc[i][j], 0, 0, 0);
  }

  if (OUT_MODE == 1) {
    bf16_t* P = blockIdx.z == 0 ? p0 : blockIdx.z == 1 ? p1 : blockIdx.z == 2 ? p2 : p3;
#pragma unroll
    for (int i = 0; i < 8; i++)
#pragma unroll
      for (int j = 0; j < 4; j++) {
        int col = bcol + wc + j * 16 + m16;
#pragma unroll
        for (int r = 0; r < 4; r++) {
          int row = brow + wr + i * 16 + quad * 4 + r;
          P[(long)row * ldc + col] = (bf16_t)acc[i][j][r];
        }
      }
  } else {
#pragma unroll
    for (int i = 0; i < 8; i++)
#pragma unroll
      for (int j = 0; j < 4; j++) {
        int col = bcol + wc + j * 16 + m16;
        float bv = bias[col];
        if (VOFF && col >= VOFF) {
          int hh = (col - VOFF) >> 6, dd = col & 63;
          int row0 = brow + wr + i * 16 + quad * 4;
          int bb = row0 >> 10, seq = row0 & 1023;
          bf16x4 pk;
#pragma unroll
          for (int r = 0; r < 4; r++) pk[r] = (bf16_t)(acc[i][j][r] + bv);
          *(bf16x4*)(Vt + (long)(bb * 16 + hh) * 65536 + dd * 1024 + seq) = pk;
        } else {
#pragma unroll
          for (int r = 0; r < 4; r++) {
            int row = brow + wr + i * 16 + quad * 4 + r;
            float v = acc[i][j][r] + bv;
            if (RELU) v = v > 0.f ? v : 0.f;
            C[(long)row * ldc + col] = (bf16_t)v;
          }
        }
      }
  }
}

// ---------------------------------------------------------------------------
// Split-K reduce (NPART partials) + bias (+resid) (+LayerNorm). 1 row/block.
// ---------------------------------------------------------------------------
template<int LN, int RESID, int OUTF, int OUTB, int NPART>
__global__ __launch_bounds__(256)
void k_reduceN(const bf16_t* __restrict__ p0, const bf16_t* __restrict__ p1,
               const bf16_t* __restrict__ p2, const bf16_t* __restrict__ p3,
               const float* __restrict__ bias, const float* __restrict__ resid,
               const float* __restrict__ gamma, const float* __restrict__ beta,
               float* __restrict__ outf, bf16_t* __restrict__ outb)
{
  constexpr int D = 1024;
  __shared__ float red[8];
  int row = blockIdx.x, tid = threadIdx.x;
  long off = (long)row * D + tid * 4;
  bf16x4 a0 = *(const bf16x4*)(p0 + off);
  bf16x4 a1 = *(const bf16x4*)(p1 + off);
  float4 bb4 = *(const float4*)(bias + tid * 4);
  float4 v;
  v.x = (float)a0[0] + (float)a1[0] + bb4.x;
  v.y = (float)a0[1] + (float)a1[1] + bb4.y;
  v.z = (float)a0[2] + (float)a1[2] + bb4.z;
  v.w = (float)a0[3] + (float)a1[3] + bb4.w;
  if (NPART == 4) {
    bf16x4 a2 = *(const bf16x4*)(p2 + off);
    bf16x4 a3 = *(const bf16x4*)(p3 + off);
    v.x += (float)a2[0] + (float)a3[0];
    v.y += (float)a2[1] + (float)a3[1];
    v.z += (float)a2[2] + (float)a3[2];
    v.w += (float)a2[3] + (float)a3[3];
  }
  if (RESID) {
    float4 q = *(const float4*)(resid + off);
    v.x += q.x; v.y += q.y; v.z += q.z; v.w += q.w;
  }
  float4 y = v;
  if (LN) {
    float s  = v.x + v.y + v.z + v.w;
    float sq = v.x * v.x + v.y * v.y + v.z * v.z + v.w * v.w;
#pragma unroll
    for (int o = 1; o < 64; o <<= 1) {
      s  += __shfl_xor(s, o, 64);
      sq += __shfl_xor(sq, o, 64);
    }
    int wave = tid >> 6, lane = tid & 63;
    if (lane == 0) { red[wave * 2] = s; red[wave * 2 + 1] = sq; }
    __syncthreads();
    float ts = red[0] + red[2] + red[4] + red[6];
    float tq = red[1] + red[3] + red[5] + red[7];
    float mu = ts * (1.f / D);
    float var = tq * (1.f / D) - mu * mu;
    float rstd = rsqrtf(var + 1e-5f);
    float4 g  = *(const float4*)(gamma + tid * 4);
    float4 be = *(const float4*)(beta + tid * 4);
    y.x = (v.x - mu) * rstd * g.x + be.x;
    y.y = (v.y - mu) * rstd * g.y + be.y;
    y.z = (v.z - mu) * rstd * g.z + be.z;
    y.w = (v.w - mu) * rstd * g.w + be.w;
  }
  if (OUTF) *(float4*)(outf + off) = y;
  if (OUTB) {
    bf16x4 o;
    o[0] = (bf16_t)y.x; o[1] = (bf16_t)y.y; o[2] = (bf16_t)y.z; o[3] = (bf16_t)y.w;
    *(bf16x4*)(outb + off) = o;
  }
}

// ---------------------------------------------------------------------------
// Flash attention (round-0 structure: LDS double-buffered KV staging — the
// L2-direct variant measured +60us, latency-bound). Added: s_setprio around
// MFMA clusters (m191: +4-7% on attn — independent blocks give the scheduler
// role diversity; GEMM lockstep case measured null, m190).
// ---------------------------------------------------------------------------
template<int CAUSAL>
__global__ __launch_bounds__(256, 2)
void k_attn(const bf16_t* __restrict__ Q, int ldq,
            const bf16_t* __restrict__ Kp, int ldk,
            const bf16_t* __restrict__ Vt,
            bf16_t* __restrict__ O)
{
  constexpr int S = 1024;
  __shared__ bf16_t Kls[2][4096];
  __shared__ bf16_t Vls[2][4096];
  __shared__ bf16_t Pls[4][32 * 72];

  const int tid = threadIdx.x;
  const int wave = tid >> 6, lane = tid & 63;
  const int quad = lane >> 4, m16 = lane & 15;
  const int qt = blockIdx.x, bh = blockIdx.y, b = bh >> 4, h = bh & 15;
  const int qbase = qt * 128 + wave * 32;

  bf16x8 qf[2][2];
#pragma unroll
  for (int rh = 0; rh < 2; rh++) {
    const bf16_t* qp = Q + (long)(b * S + qbase + rh * 16 + m16) * ldq + h * 64 + quad * 8;
    qf[rh][0] = *(const bf16x8*)qp;
    qf[rh][1] = *(const bf16x8*)(qp + 32);
  }

  f32x4 o_acc[2][4];
#pragma unroll
  for (int rh = 0; rh < 2; rh++)
#pragma unroll
    for (int t = 0; t < 4; t++) o_acc[rh][t] = (f32x4){0.f, 0.f, 0.f, 0.f};
  float rsum[2][4];
#pragma unroll
  for (int rh = 0; rh < 2; rh++)
#pragma unroll
    for (int r = 0; r < 4; r++) rsum[rh][r] = 0.f;

  auto stage = [&](int c, int buf) {
#pragma unroll
    for (int i = 0; i < 2; i++) {
      int t2 = wave * 2 + i;
      int rg = t2 & 3, ph = t2 >> 2;
      async_ld16(Kp + (long)(b * S + c * 64 + rg * 16 + m16) * ldk + h * 64 + ph * 32 + quad * 8,
                 Kls[buf] + t2 * 512);
      async_ld16(Vt + (long)bh * 65536 + (rg * 16 + m16) * 1024 + c * 64 + ph * 32 + quad * 8,
                 Vls[buf] + t2 * 512);
    }
  };

  const int nch = CAUSAL ? (2 * qt + 2) : 16;
  stage(0, 0);

  for (int c = 0; c < nch; c++) {
    __syncthreads();
    const int cur = c & 1;
    if (c + 1 < nch) stage(c + 1, cur ^ 1);

    f32x4 s[2][4];
#pragma unroll
    for (int t = 0; t < 4; t++) {
      bf16x8 k0 = *(const bf16x8*)(Kls[cur] + (0 * 4 + t) * 512 + quad * 128 + m16 * 8);
      bf16x8 k1 = *(const bf16x8*)(Kls[cur] + (1 * 4 + t) * 512 + quad * 128 + m16 * 8);
      __builtin_amdgcn_s_setprio(1);
#pragma unroll
      for (int rh = 0; rh < 2; rh++) {
        f32x4 z = (f32x4){0.f, 0.f, 0.f, 0.f};
        z = __builtin_amdgcn_mfma_f32_16x16x32_bf16(qf[rh][0], k0, z, 0, 0, 0);
        z = __builtin_amdgcn_mfma_f32_16x16x32_bf16(qf[rh][1], k1, z, 0, 0, 0);
        s[rh][t] = z;
      }
      __builtin_amdgcn_s_setprio(0);
    }

    bf16_t* pw = Pls[wave];
#pragma unroll
    for (int rh = 0; rh < 2; rh++)
#pragma unroll
      for (int r = 0; r < 4; r++) {
        int qg = qbase + rh * 16 + quad * 4 + r;
#pragma unroll
        for (int t = 0; t < 4; t++) {
          float v = s[rh][t][r] * 0.125f;
          float p;
          if (CAUSAL) {
            int kvg = c * 64 + t * 16 + m16;
            p = (kvg <= qg) ? __expf(v) : 0.f;
          } else {
            p = __expf(v);
          }
          rsum[rh][r] += p;
          pw[(rh * 16 + quad * 4 + r) * 72 + t * 16 + m16] = (bf16_t)p;
        }
      }

    bf16x8 pf[2][2];
#pragma unroll
    for (int rh = 0; rh < 2; rh++)
#pragma unroll
      for (int kvh = 0; kvh < 2; kvh++)
        pf[rh][kvh] = *(const bf16x8*)(pw + (rh * 16 + m16) * 72 + kvh * 32 + quad * 8);
#pragma unroll
    for (int t = 0; t < 4; t++) {
      bf16x8 v0 = *(const bf16x8*)(Vls[cur] + (0 * 4 + t) * 512 + quad * 128 + m16 * 8);
      bf16x8 v1 = *(const bf16x8*)(Vls[cur] + (1 * 4 + t) * 512 + quad * 128 + m16 * 8);
      __builtin_amdgcn_s_setprio(1);
#pragma unroll
      for (int rh = 0; rh < 2; rh++) {
        o_acc[rh][t] = __builtin_amdgcn_mfma_f32_16x16x32_bf16(pf[rh][0], v0, o_acc[rh][t], 0, 0, 0);
        o_acc[rh][t] = __builtin_amdgcn_mfma_f32_16x16x32_bf16(pf[rh][1], v1, o_acc[rh][t], 0, 0, 0);
      }
      __builtin_amdgcn_s_setprio(0);
    }
  }

#pragma unroll
  for (int rh = 0; rh < 2; rh++)
#pragma unroll
    for (int r = 0; r < 4; r++) {
      float v = rsum[rh][r];
      v += __shfl_xor(v, 1, 64);
      v += __shfl_xor(v, 2, 64);
      v += __shfl_xor(v, 4, 64);
      v += __shfl_xor(v, 8, 64);
      rsum[rh][r] = 1.f / v;
    }
#pragma unroll
  for (int rh = 0; rh < 2; rh++)
#pragma unroll
    for (int t = 0; t < 4; t++)
#pragma unroll
      for (int r = 0; r < 4; r++) {
        int row = b * S + qbase + rh * 16 + quad * 4 + r;
        int col = h * 64 + t * 16 + m16;
        O[(long)row * 1024 + col] = (bf16_t)(o_acc[rh][t][r] * rsum[rh][r]);
      }
}

// ---------------------------------------------------------------------------
extern "C" void kernel_launch(void* const* d_in, const int* in_sizes, int n_in,
                              void* d_out, int out_size, void* d_ws, size_t ws_size,
                              hipStream_t stream)
{
  const float* x   = (const float*)d_in[0];
  const float* enc = (const float*)d_in[1];
  const float* WqS = (const float*)d_in[3];
  const float* bqS = (const float*)d_in[4];
  const float* WkS = (const float*)d_in[5];
  const float* bkS = (const float*)d_in[6];
  const float* WvS = (const float*)d_in[7];
  const float* bvS = (const float*)d_in[8];
  const float* WqX = (const float*)d_in[9];
  const float* bqX = (const float*)d_in[10];
  const float* WkX = (const float*)d_in[11];
  const float* bkX = (const float*)d_in[12];
  const float* WvX = (const float*)d_in[13];
  const float* bvX = (const float*)d_in[14];
  const float* Wo  = (const float*)d_in[15];
  const float* bo  = (const float*)d_in[16];
  const float* W1  = (const float*)d_in[17];
  const float* b1  = (const float*)d_in[18];
  const float* W2  = (const float*)d_in[19];
  const float* b2  = (const float*)d_in[20];
  const float* g1  = (const float*)d_in[21];
  const float* be1 = (const float*)d_in[22];
  const float* g2  = (const float*)d_in[23];
  const float* be2 = (const float*)d_in[24];
  const float* g3  = (const float*)d_in[25];
  const float* be3 = (const float*)d_in[26];

  char* ws = (char*)d_ws;
  const long MBy = 1048576;
  bf16_t* WqkvST = (bf16_t*)(ws + 0 * MBy);            // 6 MB
  bf16_t* WqXT   = (bf16_t*)(ws + 6 * MBy);            // 2 MB
  bf16_t* WkvXT  = (bf16_t*)(ws + 8 * MBy);            // 4 MB
  bf16_t* WoT    = (bf16_t*)(ws + 12 * MBy);           // 2 MB
  bf16_t* W1T    = (bf16_t*)(ws + 14 * MBy);           // 8 MB
  bf16_t* W2T    = (bf16_t*)(ws + 22 * MBy);           // 8 MB
  float*  bqkvS  = (float*)(ws + 30 * MBy);            // 12 KB
  float*  bkvX   = (float*)(ws + 30 * MBy + 16384);    // 8 KB
  bf16_t* xb     = (bf16_t*)(ws + 31 * MBy);           // 8 MB (P1) -> Qx (P2)
  bf16_t* Qx     = xb;
  bf16_t* encb   = (bf16_t*)(ws + 39 * MBy);           // 8 MB (until KVenc)
  float*  x1f    = (float*)(ws + 47 * MBy);            // 16 MB f32 (resid chain)
  bf16_t* x1b    = (bf16_t*)(ws + 63 * MBy);           // 8 MB (->x2b)
  bf16_t* Z      = (bf16_t*)(ws + 71 * MBy);           // 8 MB attn out
  bf16_t* QK     = (bf16_t*)(ws + 79 * MBy);           // 16 MB [4096][2048] (P1)
  bf16_t* Kenc   = (bf16_t*)(ws + 79 * MBy);           // 8 MB [4096][1024] (P2)
  bf16_t* Vt     = (bf16_t*)(ws + 95 * MBy);           // 8 MB [64][64][1024]
  // split-K partial arena: overlays Vt region when dead (z=2 -> only pa0/pa1)
  bf16_t* pa0 = (bf16_t*)(ws + 95 * MBy);
  bf16_t* pa1 = (bf16_t*)(ws + 103 * MBy);
  bf16_t* Hbuf = (bf16_t*)(ws + 95 * MBy);             // 32 MB (P3)
  // FFN2 partials over dead weight/input regions
  bf16_t* pf0 = (bf16_t*)(ws + 0 * MBy);
  bf16_t* pf1 = (bf16_t*)(ws + 8 * MBy);
  bf16_t* pf2 = (bf16_t*)(ws + 31 * MBy);
  bf16_t* pf3 = (bf16_t*)(ws + 39 * MBy);

  dim3 tb(256), tb512(512);

  // ---- fused prep (1 dispatch) ----
  PrepArgs pa;
  pa.WqS = WqS; pa.WkS = WkS; pa.WvS = WvS; pa.WqX = WqX; pa.WkX = WkX; pa.WvX = WvX;
  pa.Wo = Wo; pa.W1 = W1; pa.W2 = W2; pa.x = x; pa.enc = enc;
  pa.bqS = bqS; pa.bkS = bkS; pa.bvS = bvS; pa.bkX = bkX; pa.bvX = bvX;
  pa.WqkvST = WqkvST; pa.WqXT = WqXT; pa.WkvXT = WkvXT; pa.WoT = WoT;
  pa.W1T = W1T; pa.W2T = W2T; pa.xb = xb; pa.encb = encb;
  pa.bqkv = bqkvS; pa.bkvx = bkvX;
  k_prep<<<dim3(17413), tb, 0, stream>>>(pa);

  // ---- phase 1: self-attention ----
  k_gemm<0, 0, 2048><<<dim3(768, 1, 1), tb, 0, stream>>>(
      xb, 1024, WqkvST, 1024, bqkvS, QK, 2048, Vt,
      nullptr, nullptr, nullptr, nullptr, 1024, 24);
  k_attn<1><<<dim3(8, 64), tb, 0, stream>>>(QK, 2048, QK + 1024, 2048, Vt, Z);
  k_gemm<1, 0, 0><<<dim3(256, 1, 2), tb, 0, stream>>>(
      Z, 1024, WoT, 1024, nullptr, nullptr, 1024, nullptr,
      pa0, pa1, nullptr, nullptr, 1024, 8);
  k_reduceN<1, 1, 1, 1, 2><<<dim3(4096), tb, 0, stream>>>(
      pa0, pa1, nullptr, nullptr, bo, x, g1, be1, x1f, x1b);

  // ---- phase 2: cross-attention ----
  k_gemm<1, 0, 0><<<dim3(256, 1, 2), tb, 0, stream>>>(
      x1b, 1024, WqXT, 1024, nullptr, nullptr, 1024, nullptr,
      pa0, pa1, nullptr, nullptr, 1024, 8);
  k_reduceN<0, 0, 0, 1, 2><<<dim3(4096), tb, 0, stream>>>(
      pa0, pa1, nullptr, nullptr, bqX, nullptr, nullptr, nullptr, nullptr, Qx);
  k_gemm<0, 0, 1024><<<dim3(512, 1, 1), tb, 0, stream>>>(
      encb, 1024, WkvXT, 1024, bkvX, Kenc, 1024, Vt,
      nullptr, nullptr, nullptr, nullptr, 1024, 16);
  k_attn<0><<<dim3(8, 64), tb, 0, stream>>>(Qx, 1024, Kenc, 1024, Vt, Z);
  k_gemm<1, 0, 0><<<dim3(256, 1, 2), tb, 0, stream>>>(
      Z, 1024, WoT, 1024, nullptr, nullptr, 1024, nullptr,
      pa0, pa1, nullptr, nullptr, 1024, 8);
  k_reduceN<1, 1, 1, 1, 2><<<dim3(4096), tb, 0, stream>>>(
      pa0, pa1, nullptr, nullptr, bo, x1f, g2, be2, x1f, x1b);

  // ---- phase 3: FFN ----
  k_gemm256<0, 1, 0><<<dim3(256, 1, 1), tb512, 0, stream>>>(
      x1b, 1024, W1T, 1024, b1, Hbuf, 4096, nullptr,
      nullptr, nullptr, nullptr, nullptr, 1024, 16);
  k_gemm256<1, 0, 0><<<dim3(64, 1, 4), tb512, 0, stream>>>(
      Hbuf, 4096, W2T, 4096, nullptr, nullptr, 1024, nullptr,
      pf0, pf1, pf2, pf3, 4096, 4);
  k_reduceN<1, 1, 1, 0, 4><<<dim3(4096), tb, 0, stream>>>(
      pf0, pf1, pf2, pf3, b2, x1f, g3, be3, (float*)d_out, nullptr);
}

// Round 6
// 552.715 us; speedup vs baseline: 1.0162x; 1.0162x over previous
//
#include <hip/hip_runtime.h>
#include <cstdint>

typedef __bf16 bf16_t;
typedef bf16_t bf16x8 __attribute__((ext_vector_type(8)));
typedef bf16_t bf16x4 __attribute__((ext_vector_type(4)));
typedef float  f32x4  __attribute__((ext_vector_type(4)));

#define DEVI static __device__ __forceinline__

DEVI void async_ld16(const bf16_t* g, bf16_t* l) {
  __builtin_amdgcn_global_load_lds((const __attribute__((address_space(1))) void*)g,
                                   (__attribute__((address_space(3))) void*)l, 16, 0, 0);
}

// ---------------------------------------------------------------------------
// Fused prep: all weight transposes + bf16 converts + bias packs, one dispatch.
// ---------------------------------------------------------------------------
struct PrepArgs {
  const float *WqS, *WkS, *WvS, *WqX, *WkX, *WvX, *Wo, *W1, *W2, *x, *enc;
  const float *bqS, *bkS, *bvS, *bkX, *bvX;
  bf16_t *WqkvST, *WqXT, *WkvXT, *WoT, *W1T, *W2T, *xb, *encb;
  float *bqkv, *bkvx;
};

__global__ __launch_bounds__(256)
void k_prep(PrepArgs a)
{
  __shared__ float tile[32][33];
  const int blk = blockIdx.x, tid = threadIdx.x;
  const int tx = tid & 31, ty = tid >> 5;

  const float* src = nullptr;
  bf16_t* dst = nullptr;
  int srcLd = 0, dstLd = 0, m0 = 0, n0 = 0;
  bool do_tr = false;

  if (blk < 6144) {
    int j = blk >> 10, q = blk & 1023;
    src = j == 0 ? a.WqS : j == 1 ? a.WkS : j == 2 ? a.WvS : j == 3 ? a.WqX : j == 4 ? a.WkX : a.WvX;
    dst = j == 0 ? a.WqkvST : j == 1 ? a.WqkvST + 1048576 : j == 2 ? a.WqkvST + 2097152
        : j == 3 ? a.WqXT : j == 4 ? a.WkvXT : a.WkvXT + 1048576;
    int batch = q >> 6, rem = q & 63;
    src += (long)batch * 65536; dst += (long)batch * 65536;
    srcLd = 64; dstLd = 1024;
    n0 = (rem & 1) * 32; m0 = (rem >> 1) * 32;
    do_tr = true;
  } else if (blk < 7168) {
    int q = blk - 6144;
    src = a.Wo; dst = a.WoT; srcLd = 1024; dstLd = 1024;
    m0 = (q >> 5) * 32; n0 = (q & 31) * 32; do_tr = true;
  } else if (blk < 11264) {
    int q = blk - 7168;
    src = a.W1; dst = a.W1T; srcLd = 4096; dstLd = 1024;
    m0 = (q >> 7) * 32; n0 = (q & 127) * 32; do_tr = true;
  } else if (blk < 15360) {
    int q = blk - 11264;
    src = a.W2; dst = a.W2T; srcLd = 1024; dstLd = 4096;
    m0 = (q >> 5) * 32; n0 = (q & 31) * 32; do_tr = true;
  } else if (blk < 16384) {
    long base = (long)(blk - 15360) * 4096 + tid * 4;
#pragma unroll
    for (int u = 0; u < 4; u++) {
      float4 v = *(const float4*)(a.x + base + u * 1024);
      bf16x4 o; o[0] = (bf16_t)v.x; o[1] = (bf16_t)v.y; o[2] = (bf16_t)v.z; o[3] = (bf16_t)v.w;
      *(bf16x4*)(a.xb + base + u * 1024) = o;
    }
    return;
  } else if (blk < 17408) {
    long base = (long)(blk - 16384) * 4096 + tid * 4;
#pragma unroll
    for (int u = 0; u < 4; u++) {
      float4 v = *(const float4*)(a.enc + base + u * 1024);
      bf16x4 o; o[0] = (bf16_t)v.x; o[1] = (bf16_t)v.y; o[2] = (bf16_t)v.z; o[3] = (bf16_t)v.w;
      *(bf16x4*)(a.encb + base + u * 1024) = o;
    }
    return;
  } else {
    int gi = (blk - 17408) * 1024 + tid * 4;
#pragma unroll
    for (int j = 0; j < 4; j++) {
      int i = gi + j;
      if (i < 1024)      a.bqkv[i] = a.bqS[i];
      else if (i < 2048) a.bqkv[i] = a.bkS[i - 1024];
      else if (i < 3072) a.bqkv[i] = a.bvS[i - 2048];
      else if (i < 4096) a.bkvx[i - 3072] = a.bkX[i - 3072];
      else if (i < 5120) a.bkvx[i - 3072] = a.bvX[i - 4096];
    }
    return;
  }

  if (do_tr) {
#pragma unroll
    for (int i = 0; i < 4; i++)
      tile[ty + i * 8][tx] = src[(long)(m0 + ty + i * 8) * srcLd + n0 + tx];
    __syncthreads();
#pragma unroll
    for (int i = 0; i < 4; i++)
      dst[(long)(n0 + ty + i * 8) * dstLd + m0 + tx] = (bf16_t)tile[tx][ty + i * 8];
  }
}

// ---------------------------------------------------------------------------
// GEMM 128x128 tile, BK=32, 2-phase double-buffered global_load_lds.
// (Known-good core — do not re-pipeline (m131-m141); do not shrink tile
//  (64^2: 126us vs 77us); do NOT raise BK here: 64KB LDS would cut occupancy
//  3->2 blocks/CU, m132's measured regression 874->508.)
// ---------------------------------------------------------------------------
template<int OUT_MODE, int RELU, int VOFF>
__global__ __launch_bounds__(256, 2)
void k_gemm(const bf16_t* __restrict__ A, int lda,
            const bf16_t* __restrict__ Bt, int ldb,
            const float* __restrict__ bias,
            bf16_t* __restrict__ C, int ldc,
            bf16_t* __restrict__ Vt,
            bf16_t* __restrict__ p0, bf16_t* __restrict__ p1,
            bf16_t* __restrict__ p2, bf16_t* __restrict__ p3,
            int Ktot, int nx)
{
  __shared__ bf16_t As[2][128 * 32];
  __shared__ bf16_t Bs[2][128 * 32];
  const int tid  = threadIdx.x;
  const int wave = tid >> 6, lane = tid & 63;
  const int quad = lane >> 4, m16 = lane & 15;

  int lin = blockIdx.x;
  int perx = gridDim.x >> 3;
  int t = (lin & 7) * perx + (lin >> 3);
  const int bcol = (t % nx) * 128, brow = (t / nx) * 128;
  const int wr = (wave >> 1) * 64, wc = (wave & 1) * 64;

  const int Kper = Ktot / gridDim.z;
  const int k0 = blockIdx.z * Kper;

  f32x4 acc[4][4];
#pragma unroll
  for (int i = 0; i < 4; i++)
#pragma unroll
    for (int j = 0; j < 4; j++) acc[i][j] = (f32x4){0.f, 0.f, 0.f, 0.f};

  auto stage = [&](int kt, int buf) {
#pragma unroll
    for (int i = 0; i < 2; i++) {
      int rg = wave * 2 + i;
      async_ld16(A  + (long)(brow + rg * 16 + m16) * lda + kt + quad * 8, As[buf] + rg * 512);
      async_ld16(Bt + (long)(bcol + rg * 16 + m16) * ldb + kt + quad * 8, Bs[buf] + rg * 512);
    }
  };

  stage(k0, 0);
  __syncthreads();

  const int nIter = Kper >> 5;
  for (int it = 0; it < nIter; it++) {
    const int cur = it & 1;
    if (it + 1 < nIter) stage(k0 + (it + 1) * 32, cur ^ 1);

    bf16x8 af[4], bfr[4];
#pragma unroll
    for (int tt = 0; tt < 4; tt++) {
      af[tt]  = *(const bf16x8*)(As[cur] + ((wr + tt * 16) >> 4) * 512 + quad * 128 + m16 * 8);
      bfr[tt] = *(const bf16x8*)(Bs[cur] + ((wc + tt * 16) >> 4) * 512 + quad * 128 + m16 * 8);
    }
#pragma unroll
    for (int i = 0; i < 4; i++)
#pragma unroll
      for (int j = 0; j < 4; j++)
        acc[i][j] = __builtin_amdgcn_mfma_f32_16x16x32_bf16(af[i], bfr[j], acc[i][j], 0, 0, 0);

    __syncthreads();
  }

  if (OUT_MODE == 1) {
    bf16_t* P = blockIdx.z == 0 ? p0 : blockIdx.z == 1 ? p1 : blockIdx.z == 2 ? p2 : p3;
#pragma unroll
    for (int i = 0; i < 4; i++)
#pragma unroll
      for (int j = 0; j < 4; j++) {
        int col = bcol + wc + j * 16 + m16;
#pragma unroll
        for (int r = 0; r < 4; r++) {
          int row = brow + wr + i * 16 + quad * 4 + r;
          P[(long)row * ldc + col] = (bf16_t)acc[i][j][r];
        }
      }
  } else {
#pragma unroll
    for (int i = 0; i < 4; i++)
#pragma unroll
      for (int j = 0; j < 4; j++) {
        int col = bcol + wc + j * 16 + m16;
        float bv = bias[col];
        if (VOFF && col >= VOFF) {
          int hh = (col - VOFF) >> 6, dd = col & 63;
          int row0 = brow + wr + i * 16 + quad * 4;
          int bb = row0 >> 10, seq = row0 & 1023;
          bf16x4 pk;
#pragma unroll
          for (int r = 0; r < 4; r++) pk[r] = (bf16_t)(acc[i][j][r] + bv);
          *(bf16x4*)(Vt + (long)(bb * 16 + hh) * 65536 + dd * 1024 + seq) = pk;
        } else {
#pragma unroll
          for (int r = 0; r < 4; r++) {
            int row = brow + wr + i * 16 + quad * 4 + r;
            float v = acc[i][j][r] + bv;
            if (RELU) v = v > 0.f ? v : 0.f;
            C[(long)row * ldc + col] = (bf16_t)v;
          }
        }
      }
  }
}

// ---------------------------------------------------------------------------
// GEMM 256x256 tile, BK=64, 2-phase double-buffer (m230-V0 / T3-minimal
// structure, 682 TF measured on this chip). Round-5 post-mortem: counted
// vmcnt at BK=32 granularity was neutral — the lever is MFMA-per-barrier,
// so BK 32->64 doubles it (64 MFMA/wave per drain) and halves drain count.
// LDS 2 x (A 32KB + B 32KB) = 128 KB -> 1 blk/CU (unchanged — already 1).
// Subtile layout: (rg, ks) at offset (rg*2+ks)*512, rg=16-row group,
// ks=32-K half; within subtile the proven packed map (quad*128 + m16*8).
// Stage-early: next tile's 8 DMAs issue before current compute; the
// __syncthreads() drain then lands after ~64 MFMA of cover. (512,2): VGPR
// cap 256 — (512,4) spilled acc (round-3). Used for FFN1 + FFN2 only.
// ---------------------------------------------------------------------------
template<int OUT_MODE, int RELU, int VOFF>
__global__ __launch_bounds__(512, 2)
void k_gemm256(const bf16_t* __restrict__ A, int lda,
               const bf16_t* __restrict__ Bt, int ldb,
               const float* __restrict__ bias,
               bf16_t* __restrict__ C, int ldc,
               bf16_t* __restrict__ Vt,
               bf16_t* __restrict__ p0, bf16_t* __restrict__ p1,
               bf16_t* __restrict__ p2, bf16_t* __restrict__ p3,
               int Ktot, int nx)
{
  __shared__ bf16_t As[2][256 * 64];
  __shared__ bf16_t Bs[2][256 * 64];
  const int tid  = threadIdx.x;
  const int wave = tid >> 6, lane = tid & 63;
  const int quad = lane >> 4, m16 = lane & 15;

  int lin = blockIdx.x;
  int perx = gridDim.x >> 3;
  int t = (lin & 7) * perx + (lin >> 3);
  const int bcol = (t % nx) * 256, brow = (t / nx) * 256;
  const int wr = (wave >> 2) * 128, wc = (wave & 3) * 64;

  const int Kper = Ktot / gridDim.z;
  const int k0 = blockIdx.z * Kper;

  f32x4 acc[8][4];
#pragma unroll
  for (int i = 0; i < 8; i++)
#pragma unroll
    for (int j = 0; j < 4; j++) acc[i][j] = (f32x4){0.f, 0.f, 0.f, 0.f};

  // wave w stages row-groups {2w, 2w+1} of A and B, both 32-K halves:
  // 8 async 16B loads per wave per K-tile (64 KB/tile total).
  auto stage = [&](int kt, int buf) {
#pragma unroll
    for (int i = 0; i < 2; i++) {
      int rg = wave * 2 + i;
#pragma unroll
      for (int ks = 0; ks < 2; ks++) {
        async_ld16(A  + (long)(brow + rg * 16 + m16) * lda + kt + ks * 32 + quad * 8,
                   As[buf] + (rg * 2 + ks) * 512);
        async_ld16(Bt + (long)(bcol + rg * 16 + m16) * ldb + kt + ks * 32 + quad * 8,
                   Bs[buf] + (rg * 2 + ks) * 512);
      }
    }
  };

  stage(k0, 0);
  __syncthreads();

  const int nIter = Kper >> 6;
  for (int it = 0; it < nIter; it++) {
    const int cur = it & 1;
    if (it + 1 < nIter) stage(k0 + (it + 1) * 64, cur ^ 1);

    const bf16_t* Ac = As[cur];
    const bf16_t* Bc = Bs[cur];
#pragma unroll
    for (int ks = 0; ks < 2; ks++) {
      bf16x8 af[8], bfr[4];
#pragma unroll
      for (int tt = 0; tt < 8; tt++)
        af[tt] = *(const bf16x8*)(Ac + (((wr + tt * 16) >> 4) * 2 + ks) * 512 + quad * 128 + m16 * 8);
#pragma unroll
      for (int j = 0; j < 4; j++)
        bfr[j] = *(const bf16x8*)(Bc + (((wc + j * 16) >> 4) * 2 + ks) * 512 + quad * 128 + m16 * 8);
#pragma unroll
      for (int i = 0; i < 8; i++)
#pragma unroll
        for (int j = 0; j < 4; j++)
          acc[i][j] = __builtin_amdgcn_mfma_f32_16x16x32_bf16(af[i], bfr[j], acc[i][j], 0, 0, 0);
    }

    __syncthreads();
  }

  if (OUT_MODE == 1) {
    bf16_t* P = blockIdx.z == 0 ? p0 : blockIdx.z == 1 ? p1 : blockIdx.z == 2 ? p2 : p3;
#pragma unroll
    for (int i = 0; i < 8; i++)
#pragma unroll
      for (int j = 0; j < 4; j++) {
        int col = bcol + wc + j * 16 + m16;
#pragma unroll
        for (int r = 0; r < 4; r++) {
          int row = brow + wr + i * 16 + quad * 4 + r;
          P[(long)row * ldc + col] = (bf16_t)acc[i][j][r];
        }
      }
  } else {
#pragma unroll
    for (int i = 0; i < 8; i++)
#pragma unroll
      for (int j = 0; j < 4; j++) {
        int col = bcol + wc + j * 16 + m16;
        float bv = bias[col];
        if (VOFF && col >= VOFF) {
          int hh = (col - VOFF) >> 6, dd = col & 63;
          int row0 = brow + wr + i * 16 + quad * 4;
          int bb = row0 >> 10, seq = row0 & 1023;
          bf16x4 pk;
#pragma unroll
          for (int r = 0; r < 4; r++) pk[r] = (bf16_t)(acc[i][j][r] + bv);
          *(bf16x4*)(Vt + (long)(bb * 16 + hh) * 65536 + dd * 1024 + seq) = pk;
        } else {
#pragma unroll
          for (int r = 0; r < 4; r++) {
            int row = brow + wr + i * 16 + quad * 4 + r;
            float v = acc[i][j][r] + bv;
            if (RELU) v = v > 0.f ? v : 0.f;
            C[(long)row * ldc + col] = (bf16_t)v;
          }
        }
      }
  }
}

// ---------------------------------------------------------------------------
// Split-K reduce (NPART partials) + bias (+resid) (+LayerNorm). 1 row/block.
// ---------------------------------------------------------------------------
template<int LN, int RESID, int OUTF, int OUTB, int NPART>
__global__ __launch_bounds__(256)
void k_reduceN(const bf16_t* __restrict__ p0, const bf16_t* __restrict__ p1,
               const bf16_t* __restrict__ p2, const bf16_t* __restrict__ p3,
               const float* __restrict__ bias, const float* __restrict__ resid,
               const float* __restrict__ gamma, const float* __restrict__ beta,
               float* __restrict__ outf, bf16_t* __restrict__ outb)
{
  constexpr int D = 1024;
  __shared__ float red[8];
  int row = blockIdx.x, tid = threadIdx.x;
  long off = (long)row * D + tid * 4;
  bf16x4 a0 = *(const bf16x4*)(p0 + off);
  bf16x4 a1 = *(const bf16x4*)(p1 + off);
  float4 bb4 = *(const float4*)(bias + tid * 4);
  float4 v;
  v.x = (float)a0[0] + (float)a1[0] + bb4.x;
  v.y = (float)a0[1] + (float)a1[1] + bb4.y;
  v.z = (float)a0[2] + (float)a1[2] + bb4.z;
  v.w = (float)a0[3] + (float)a1[3] + bb4.w;
  if (NPART == 4) {
    bf16x4 a2 = *(const bf16x4*)(p2 + off);
    bf16x4 a3 = *(const bf16x4*)(p3 + off);
    v.x += (float)a2[0] + (float)a3[0];
    v.y += (float)a2[1] + (float)a3[1];
    v.z += (float)a2[2] + (float)a3[2];
    v.w += (float)a2[3] + (float)a3[3];
  }
  if (RESID) {
    float4 q = *(const float4*)(resid + off);
    v.x += q.x; v.y += q.y; v.z += q.z; v.w += q.w;
  }
  float4 y = v;
  if (LN) {
    float s  = v.x + v.y + v.z + v.w;
    float sq = v.x * v.x + v.y * v.y + v.z * v.z + v.w * v.w;
#pragma unroll
    for (int o = 1; o < 64; o <<= 1) {
      s  += __shfl_xor(s, o, 64);
      sq += __shfl_xor(sq, o, 64);
    }
    int wave = tid >> 6, lane = tid & 63;
    if (lane == 0) { red[wave * 2] = s; red[wave * 2 + 1] = sq; }
    __syncthreads();
    float ts = red[0] + red[2] + red[4] + red[6];
    float tq = red[1] + red[3] + red[5] + red[7];
    float mu = ts * (1.f / D);
    float var = tq * (1.f / D) - mu * mu;
    float rstd = rsqrtf(var + 1e-5f);
    float4 g  = *(const float4*)(gamma + tid * 4);
    float4 be = *(const float4*)(beta + tid * 4);
    y.x = (v.x - mu) * rstd * g.x + be.x;
    y.y = (v.y - mu) * rstd * g.y + be.y;
    y.z = (v.z - mu) * rstd * g.z + be.z;
    y.w = (v.w - mu) * rstd * g.w + be.w;
  }
  if (OUTF) *(float4*)(outf + off) = y;
  if (OUTB) {
    bf16x4 o;
    o[0] = (bf16_t)y.x; o[1] = (bf16_t)y.y; o[2] = (bf16_t)y.z; o[3] = (bf16_t)y.w;
    *(bf16x4*)(outb + off) = o;
  }
}

// ---------------------------------------------------------------------------
// Flash attention (round-0 structure: LDS double-buffered KV staging — the
// L2-direct variant measured +60us, latency-bound). s_setprio around MFMA
// clusters kept (m191: +4-7% regime; measured neutral-at-worst here).
// ---------------------------------------------------------------------------
template<int CAUSAL>
__global__ __launch_bounds__(256, 2)
void k_attn(const bf16_t* __restrict__ Q, int ldq,
            const bf16_t* __restrict__ Kp, int ldk,
            const bf16_t* __restrict__ Vt,
            bf16_t* __restrict__ O)
{
  constexpr int S = 1024;
  __shared__ bf16_t Kls[2][4096];
  __shared__ bf16_t Vls[2][4096];
  __shared__ bf16_t Pls[4][32 * 72];

  const int tid = threadIdx.x;
  const int wave = tid >> 6, lane = tid & 63;
  const int quad = lane >> 4, m16 = lane & 15;
  const int qt = blockIdx.x, bh = blockIdx.y, b = bh >> 4, h = bh & 15;
  const int qbase = qt * 128 + wave * 32;

  bf16x8 qf[2][2];
#pragma unroll
  for (int rh = 0; rh < 2; rh++) {
    const bf16_t* qp = Q + (long)(b * S + qbase + rh * 16 + m16) * ldq + h * 64 + quad * 8;
    qf[rh][0] = *(const bf16x8*)qp;
    qf[rh][1] = *(const bf16x8*)(qp + 32);
  }

  f32x4 o_acc[2][4];
#pragma unroll
  for (int rh = 0; rh < 2; rh++)
#pragma unroll
    for (int t = 0; t < 4; t++) o_acc[rh][t] = (f32x4){0.f, 0.f, 0.f, 0.f};
  float rsum[2][4];
#pragma unroll
  for (int rh = 0; rh < 2; rh++)
#pragma unroll
    for (int r = 0; r < 4; r++) rsum[rh][r] = 0.f;

  auto stage = [&](int c, int buf) {
#pragma unroll
    for (int i = 0; i < 2; i++) {
      int t2 = wave * 2 + i;
      int rg = t2 & 3, ph = t2 >> 2;
      async_ld16(Kp + (long)(b * S + c * 64 + rg * 16 + m16) * ldk + h * 64 + ph * 32 + quad * 8,
                 Kls[buf] + t2 * 512);
      async_ld16(Vt + (long)bh * 65536 + (rg * 16 + m16) * 1024 + c * 64 + ph * 32 + quad * 8,
                 Vls[buf] + t2 * 512);
    }
  };

  const int nch = CAUSAL ? (2 * qt + 2) : 16;
  stage(0, 0);

  for (int c = 0; c < nch; c++) {
    __syncthreads();
    const int cur = c & 1;
    if (c + 1 < nch) stage(c + 1, cur ^ 1);

    f32x4 s[2][4];
#pragma unroll
    for (int t = 0; t < 4; t++) {
      bf16x8 k0 = *(const bf16x8*)(Kls[cur] + (0 * 4 + t) * 512 + quad * 128 + m16 * 8);
      bf16x8 k1 = *(const bf16x8*)(Kls[cur] + (1 * 4 + t) * 512 + quad * 128 + m16 * 8);
      __builtin_amdgcn_s_setprio(1);
#pragma unroll
      for (int rh = 0; rh < 2; rh++) {
        f32x4 z = (f32x4){0.f, 0.f, 0.f, 0.f};
        z = __builtin_amdgcn_mfma_f32_16x16x32_bf16(qf[rh][0], k0, z, 0, 0, 0);
        z = __builtin_amdgcn_mfma_f32_16x16x32_bf16(qf[rh][1], k1, z, 0, 0, 0);
        s[rh][t] = z;
      }
      __builtin_amdgcn_s_setprio(0);
    }

    bf16_t* pw = Pls[wave];
#pragma unroll
    for (int rh = 0; rh < 2; rh++)
#pragma unroll
      for (int r = 0; r < 4; r++) {
        int qg = qbase + rh * 16 + quad * 4 + r;
#pragma unroll
        for (int t = 0; t < 4; t++) {
          float v = s[rh][t][r] * 0.125f;
          float p;
          if (CAUSAL) {
            int kvg = c * 64 + t * 16 + m16;
            p = (kvg <= qg) ? __expf(v) : 0.f;
          } else {
            p = __expf(v);
          }
          rsum[rh][r] += p;
          pw[(rh * 16 + quad * 4 + r) * 72 + t * 16 + m16] = (bf16_t)p;
        }
      }

    bf16x8 pf[2][2];
#pragma unroll
    for (int rh = 0; rh < 2; rh++)
#pragma unroll
      for (int kvh = 0; kvh < 2; kvh++)
        pf[rh][kvh] = *(const bf16x8*)(pw + (rh * 16 + m16) * 72 + kvh * 32 + quad * 8);
#pragma unroll
    for (int t = 0; t < 4; t++) {
      bf16x8 v0 = *(const bf16x8*)(Vls[cur] + (0 * 4 + t) * 512 + quad * 128 + m16 * 8);
      bf16x8 v1 = *(const bf16x8*)(Vls[cur] + (1 * 4 + t) * 512 + quad * 128 + m16 * 8);
      __builtin_amdgcn_s_setprio(1);
#pragma unroll
      for (int rh = 0; rh < 2; rh++) {
        o_acc[rh][t] = __builtin_amdgcn_mfma_f32_16x16x32_bf16(pf[rh][0], v0, o_acc[rh][t], 0, 0, 0);
        o_acc[rh][t] = __builtin_amdgcn_mfma_f32_16x16x32_bf16(pf[rh][1], v1, o_acc[rh][t], 0, 0, 0);
      }
      __builtin_amdgcn_s_setprio(0);
    }
  }

#pragma unroll
  for (int rh = 0; rh < 2; rh++)
#pragma unroll
    for (int r = 0; r < 4; r++) {
      float v = rsum[rh][r];
      v += __shfl_xor(v, 1, 64);
      v += __shfl_xor(v, 2, 64);
      v += __shfl_xor(v, 4, 64);
      v += __shfl_xor(v, 8, 64);
      rsum[rh][r] = 1.f / v;
    }
#pragma unroll
  for (int rh = 0; rh < 2; rh++)
#pragma unroll
    for (int t = 0; t < 4; t++)
#pragma unroll
      for (int r = 0; r < 4; r++) {
        int row = b * S + qbase + rh * 16 + quad * 4 + r;
        int col = h * 64 + t * 16 + m16;
        O[(long)row * 1024 + col] = (bf16_t)(o_acc[rh][t][r] * rsum[rh][r]);
      }
}

// ---------------------------------------------------------------------------
extern "C" void kernel_launch(void* const* d_in, const int* in_sizes, int n_in,
                              void* d_out, int out_size, void* d_ws, size_t ws_size,
                              hipStream_t stream)
{
  const float* x   = (const float*)d_in[0];
  const float* enc = (const float*)d_in[1];
  const float* WqS = (const float*)d_in[3];
  const float* bqS = (const float*)d_in[4];
  const float* WkS = (const float*)d_in[5];
  const float* bkS = (const float*)d_in[6];
  const float* WvS = (const float*)d_in[7];
  const float* bvS = (const float*)d_in[8];
  const float* WqX = (const float*)d_in[9];
  const float* bqX = (const float*)d_in[10];
  const float* WkX = (const float*)d_in[11];
  const float* bkX = (const float*)d_in[12];
  const float* WvX = (const float*)d_in[13];
  const float* bvX = (const float*)d_in[14];
  const float* Wo  = (const float*)d_in[15];
  const float* bo  = (const float*)d_in[16];
  const float* W1  = (const float*)d_in[17];
  const float* b1  = (const float*)d_in[18];
  const float* W2  = (const float*)d_in[19];
  const float* b2  = (const float*)d_in[20];
  const float* g1  = (const float*)d_in[21];
  const float* be1 = (const float*)d_in[22];
  const float* g2  = (const float*)d_in[23];
  const float* be2 = (const float*)d_in[24];
  const float* g3  = (const float*)d_in[25];
  const float* be3 = (const float*)d_in[26];

  char* ws = (char*)d_ws;
  const long MBy = 1048576;
  bf16_t* WqkvST = (bf16_t*)(ws + 0 * MBy);            // 6 MB
  bf16_t* WqXT   = (bf16_t*)(ws + 6 * MBy);            // 2 MB
  bf16_t* WkvXT  = (bf16_t*)(ws + 8 * MBy);            // 4 MB
  bf16_t* WoT    = (bf16_t*)(ws + 12 * MBy);           // 2 MB
  bf16_t* W1T    = (bf16_t*)(ws + 14 * MBy);           // 8 MB
  bf16_t* W2T    = (bf16_t*)(ws + 22 * MBy);           // 8 MB
  float*  bqkvS  = (float*)(ws + 30 * MBy);            // 12 KB
  float*  bkvX   = (float*)(ws + 30 * MBy + 16384);    // 8 KB
  bf16_t* xb     = (bf16_t*)(ws + 31 * MBy);           // 8 MB (P1) -> Qx (P2)
  bf16_t* Qx     = xb;
  bf16_t* encb   = (bf16_t*)(ws + 39 * MBy);           // 8 MB (until KVenc)
  float*  x1f    = (float*)(ws + 47 * MBy);            // 16 MB f32 (resid chain)
  bf16_t* x1b    = (bf16_t*)(ws + 63 * MBy);           // 8 MB (->x2b)
  bf16_t* Z      = (bf16_t*)(ws + 71 * MBy);           // 8 MB attn out
  bf16_t* QK     = (bf16_t*)(ws + 79 * MBy);           // 16 MB [4096][2048] (P1)
  bf16_t* Kenc   = (bf16_t*)(ws + 79 * MBy);           // 8 MB [4096][1024] (P2)
  bf16_t* Vt     = (bf16_t*)(ws + 95 * MBy);           // 8 MB [64][64][1024]
  // split-K partial arena: overlays Vt region when dead (z=2 -> only pa0/pa1)
  bf16_t* pa0 = (bf16_t*)(ws + 95 * MBy);
  bf16_t* pa1 = (bf16_t*)(ws + 103 * MBy);
  bf16_t* Hbuf = (bf16_t*)(ws + 95 * MBy);             // 32 MB (P3)
  // FFN2 partials over dead weight/input regions
  bf16_t* pf0 = (bf16_t*)(ws + 0 * MBy);
  bf16_t* pf1 = (bf16_t*)(ws + 8 * MBy);
  bf16_t* pf2 = (bf16_t*)(ws + 31 * MBy);
  bf16_t* pf3 = (bf16_t*)(ws + 39 * MBy);

  dim3 tb(256), tb512(512);

  // ---- fused prep (1 dispatch) ----
  PrepArgs pa;
  pa.WqS = WqS; pa.WkS = WkS; pa.WvS = WvS; pa.WqX = WqX; pa.WkX = WkX; pa.WvX = WvX;
  pa.Wo = Wo; pa.W1 = W1; pa.W2 = W2; pa.x = x; pa.enc = enc;
  pa.bqS = bqS; pa.bkS = bkS; pa.bvS = bvS; pa.bkX = bkX; pa.bvX = bvX;
  pa.WqkvST = WqkvST; pa.WqXT = WqXT; pa.WkvXT = WkvXT; pa.WoT = WoT;
  pa.W1T = W1T; pa.W2T = W2T; pa.xb = xb; pa.encb = encb;
  pa.bqkv = bqkvS; pa.bkvx = bkvX;
  k_prep<<<dim3(17413), tb, 0, stream>>>(pa);

  // ---- phase 1: self-attention ----
  k_gemm<0, 0, 2048><<<dim3(768, 1, 1), tb, 0, stream>>>(
      xb, 1024, WqkvST, 1024, bqkvS, QK, 2048, Vt,
      nullptr, nullptr, nullptr, nullptr, 1024, 24);
  k_attn<1><<<dim3(8, 64), tb, 0, stream>>>(QK, 2048, QK + 1024, 2048, Vt, Z);
  k_gemm<1, 0, 0><<<dim3(256, 1, 2), tb, 0, stream>>>(
      Z, 1024, WoT, 1024, nullptr, nullptr, 1024, nullptr,
      pa0, pa1, nullptr, nullptr, 1024, 8);
  k_reduceN<1, 1, 1, 1, 2><<<dim3(4096), tb, 0, stream>>>(
      pa0, pa1, nullptr, nullptr, bo, x, g1, be1, x1f, x1b);

  // ---- phase 2: cross-attention ----
  k_gemm<1, 0, 0><<<dim3(256, 1, 2), tb, 0, stream>>>(
      x1b, 1024, WqXT, 1024, nullptr, nullptr, 1024, nullptr,
      pa0, pa1, nullptr, nullptr, 1024, 8);
  k_reduceN<0, 0, 0, 1, 2><<<dim3(4096), tb, 0, stream>>>(
      pa0, pa1, nullptr, nullptr, bqX, nullptr, nullptr, nullptr, nullptr, Qx);
  k_gemm<0, 0, 1024><<<dim3(512, 1, 1), tb, 0, stream>>>(
      encb, 1024, WkvXT, 1024, bkvX, Kenc, 1024, Vt,
      nullptr, nullptr, nullptr, nullptr, 1024, 16);
  k_attn<0><<<dim3(8, 64), tb, 0, stream>>>(Qx, 1024, Kenc, 1024, Vt, Z);
  k_gemm<1, 0, 0><<<dim3(256, 1, 2), tb, 0, stream>>>(
      Z, 1024, WoT, 1024, nullptr, nullptr, 1024, nullptr,
      pa0, pa1, nullptr, nullptr, 1024, 8);
  k_reduceN<1, 1, 1, 1, 2><<<dim3(4096), tb, 0, stream>>>(
      pa0, pa1, nullptr, nullptr, bo, x1f, g2, be2, x1f, x1b);

  // ---- phase 3: FFN ----
  k_gemm256<0, 1, 0><<<dim3(256, 1, 1), tb512, 0, stream>>>(
      x1b, 1024, W1T, 1024, b1, Hbuf, 4096, nullptr,
      nullptr, nullptr, nullptr, nullptr, 1024, 16);
  k_gemm256<1, 0, 0><<<dim3(64, 1, 4), tb512, 0, stream>>>(
      Hbuf, 4096, W2T, 4096, nullptr, nullptr, 1024, nullptr,
      pf0, pf1, pf2, pf3, 4096, 4);
  k_reduceN<1, 1, 1, 0, 4><<<dim3(4096), tb, 0, stream>>>(
      pf0, pf1, pf2, pf3, b2, x1f, g3, be3, (float*)d_out, nullptr);
}

// Round 7
// 548.091 us; speedup vs baseline: 1.0247x; 1.0084x over previous
//
#include <hip/hip_runtime.h>
#include <cstdint>

typedef __bf16 bf16_t;
typedef bf16_t bf16x8 __attribute__((ext_vector_type(8)));
typedef bf16_t bf16x4 __attribute__((ext_vector_type(4)));
typedef float  f32x4  __attribute__((ext_vector_type(4)));

#define DEVI static __device__ __forceinline__

DEVI void async_ld16(const bf16_t* g, bf16_t* l) {
  __builtin_amdgcn_global_load_lds((const __attribute__((address_space(1))) void*)g,
                                   (__attribute__((address_space(3))) void*)l, 16, 0, 0);
}

// ---------------------------------------------------------------------------
// Fused prep: all weight transposes + bf16 converts + bias packs, one dispatch.
// Round-7: transpose path vectorized — float4 loads (16B/lane) + bf16x4
// stores, single load/store pass (was 4x scalar-f32 passes). tile padded to
// [32][36] so &tile[r][c4] is 16B-aligned (36*4=144 ≡ 0 mod 16).
// ---------------------------------------------------------------------------
struct PrepArgs {
  const float *WqS, *WkS, *WvS, *WqX, *WkX, *WvX, *Wo, *W1, *W2, *x, *enc;
  const float *bqS, *bkS, *bvS, *bkX, *bvX;
  bf16_t *WqkvST, *WqXT, *WkvXT, *WoT, *W1T, *W2T, *xb, *encb;
  float *bqkv, *bkvx;
};

__global__ __launch_bounds__(256)
void k_prep(PrepArgs a)
{
  __shared__ float tile[32][36];
  const int blk = blockIdx.x, tid = threadIdx.x;

  const float* src = nullptr;
  bf16_t* dst = nullptr;
  int srcLd = 0, dstLd = 0, m0 = 0, n0 = 0;
  bool do_tr = false;

  if (blk < 6144) {
    int j = blk >> 10, q = blk & 1023;
    src = j == 0 ? a.WqS : j == 1 ? a.WkS : j == 2 ? a.WvS : j == 3 ? a.WqX : j == 4 ? a.WkX : a.WvX;
    dst = j == 0 ? a.WqkvST : j == 1 ? a.WqkvST + 1048576 : j == 2 ? a.WqkvST + 2097152
        : j == 3 ? a.WqXT : j == 4 ? a.WkvXT : a.WkvXT + 1048576;
    int batch = q >> 6, rem = q & 63;
    src += (long)batch * 65536; dst += (long)batch * 65536;
    srcLd = 64; dstLd = 1024;
    n0 = (rem & 1) * 32; m0 = (rem >> 1) * 32;
    do_tr = true;
  } else if (blk < 7168) {
    int q = blk - 6144;
    src = a.Wo; dst = a.WoT; srcLd = 1024; dstLd = 1024;
    m0 = (q >> 5) * 32; n0 = (q & 31) * 32; do_tr = true;
  } else if (blk < 11264) {
    int q = blk - 7168;
    src = a.W1; dst = a.W1T; srcLd = 4096; dstLd = 1024;
    m0 = (q >> 7) * 32; n0 = (q & 127) * 32; do_tr = true;
  } else if (blk < 15360) {
    int q = blk - 11264;
    src = a.W2; dst = a.W2T; srcLd = 1024; dstLd = 4096;
    m0 = (q >> 5) * 32; n0 = (q & 31) * 32; do_tr = true;
  } else if (blk < 16384) {
    long base = (long)(blk - 15360) * 4096 + tid * 4;
#pragma unroll
    for (int u = 0; u < 4; u++) {
      float4 v = *(const float4*)(a.x + base + u * 1024);
      bf16x4 o; o[0] = (bf16_t)v.x; o[1] = (bf16_t)v.y; o[2] = (bf16_t)v.z; o[3] = (bf16_t)v.w;
      *(bf16x4*)(a.xb + base + u * 1024) = o;
    }
    return;
  } else if (blk < 17408) {
    long base = (long)(blk - 16384) * 4096 + tid * 4;
#pragma unroll
    for (int u = 0; u < 4; u++) {
      float4 v = *(const float4*)(a.enc + base + u * 1024);
      bf16x4 o; o[0] = (bf16_t)v.x; o[1] = (bf16_t)v.y; o[2] = (bf16_t)v.z; o[3] = (bf16_t)v.w;
      *(bf16x4*)(a.encb + base + u * 1024) = o;
    }
    return;
  } else {
    int gi = (blk - 17408) * 1024 + tid * 4;
#pragma unroll
    for (int j = 0; j < 4; j++) {
      int i = gi + j;
      if (i < 1024)      a.bqkv[i] = a.bqS[i];
      else if (i < 2048) a.bqkv[i] = a.bkS[i - 1024];
      else if (i < 3072) a.bqkv[i] = a.bvS[i - 2048];
      else if (i < 4096) a.bkvx[i - 3072] = a.bkX[i - 3072];
      else if (i < 5120) a.bkvx[i - 3072] = a.bvX[i - 4096];
    }
    return;
  }

  if (do_tr) {
    // load pass: thread t reads float4 at row r=t>>3, cols c4=(t&7)*4
    {
      int r = tid >> 3, c4 = (tid & 7) * 4;
      *(float4*)&tile[r][c4] = *(const float4*)(src + (long)(m0 + r) * srcLd + n0 + c4);
    }
    __syncthreads();
    // store pass: thread t writes bf16x4 at out-row nr=t>>3, m-quad mq=(t&7)*4
    {
      int nr = tid >> 3, mq = (tid & 7) * 4;
      bf16x4 o;
      o[0] = (bf16_t)tile[mq + 0][nr];
      o[1] = (bf16_t)tile[mq + 1][nr];
      o[2] = (bf16_t)tile[mq + 2][nr];
      o[3] = (bf16_t)tile[mq + 3][nr];
      *(bf16x4*)(dst + (long)(n0 + nr) * dstLd + m0 + mq) = o;
    }
  }
}

// ---------------------------------------------------------------------------
// GEMM 128x128 tile, BK=32, 2-phase double-buffered global_load_lds.
// (Known-good core — do not re-pipeline (m131-m141); do not shrink tile
//  (64^2: 126us vs 77us); do NOT raise BK here (m132: occupancy 3->2 regress);
//  no setprio here: m190 measured it slightly negative on 4-wave 128^2.)
// ---------------------------------------------------------------------------
template<int OUT_MODE, int RELU, int VOFF>
__global__ __launch_bounds__(256, 2)
void k_gemm(const bf16_t* __restrict__ A, int lda,
            const bf16_t* __restrict__ Bt, int ldb,
            const float* __restrict__ bias,
            bf16_t* __restrict__ C, int ldc,
            bf16_t* __restrict__ Vt,
            bf16_t* __restrict__ p0, bf16_t* __restrict__ p1,
            bf16_t* __restrict__ p2, bf16_t* __restrict__ p3,
            int Ktot, int nx)
{
  __shared__ bf16_t As[2][128 * 32];
  __shared__ bf16_t Bs[2][128 * 32];
  const int tid  = threadIdx.x;
  const int wave = tid >> 6, lane = tid & 63;
  const int quad = lane >> 4, m16 = lane & 15;

  int lin = blockIdx.x;
  int perx = gridDim.x >> 3;
  int t = (lin & 7) * perx + (lin >> 3);
  const int bcol = (t % nx) * 128, brow = (t / nx) * 128;
  const int wr = (wave >> 1) * 64, wc = (wave & 1) * 64;

  const int Kper = Ktot / gridDim.z;
  const int k0 = blockIdx.z * Kper;

  f32x4 acc[4][4];
#pragma unroll
  for (int i = 0; i < 4; i++)
#pragma unroll
    for (int j = 0; j < 4; j++) acc[i][j] = (f32x4){0.f, 0.f, 0.f, 0.f};

  auto stage = [&](int kt, int buf) {
#pragma unroll
    for (int i = 0; i < 2; i++) {
      int rg = wave * 2 + i;
      async_ld16(A  + (long)(brow + rg * 16 + m16) * lda + kt + quad * 8, As[buf] + rg * 512);
      async_ld16(Bt + (long)(bcol + rg * 16 + m16) * ldb + kt + quad * 8, Bs[buf] + rg * 512);
    }
  };

  stage(k0, 0);
  __syncthreads();

  const int nIter = Kper >> 5;
  for (int it = 0; it < nIter; it++) {
    const int cur = it & 1;
    if (it + 1 < nIter) stage(k0 + (it + 1) * 32, cur ^ 1);

    bf16x8 af[4], bfr[4];
#pragma unroll
    for (int tt = 0; tt < 4; tt++) {
      af[tt]  = *(const bf16x8*)(As[cur] + ((wr + tt * 16) >> 4) * 512 + quad * 128 + m16 * 8);
      bfr[tt] = *(const bf16x8*)(Bs[cur] + ((wc + tt * 16) >> 4) * 512 + quad * 128 + m16 * 8);
    }
#pragma unroll
    for (int i = 0; i < 4; i++)
#pragma unroll
      for (int j = 0; j < 4; j++)
        acc[i][j] = __builtin_amdgcn_mfma_f32_16x16x32_bf16(af[i], bfr[j], acc[i][j], 0, 0, 0);

    __syncthreads();
  }

  if (OUT_MODE == 1) {
    bf16_t* P = blockIdx.z == 0 ? p0 : blockIdx.z == 1 ? p1 : blockIdx.z == 2 ? p2 : p3;
#pragma unroll
    for (int i = 0; i < 4; i++)
#pragma unroll
      for (int j = 0; j < 4; j++) {
        int col = bcol + wc + j * 16 + m16;
#pragma unroll
        for (int r = 0; r < 4; r++) {
          int row = brow + wr + i * 16 + quad * 4 + r;
          P[(long)row * ldc + col] = (bf16_t)acc[i][j][r];
        }
      }
  } else {
#pragma unroll
    for (int i = 0; i < 4; i++)
#pragma unroll
      for (int j = 0; j < 4; j++) {
        int col = bcol + wc + j * 16 + m16;
        float bv = bias[col];
        if (VOFF && col >= VOFF) {
          int hh = (col - VOFF) >> 6, dd = col & 63;
          int row0 = brow + wr + i * 16 + quad * 4;
          int bb = row0 >> 10, seq = row0 & 1023;
          bf16x4 pk;
#pragma unroll
          for (int r = 0; r < 4; r++) pk[r] = (bf16_t)(acc[i][j][r] + bv);
          *(bf16x4*)(Vt + (long)(bb * 16 + hh) * 65536 + dd * 1024 + seq) = pk;
        } else {
#pragma unroll
          for (int r = 0; r < 4; r++) {
            int row = brow + wr + i * 16 + quad * 4 + r;
            float v = acc[i][j][r] + bv;
            if (RELU) v = v > 0.f ? v : 0.f;
            C[(long)row * ldc + col] = (bf16_t)v;
          }
        }
      }
  }
}

// ---------------------------------------------------------------------------
// GEMM 256x256 tile, BK=64, 2-phase double-buffer (m230-V0 / T3-minimal
// structure). Round-6: BK 32->64 = +3% (62.5->60.8us). Per-iter model:
// MFMA ~2.5k cy + LDS-read ~1.5k + stage-arrival ~2k, largely serialized at
// 1 blk/CU — the fine 8-phase interleave would overlap them but its exact
// race-free slot schedule is not reconstructible from docs (m152 risk);
// not attempted headlessly. Round-7: + T5 setprio tightly around each
// 32-MFMA ks-cluster (T3 recipe includes it; 8 waves stagger between
// barriers -> role diversity, unlike m190's 4-wave null). No lgkmcnt
// pinning (m141: over-pinning regresses). (512,2): VGPR cap 256 — (512,4)
// spilled acc (round-3). LDS 128KB -> 1 blk/CU. Used for FFN1 + FFN2 only.
// ---------------------------------------------------------------------------
template<int OUT_MODE, int RELU, int VOFF>
__global__ __launch_bounds__(512, 2)
void k_gemm256(const bf16_t* __restrict__ A, int lda,
               const bf16_t* __restrict__ Bt, int ldb,
               const float* __restrict__ bias,
               bf16_t* __restrict__ C, int ldc,
               bf16_t* __restrict__ Vt,
               bf16_t* __restrict__ p0, bf16_t* __restrict__ p1,
               bf16_t* __restrict__ p2, bf16_t* __restrict__ p3,
               int Ktot, int nx)
{
  __shared__ bf16_t As[2][256 * 64];
  __shared__ bf16_t Bs[2][256 * 64];
  const int tid  = threadIdx.x;
  const int wave = tid >> 6, lane = tid & 63;
  const int quad = lane >> 4, m16 = lane & 15;

  int lin = blockIdx.x;
  int perx = gridDim.x >> 3;
  int t = (lin & 7) * perx + (lin >> 3);
  const int bcol = (t % nx) * 256, brow = (t / nx) * 256;
  const int wr = (wave >> 2) * 128, wc = (wave & 3) * 64;

  const int Kper = Ktot / gridDim.z;
  const int k0 = blockIdx.z * Kper;

  f32x4 acc[8][4];
#pragma unroll
  for (int i = 0; i < 8; i++)
#pragma unroll
    for (int j = 0; j < 4; j++) acc[i][j] = (f32x4){0.f, 0.f, 0.f, 0.f};

  // wave w stages row-groups {2w, 2w+1} of A and B, both 32-K halves:
  // 8 async 16B loads per wave per K-tile (64 KB/tile total).
  auto stage = [&](int kt, int buf) {
#pragma unroll
    for (int i = 0; i < 2; i++) {
      int rg = wave * 2 + i;
#pragma unroll
      for (int ks = 0; ks < 2; ks++) {
        async_ld16(A  + (long)(brow + rg * 16 + m16) * lda + kt + ks * 32 + quad * 8,
                   As[buf] + (rg * 2 + ks) * 512);
        async_ld16(Bt + (long)(bcol + rg * 16 + m16) * ldb + kt + ks * 32 + quad * 8,
                   Bs[buf] + (rg * 2 + ks) * 512);
      }
    }
  };

  stage(k0, 0);
  __syncthreads();

  const int nIter = Kper >> 6;
  for (int it = 0; it < nIter; it++) {
    const int cur = it & 1;
    if (it + 1 < nIter) stage(k0 + (it + 1) * 64, cur ^ 1);

    const bf16_t* Ac = As[cur];
    const bf16_t* Bc = Bs[cur];
#pragma unroll
    for (int ks = 0; ks < 2; ks++) {
      bf16x8 af[8], bfr[4];
#pragma unroll
      for (int tt = 0; tt < 8; tt++)
        af[tt] = *(const bf16x8*)(Ac + (((wr + tt * 16) >> 4) * 2 + ks) * 512 + quad * 128 + m16 * 8);
#pragma unroll
      for (int j = 0; j < 4; j++)
        bfr[j] = *(const bf16x8*)(Bc + (((wc + j * 16) >> 4) * 2 + ks) * 512 + quad * 128 + m16 * 8);
      __builtin_amdgcn_s_setprio(1);
#pragma unroll
      for (int i = 0; i < 8; i++)
#pragma unroll
        for (int j = 0; j < 4; j++)
          acc[i][j] = __builtin_amdgcn_mfma_f32_16x16x32_bf16(af[i], bfr[j], acc[i][j], 0, 0, 0);
      __builtin_amdgcn_s_setprio(0);
    }

    __syncthreads();
  }

  if (OUT_MODE == 1) {
    bf16_t* P = blockIdx.z == 0 ? p0 : blockIdx.z == 1 ? p1 : blockIdx.z == 2 ? p2 : p3;
#pragma unroll
    for (int i = 0; i < 8; i++)
#pragma unroll
      for (int j = 0; j < 4; j++) {
        int col = bcol + wc + j * 16 + m16;
#pragma unroll
        for (int r = 0; r < 4; r++) {
          int row = brow + wr + i * 16 + quad * 4 + r;
          P[(long)row * ldc + col] = (bf16_t)acc[i][j][r];
        }
      }
  } else {
#pragma unroll
    for (int i = 0; i < 8; i++)
#pragma unroll
      for (int j = 0; j < 4; j++) {
        int col = bcol + wc + j * 16 + m16;
        float bv = bias[col];
        if (VOFF && col >= VOFF) {
          int hh = (col - VOFF) >> 6, dd = col & 63;
          int row0 = brow + wr + i * 16 + quad * 4;
          int bb = row0 >> 10, seq = row0 & 1023;
          bf16x4 pk;
#pragma unroll
          for (int r = 0; r < 4; r++) pk[r] = (bf16_t)(acc[i][j][r] + bv);
          *(bf16x4*)(Vt + (long)(bb * 16 + hh) * 65536 + dd * 1024 + seq) = pk;
        } else {
#pragma unroll
          for (int r = 0; r < 4; r++) {
            int row = brow + wr + i * 16 + quad * 4 + r;
            float v = acc[i][j][r] + bv;
            if (RELU) v = v > 0.f ? v : 0.f;
            C[(long)row * ldc + col] = (bf16_t)v;
          }
        }
      }
  }
}

// ---------------------------------------------------------------------------
// Split-K reduce (NPART partials) + bias (+resid) (+LayerNorm). 1 row/block.
// ---------------------------------------------------------------------------
template<int LN, int RESID, int OUTF, int OUTB, int NPART>
__global__ __launch_bounds__(256)
void k_reduceN(const bf16_t* __restrict__ p0, const bf16_t* __restrict__ p1,
               const bf16_t* __restrict__ p2, const bf16_t* __restrict__ p3,
               const float* __restrict__ bias, const float* __restrict__ resid,
               const float* __restrict__ gamma, const float* __restrict__ beta,
               float* __restrict__ outf, bf16_t* __restrict__ outb)
{
  constexpr int D = 1024;
  __shared__ float red[8];
  int row = blockIdx.x, tid = threadIdx.x;
  long off = (long)row * D + tid * 4;
  bf16x4 a0 = *(const bf16x4*)(p0 + off);
  bf16x4 a1 = *(const bf16x4*)(p1 + off);
  float4 bb4 = *(const float4*)(bias + tid * 4);
  float4 v;
  v.x = (float)a0[0] + (float)a1[0] + bb4.x;
  v.y = (float)a0[1] + (float)a1[1] + bb4.y;
  v.z = (float)a0[2] + (float)a1[2] + bb4.z;
  v.w = (float)a0[3] + (float)a1[3] + bb4.w;
  if (NPART == 4) {
    bf16x4 a2 = *(const bf16x4*)(p2 + off);
    bf16x4 a3 = *(const bf16x4*)(p3 + off);
    v.x += (float)a2[0] + (float)a3[0];
    v.y += (float)a2[1] + (float)a3[1];
    v.z += (float)a2[2] + (float)a3[2];
    v.w += (float)a2[3] + (float)a3[3];
  }
  if (RESID) {
    float4 q = *(const float4*)(resid + off);
    v.x += q.x; v.y += q.y; v.z += q.z; v.w += q.w;
  }
  float4 y = v;
  if (LN) {
    float s  = v.x + v.y + v.z + v.w;
    float sq = v.x * v.x + v.y * v.y + v.z * v.z + v.w * v.w;
#pragma unroll
    for (int o = 1; o < 64; o <<= 1) {
      s  += __shfl_xor(s, o, 64);
      sq += __shfl_xor(sq, o, 64);
    }
    int wave = tid >> 6, lane = tid & 63;
    if (lane == 0) { red[wave * 2] = s; red[wave * 2 + 1] = sq; }
    __syncthreads();
    float ts = red[0] + red[2] + red[4] + red[6];
    float tq = red[1] + red[3] + red[5] + red[7];
    float mu = ts * (1.f / D);
    float var = tq * (1.f / D) - mu * mu;
    float rstd = rsqrtf(var + 1e-5f);
    float4 g  = *(const float4*)(gamma + tid * 4);
    float4 be = *(const float4*)(beta + tid * 4);
    y.x = (v.x - mu) * rstd * g.x + be.x;
    y.y = (v.y - mu) * rstd * g.y + be.y;
    y.z = (v.z - mu) * rstd * g.z + be.z;
    y.w = (v.w - mu) * rstd * g.w + be.w;
  }
  if (OUTF) *(float4*)(outf + off) = y;
  if (OUTB) {
    bf16x4 o;
    o[0] = (bf16_t)y.x; o[1] = (bf16_t)y.y; o[2] = (bf16_t)y.z; o[3] = (bf16_t)y.w;
    *(bf16x4*)(outb + off) = o;
  }
}

// ---------------------------------------------------------------------------
// Flash attention (round-0 structure: LDS double-buffered KV staging — the
// L2-direct variant measured +60us, latency-bound). s_setprio around MFMA
// clusters kept (m191 regime).
// ---------------------------------------------------------------------------
template<int CAUSAL>
__global__ __launch_bounds__(256, 2)
void k_attn(const bf16_t* __restrict__ Q, int ldq,
            const bf16_t* __restrict__ Kp, int ldk,
            const bf16_t* __restrict__ Vt,
            bf16_t* __restrict__ O)
{
  constexpr int S = 1024;
  __shared__ bf16_t Kls[2][4096];
  __shared__ bf16_t Vls[2][4096];
  __shared__ bf16_t Pls[4][32 * 72];

  const int tid = threadIdx.x;
  const int wave = tid >> 6, lane = tid & 63;
  const int quad = lane >> 4, m16 = lane & 15;
  const int qt = blockIdx.x, bh = blockIdx.y, b = bh >> 4, h = bh & 15;
  const int qbase = qt * 128 + wave * 32;

  bf16x8 qf[2][2];
#pragma unroll
  for (int rh = 0; rh < 2; rh++) {
    const bf16_t* qp = Q + (long)(b * S + qbase + rh * 16 + m16) * ldq + h * 64 + quad * 8;
    qf[rh][0] = *(const bf16x8*)qp;
    qf[rh][1] = *(const bf16x8*)(qp + 32);
  }

  f32x4 o_acc[2][4];
#pragma unroll
  for (int rh = 0; rh < 2; rh++)
#pragma unroll
    for (int t = 0; t < 4; t++) o_acc[rh][t] = (f32x4){0.f, 0.f, 0.f, 0.f};
  float rsum[2][4];
#pragma unroll
  for (int rh = 0; rh < 2; rh++)
#pragma unroll
    for (int r = 0; r < 4; r++) rsum[rh][r] = 0.f;

  auto stage = [&](int c, int buf) {
#pragma unroll
    for (int i = 0; i < 2; i++) {
      int t2 = wave * 2 + i;
      int rg = t2 & 3, ph = t2 >> 2;
      async_ld16(Kp + (long)(b * S + c * 64 + rg * 16 + m16) * ldk + h * 64 + ph * 32 + quad * 8,
                 Kls[buf] + t2 * 512);
      async_ld16(Vt + (long)bh * 65536 + (rg * 16 + m16) * 1024 + c * 64 + ph * 32 + quad * 8,
                 Vls[buf] + t2 * 512);
    }
  };

  const int nch = CAUSAL ? (2 * qt + 2) : 16;
  stage(0, 0);

  for (int c = 0; c < nch; c++) {
    __syncthreads();
    const int cur = c & 1;
    if (c + 1 < nch) stage(c + 1, cur ^ 1);

    f32x4 s[2][4];
#pragma unroll
    for (int t = 0; t < 4; t++) {
      bf16x8 k0 = *(const bf16x8*)(Kls[cur] + (0 * 4 + t) * 512 + quad * 128 + m16 * 8);
      bf16x8 k1 = *(const bf16x8*)(Kls[cur] + (1 * 4 + t) * 512 + quad * 128 + m16 * 8);
      __builtin_amdgcn_s_setprio(1);
#pragma unroll
      for (int rh = 0; rh < 2; rh++) {
        f32x4 z = (f32x4){0.f, 0.f, 0.f, 0.f};
        z = __builtin_amdgcn_mfma_f32_16x16x32_bf16(qf[rh][0], k0, z, 0, 0, 0);
        z = __builtin_amdgcn_mfma_f32_16x16x32_bf16(qf[rh][1], k1, z, 0, 0, 0);
        s[rh][t] = z;
      }
      __builtin_amdgcn_s_setprio(0);
    }

    bf16_t* pw = Pls[wave];
#pragma unroll
    for (int rh = 0; rh < 2; rh++)
#pragma unroll
      for (int r = 0; r < 4; r++) {
        int qg = qbase + rh * 16 + quad * 4 + r;
#pragma unroll
        for (int t = 0; t < 4; t++) {
          float v = s[rh][t][r] * 0.125f;
          float p;
          if (CAUSAL) {
            int kvg = c * 64 + t * 16 + m16;
            p = (kvg <= qg) ? __expf(v) : 0.f;
          } else {
            p = __expf(v);
          }
          rsum[rh][r] += p;
          pw[(rh * 16 + quad * 4 + r) * 72 + t * 16 + m16] = (bf16_t)p;
        }
      }

    bf16x8 pf[2][2];
#pragma unroll
    for (int rh = 0; rh < 2; rh++)
#pragma unroll
      for (int kvh = 0; kvh < 2; kvh++)
        pf[rh][kvh] = *(const bf16x8*)(pw + (rh * 16 + m16) * 72 + kvh * 32 + quad * 8);
#pragma unroll
    for (int t = 0; t < 4; t++) {
      bf16x8 v0 = *(const bf16x8*)(Vls[cur] + (0 * 4 + t) * 512 + quad * 128 + m16 * 8);
      bf16x8 v1 = *(const bf16x8*)(Vls[cur] + (1 * 4 + t) * 512 + quad * 128 + m16 * 8);
      __builtin_amdgcn_s_setprio(1);
#pragma unroll
      for (int rh = 0; rh < 2; rh++) {
        o_acc[rh][t] = __builtin_amdgcn_mfma_f32_16x16x32_bf16(pf[rh][0], v0, o_acc[rh][t], 0, 0, 0);
        o_acc[rh][t] = __builtin_amdgcn_mfma_f32_16x16x32_bf16(pf[rh][1], v1, o_acc[rh][t], 0, 0, 0);
      }
      __builtin_amdgcn_s_setprio(0);
    }
  }

#pragma unroll
  for (int rh = 0; rh < 2; rh++)
#pragma unroll
    for (int r = 0; r < 4; r++) {
      float v = rsum[rh][r];
      v += __shfl_xor(v, 1, 64);
      v += __shfl_xor(v, 2, 64);
      v += __shfl_xor(v, 4, 64);
      v += __shfl_xor(v, 8, 64);
      rsum[rh][r] = 1.f / v;
    }
#pragma unroll
  for (int rh = 0; rh < 2; rh++)
#pragma unroll
    for (int t = 0; t < 4; t++)
#pragma unroll
      for (int r = 0; r < 4; r++) {
        int row = b * S + qbase + rh * 16 + quad * 4 + r;
        int col = h * 64 + t * 16 + m16;
        O[(long)row * 1024 + col] = (bf16_t)(o_acc[rh][t][r] * rsum[rh][r]);
      }
}

// ---------------------------------------------------------------------------
extern "C" void kernel_launch(void* const* d_in, const int* in_sizes, int n_in,
                              void* d_out, int out_size, void* d_ws, size_t ws_size,
                              hipStream_t stream)
{
  const float* x   = (const float*)d_in[0];
  const float* enc = (const float*)d_in[1];
  const float* WqS = (const float*)d_in[3];
  const float* bqS = (const float*)d_in[4];
  const float* WkS = (const float*)d_in[5];
  const float* bkS = (const float*)d_in[6];
  const float* WvS = (const float*)d_in[7];
  const float* bvS = (const float*)d_in[8];
  const float* WqX = (const float*)d_in[9];
  const float* bqX = (const float*)d_in[10];
  const float* WkX = (const float*)d_in[11];
  const float* bkX = (const float*)d_in[12];
  const float* WvX = (const float*)d_in[13];
  const float* bvX = (const float*)d_in[14];
  const float* Wo  = (const float*)d_in[15];
  const float* bo  = (const float*)d_in[16];
  const float* W1  = (const float*)d_in[17];
  const float* b1  = (const float*)d_in[18];
  const float* W2  = (const float*)d_in[19];
  const float* b2  = (const float*)d_in[20];
  const float* g1  = (const float*)d_in[21];
  const float* be1 = (const float*)d_in[22];
  const float* g2  = (const float*)d_in[23];
  const float* be2 = (const float*)d_in[24];
  const float* g3  = (const float*)d_in[25];
  const float* be3 = (const float*)d_in[26];

  char* ws = (char*)d_ws;
  const long MBy = 1048576;
  bf16_t* WqkvST = (bf16_t*)(ws + 0 * MBy);            // 6 MB
  bf16_t* WqXT   = (bf16_t*)(ws + 6 * MBy);            // 2 MB
  bf16_t* WkvXT  = (bf16_t*)(ws + 8 * MBy);            // 4 MB
  bf16_t* WoT    = (bf16_t*)(ws + 12 * MBy);           // 2 MB
  bf16_t* W1T    = (bf16_t*)(ws + 14 * MBy);           // 8 MB
  bf16_t* W2T    = (bf16_t*)(ws + 22 * MBy);           // 8 MB
  float*  bqkvS  = (float*)(ws + 30 * MBy);            // 12 KB
  float*  bkvX   = (float*)(ws + 30 * MBy + 16384);    // 8 KB
  bf16_t* xb     = (bf16_t*)(ws + 31 * MBy);           // 8 MB (P1) -> Qx (P2)
  bf16_t* Qx     = xb;
  bf16_t* encb   = (bf16_t*)(ws + 39 * MBy);           // 8 MB (until KVenc)
  float*  x1f    = (float*)(ws + 47 * MBy);            // 16 MB f32 (resid chain)
  bf16_t* x1b    = (bf16_t*)(ws + 63 * MBy);           // 8 MB (->x2b)
  bf16_t* Z      = (bf16_t*)(ws + 71 * MBy);           // 8 MB attn out
  bf16_t* QK     = (bf16_t*)(ws + 79 * MBy);           // 16 MB [4096][2048] (P1)
  bf16_t* Kenc   = (bf16_t*)(ws + 79 * MBy);           // 8 MB [4096][1024] (P2)
  bf16_t* Vt     = (bf16_t*)(ws + 95 * MBy);           // 8 MB [64][64][1024]
  // split-K partial arena: overlays Vt region when dead (z=2 -> only pa0/pa1)
  bf16_t* pa0 = (bf16_t*)(ws + 95 * MBy);
  bf16_t* pa1 = (bf16_t*)(ws + 103 * MBy);
  bf16_t* Hbuf = (bf16_t*)(ws + 95 * MBy);             // 32 MB (P3)
  // FFN2 partials over dead weight/input regions
  bf16_t* pf0 = (bf16_t*)(ws + 0 * MBy);
  bf16_t* pf1 = (bf16_t*)(ws + 8 * MBy);
  bf16_t* pf2 = (bf16_t*)(ws + 31 * MBy);
  bf16_t* pf3 = (bf16_t*)(ws + 39 * MBy);

  dim3 tb(256), tb512(512);

  // ---- fused prep (1 dispatch) ----
  PrepArgs pa;
  pa.WqS = WqS; pa.WkS = WkS; pa.WvS = WvS; pa.WqX = WqX; pa.WkX = WkX; pa.WvX = WvX;
  pa.Wo = Wo; pa.W1 = W1; pa.W2 = W2; pa.x = x; pa.enc = enc;
  pa.bqS = bqS; pa.bkS = bkS; pa.bvS = bvS; pa.bkX = bkX; pa.bvX = bvX;
  pa.WqkvST = WqkvST; pa.WqXT = WqXT; pa.WkvXT = WkvXT; pa.WoT = WoT;
  pa.W1T = W1T; pa.W2T = W2T; pa.xb = xb; pa.encb = encb;
  pa.bqkv = bqkvS; pa.bkvx = bkvX;
  k_prep<<<dim3(17413), tb, 0, stream>>>(pa);

  // ---- phase 1: self-attention ----
  k_gemm<0, 0, 2048><<<dim3(768, 1, 1), tb, 0, stream>>>(
      xb, 1024, WqkvST, 1024, bqkvS, QK, 2048, Vt,
      nullptr, nullptr, nullptr, nullptr, 1024, 24);
  k_attn<1><<<dim3(8, 64), tb, 0, stream>>>(QK, 2048, QK + 1024, 2048, Vt, Z);
  k_gemm<1, 0, 0><<<dim3(256, 1, 2), tb, 0, stream>>>(
      Z, 1024, WoT, 1024, nullptr, nullptr, 1024, nullptr,
      pa0, pa1, nullptr, nullptr, 1024, 8);
  k_reduceN<1, 1, 1, 1, 2><<<dim3(4096), tb, 0, stream>>>(
      pa0, pa1, nullptr, nullptr, bo, x, g1, be1, x1f, x1b);

  // ---- phase 2: cross-attention ----
  k_gemm<1, 0, 0><<<dim3(256, 1, 2), tb, 0, stream>>>(
      x1b, 1024, WqXT, 1024, nullptr, nullptr, 1024, nullptr,
      pa0, pa1, nullptr, nullptr, 1024, 8);
  k_reduceN<0, 0, 0, 1, 2><<<dim3(4096), tb, 0, stream>>>(
      pa0, pa1, nullptr, nullptr, bqX, nullptr, nullptr, nullptr, nullptr, Qx);
  k_gemm<0, 0, 1024><<<dim3(512, 1, 1), tb, 0, stream>>>(
      encb, 1024, WkvXT, 1024, bkvX, Kenc, 1024, Vt,
      nullptr, nullptr, nullptr, nullptr, 1024, 16);
  k_attn<0><<<dim3(8, 64), tb, 0, stream>>>(Qx, 1024, Kenc, 1024, Vt, Z);
  k_gemm<1, 0, 0><<<dim3(256, 1, 2), tb, 0, stream>>>(
      Z, 1024, WoT, 1024, nullptr, nullptr, 1024, nullptr,
      pa0, pa1, nullptr, nullptr, 1024, 8);
  k_reduceN<1, 1, 1, 1, 2><<<dim3(4096), tb, 0, stream>>>(
      pa0, pa1, nullptr, nullptr, bo, x1f, g2, be2, x1f, x1b);

  // ---- phase 3: FFN ----
  k_gemm256<0, 1, 0><<<dim3(256, 1, 1), tb512, 0, stream>>>(
      x1b, 1024, W1T, 1024, b1, Hbuf, 4096, nullptr,
      nullptr, nullptr, nullptr, nullptr, 1024, 16);
  k_gemm256<1, 0, 0><<<dim3(64, 1, 4), tb512, 0, stream>>>(
      Hbuf, 4096, W2T, 4096, nullptr, nullptr, 1024, nullptr,
      pf0, pf1, pf2, pf3, 4096, 4);
  k_reduceN<1, 1, 1, 0, 4><<<dim3(4096), tb, 0, stream>>>(
      pf0, pf1, pf2, pf3, b2, x1f, g3, be3, (float*)d_out, nullptr);
}

// Round 8
// 546.110 us; speedup vs baseline: 1.0284x; 1.0036x over previous
//
#include <hip/hip_runtime.h>
#include <cstdint>

typedef __bf16 bf16_t;
typedef bf16_t bf16x8 __attribute__((ext_vector_type(8)));
typedef bf16_t bf16x4 __attribute__((ext_vector_type(4)));
typedef float  f32x4  __attribute__((ext_vector_type(4)));

#define DEVI static __device__ __forceinline__

DEVI void async_ld16(const bf16_t* g, bf16_t* l) {
  __builtin_amdgcn_global_load_lds((const __attribute__((address_space(1))) void*)g,
                                   (__attribute__((address_space(3))) void*)l, 16, 0, 0);
}

// ---------------------------------------------------------------------------
// Fused prep: all weight transposes + bf16 converts + bias packs, one dispatch.
// Transpose path vectorized (round-7): float4 loads + bf16x4 stores, single
// pass each; tile [32][36] keeps 16B alignment.
// ---------------------------------------------------------------------------
struct PrepArgs {
  const float *WqS, *WkS, *WvS, *WqX, *WkX, *WvX, *Wo, *W1, *W2, *x, *enc;
  const float *bqS, *bkS, *bvS, *bkX, *bvX;
  bf16_t *WqkvST, *WqXT, *WkvXT, *WoT, *W1T, *W2T, *xb, *encb;
  float *bqkv, *bkvx;
};

__global__ __launch_bounds__(256)
void k_prep(PrepArgs a)
{
  __shared__ float tile[32][36];
  const int blk = blockIdx.x, tid = threadIdx.x;

  const float* src = nullptr;
  bf16_t* dst = nullptr;
  int srcLd = 0, dstLd = 0, m0 = 0, n0 = 0;
  bool do_tr = false;

  if (blk < 6144) {
    int j = blk >> 10, q = blk & 1023;
    src = j == 0 ? a.WqS : j == 1 ? a.WkS : j == 2 ? a.WvS : j == 3 ? a.WqX : j == 4 ? a.WkX : a.WvX;
    dst = j == 0 ? a.WqkvST : j == 1 ? a.WqkvST + 1048576 : j == 2 ? a.WqkvST + 2097152
        : j == 3 ? a.WqXT : j == 4 ? a.WkvXT : a.WkvXT + 1048576;
    int batch = q >> 6, rem = q & 63;
    src += (long)batch * 65536; dst += (long)batch * 65536;
    srcLd = 64; dstLd = 1024;
    n0 = (rem & 1) * 32; m0 = (rem >> 1) * 32;
    do_tr = true;
  } else if (blk < 7168) {
    int q = blk - 6144;
    src = a.Wo; dst = a.WoT; srcLd = 1024; dstLd = 1024;
    m0 = (q >> 5) * 32; n0 = (q & 31) * 32; do_tr = true;
  } else if (blk < 11264) {
    int q = blk - 7168;
    src = a.W1; dst = a.W1T; srcLd = 4096; dstLd = 1024;
    m0 = (q >> 7) * 32; n0 = (q & 127) * 32; do_tr = true;
  } else if (blk < 15360) {
    int q = blk - 11264;
    src = a.W2; dst = a.W2T; srcLd = 1024; dstLd = 4096;
    m0 = (q >> 5) * 32; n0 = (q & 31) * 32; do_tr = true;
  } else if (blk < 16384) {
    long base = (long)(blk - 15360) * 4096 + tid * 4;
#pragma unroll
    for (int u = 0; u < 4; u++) {
      float4 v = *(const float4*)(a.x + base + u * 1024);
      bf16x4 o; o[0] = (bf16_t)v.x; o[1] = (bf16_t)v.y; o[2] = (bf16_t)v.z; o[3] = (bf16_t)v.w;
      *(bf16x4*)(a.xb + base + u * 1024) = o;
    }
    return;
  } else if (blk < 17408) {
    long base = (long)(blk - 16384) * 4096 + tid * 4;
#pragma unroll
    for (int u = 0; u < 4; u++) {
      float4 v = *(const float4*)(a.enc + base + u * 1024);
      bf16x4 o; o[0] = (bf16_t)v.x; o[1] = (bf16_t)v.y; o[2] = (bf16_t)v.z; o[3] = (bf16_t)v.w;
      *(bf16x4*)(a.encb + base + u * 1024) = o;
    }
    return;
  } else {
    int gi = (blk - 17408) * 1024 + tid * 4;
#pragma unroll
    for (int j = 0; j < 4; j++) {
      int i = gi + j;
      if (i < 1024)      a.bqkv[i] = a.bqS[i];
      else if (i < 2048) a.bqkv[i] = a.bkS[i - 1024];
      else if (i < 3072) a.bqkv[i] = a.bvS[i - 2048];
      else if (i < 4096) a.bkvx[i - 3072] = a.bkX[i - 3072];
      else if (i < 5120) a.bkvx[i - 3072] = a.bvX[i - 4096];
    }
    return;
  }

  if (do_tr) {
    {
      int r = tid >> 3, c4 = (tid & 7) * 4;
      *(float4*)&tile[r][c4] = *(const float4*)(src + (long)(m0 + r) * srcLd + n0 + c4);
    }
    __syncthreads();
    {
      int nr = tid >> 3, mq = (tid & 7) * 4;
      bf16x4 o;
      o[0] = (bf16_t)tile[mq + 0][nr];
      o[1] = (bf16_t)tile[mq + 1][nr];
      o[2] = (bf16_t)tile[mq + 2][nr];
      o[3] = (bf16_t)tile[mq + 3][nr];
      *(bf16x4*)(dst + (long)(n0 + nr) * dstLd + m0 + mq) = o;
    }
  }
}

// ---------------------------------------------------------------------------
// GEMM 128x128 tile, BK=32, 2-phase double-buffered global_load_lds.
// (Known-good core — do not re-pipeline (m131-m141); do not shrink tile;
//  do NOT raise BK here (m132); no setprio (m190 null on 4-wave lockstep).)
// ---------------------------------------------------------------------------
template<int OUT_MODE, int RELU, int VOFF>
__global__ __launch_bounds__(256, 2)
void k_gemm(const bf16_t* __restrict__ A, int lda,
            const bf16_t* __restrict__ Bt, int ldb,
            const float* __restrict__ bias,
            bf16_t* __restrict__ C, int ldc,
            bf16_t* __restrict__ Vt,
            bf16_t* __restrict__ p0, bf16_t* __restrict__ p1,
            bf16_t* __restrict__ p2, bf16_t* __restrict__ p3,
            int Ktot, int nx)
{
  __shared__ bf16_t As[2][128 * 32];
  __shared__ bf16_t Bs[2][128 * 32];
  const int tid  = threadIdx.x;
  const int wave = tid >> 6, lane = tid & 63;
  const int quad = lane >> 4, m16 = lane & 15;

  int lin = blockIdx.x;
  int perx = gridDim.x >> 3;
  int t = (lin & 7) * perx + (lin >> 3);
  const int bcol = (t % nx) * 128, brow = (t / nx) * 128;
  const int wr = (wave >> 1) * 64, wc = (wave & 1) * 64;

  const int Kper = Ktot / gridDim.z;
  const int k0 = blockIdx.z * Kper;

  f32x4 acc[4][4];
#pragma unroll
  for (int i = 0; i < 4; i++)
#pragma unroll
    for (int j = 0; j < 4; j++) acc[i][j] = (f32x4){0.f, 0.f, 0.f, 0.f};

  auto stage = [&](int kt, int buf) {
#pragma unroll
    for (int i = 0; i < 2; i++) {
      int rg = wave * 2 + i;
      async_ld16(A  + (long)(brow + rg * 16 + m16) * lda + kt + quad * 8, As[buf] + rg * 512);
      async_ld16(Bt + (long)(bcol + rg * 16 + m16) * ldb + kt + quad * 8, Bs[buf] + rg * 512);
    }
  };

  stage(k0, 0);
  __syncthreads();

  const int nIter = Kper >> 5;
  for (int it = 0; it < nIter; it++) {
    const int cur = it & 1;
    if (it + 1 < nIter) stage(k0 + (it + 1) * 32, cur ^ 1);

    bf16x8 af[4], bfr[4];
#pragma unroll
    for (int tt = 0; tt < 4; tt++) {
      af[tt]  = *(const bf16x8*)(As[cur] + ((wr + tt * 16) >> 4) * 512 + quad * 128 + m16 * 8);
      bfr[tt] = *(const bf16x8*)(Bs[cur] + ((wc + tt * 16) >> 4) * 512 + quad * 128 + m16 * 8);
    }
#pragma unroll
    for (int i = 0; i < 4; i++)
#pragma unroll
      for (int j = 0; j < 4; j++)
        acc[i][j] = __builtin_amdgcn_mfma_f32_16x16x32_bf16(af[i], bfr[j], acc[i][j], 0, 0, 0);

    __syncthreads();
  }

  if (OUT_MODE == 1) {
    bf16_t* P = blockIdx.z == 0 ? p0 : blockIdx.z == 1 ? p1 : blockIdx.z == 2 ? p2 : p3;
#pragma unroll
    for (int i = 0; i < 4; i++)
#pragma unroll
      for (int j = 0; j < 4; j++) {
        int col = bcol + wc + j * 16 + m16;
#pragma unroll
        for (int r = 0; r < 4; r++) {
          int row = brow + wr + i * 16 + quad * 4 + r;
          P[(long)row * ldc + col] = (bf16_t)acc[i][j][r];
        }
      }
  } else {
#pragma unroll
    for (int i = 0; i < 4; i++)
#pragma unroll
      for (int j = 0; j < 4; j++) {
        int col = bcol + wc + j * 16 + m16;
        float bv = bias[col];
        if (VOFF && col >= VOFF) {
          int hh = (col - VOFF) >> 6, dd = col & 63;
          int row0 = brow + wr + i * 16 + quad * 4;
          int bb = row0 >> 10, seq = row0 & 1023;
          bf16x4 pk;
#pragma unroll
          for (int r = 0; r < 4; r++) pk[r] = (bf16_t)(acc[i][j][r] + bv);
          *(bf16x4*)(Vt + (long)(bb * 16 + hh) * 65536 + dd * 1024 + seq) = pk;
        } else {
#pragma unroll
          for (int r = 0; r < 4; r++) {
            int row = brow + wr + i * 16 + quad * 4 + r;
            float v = acc[i][j][r] + bv;
            if (RELU) v = v > 0.f ? v : 0.f;
            C[(long)row * ldc + col] = (bf16_t)v;
          }
        }
      }
  }
}

// ---------------------------------------------------------------------------
// GEMM 256x256 tile, BK=64, 2-phase double-buffer. 567 TF ≈ 93% of the
// 2-phase structural ceiling (m233: 607); the fine 8-phase interleave is the
// only remaining lever and is not reconstructible race-free from docs (m152)
// — frozen. setprio kept (null, harmless). (512,2): VGPR cap 256 ((512,4)
// spilled, round-3). LDS 128KB -> 1 blk/CU. Used for FFN1 + FFN2 only.
// ---------------------------------------------------------------------------
template<int OUT_MODE, int RELU, int VOFF>
__global__ __launch_bounds__(512, 2)
void k_gemm256(const bf16_t* __restrict__ A, int lda,
               const bf16_t* __restrict__ Bt, int ldb,
               const float* __restrict__ bias,
               bf16_t* __restrict__ C, int ldc,
               bf16_t* __restrict__ Vt,
               bf16_t* __restrict__ p0, bf16_t* __restrict__ p1,
               bf16_t* __restrict__ p2, bf16_t* __restrict__ p3,
               int Ktot, int nx)
{
  __shared__ bf16_t As[2][256 * 64];
  __shared__ bf16_t Bs[2][256 * 64];
  const int tid  = threadIdx.x;
  const int wave = tid >> 6, lane = tid & 63;
  const int quad = lane >> 4, m16 = lane & 15;

  int lin = blockIdx.x;
  int perx = gridDim.x >> 3;
  int t = (lin & 7) * perx + (lin >> 3);
  const int bcol = (t % nx) * 256, brow = (t / nx) * 256;
  const int wr = (wave >> 2) * 128, wc = (wave & 3) * 64;

  const int Kper = Ktot / gridDim.z;
  const int k0 = blockIdx.z * Kper;

  f32x4 acc[8][4];
#pragma unroll
  for (int i = 0; i < 8; i++)
#pragma unroll
    for (int j = 0; j < 4; j++) acc[i][j] = (f32x4){0.f, 0.f, 0.f, 0.f};

  auto stage = [&](int kt, int buf) {
#pragma unroll
    for (int i = 0; i < 2; i++) {
      int rg = wave * 2 + i;
#pragma unroll
      for (int ks = 0; ks < 2; ks++) {
        async_ld16(A  + (long)(brow + rg * 16 + m16) * lda + kt + ks * 32 + quad * 8,
                   As[buf] + (rg * 2 + ks) * 512);
        async_ld16(Bt + (long)(bcol + rg * 16 + m16) * ldb + kt + ks * 32 + quad * 8,
                   Bs[buf] + (rg * 2 + ks) * 512);
      }
    }
  };

  stage(k0, 0);
  __syncthreads();

  const int nIter = Kper >> 6;
  for (int it = 0; it < nIter; it++) {
    const int cur = it & 1;
    if (it + 1 < nIter) stage(k0 + (it + 1) * 64, cur ^ 1);

    const bf16_t* Ac = As[cur];
    const bf16_t* Bc = Bs[cur];
#pragma unroll
    for (int ks = 0; ks < 2; ks++) {
      bf16x8 af[8], bfr[4];
#pragma unroll
      for (int tt = 0; tt < 8; tt++)
        af[tt] = *(const bf16x8*)(Ac + (((wr + tt * 16) >> 4) * 2 + ks) * 512 + quad * 128 + m16 * 8);
#pragma unroll
      for (int j = 0; j < 4; j++)
        bfr[j] = *(const bf16x8*)(Bc + (((wc + j * 16) >> 4) * 2 + ks) * 512 + quad * 128 + m16 * 8);
      __builtin_amdgcn_s_setprio(1);
#pragma unroll
      for (int i = 0; i < 8; i++)
#pragma unroll
        for (int j = 0; j < 4; j++)
          acc[i][j] = __builtin_amdgcn_mfma_f32_16x16x32_bf16(af[i], bfr[j], acc[i][j], 0, 0, 0);
      __builtin_amdgcn_s_setprio(0);
    }

    __syncthreads();
  }

  if (OUT_MODE == 1) {
    bf16_t* P = blockIdx.z == 0 ? p0 : blockIdx.z == 1 ? p1 : blockIdx.z == 2 ? p2 : p3;
#pragma unroll
    for (int i = 0; i < 8; i++)
#pragma unroll
      for (int j = 0; j < 4; j++) {
        int col = bcol + wc + j * 16 + m16;
#pragma unroll
        for (int r = 0; r < 4; r++) {
          int row = brow + wr + i * 16 + quad * 4 + r;
          P[(long)row * ldc + col] = (bf16_t)acc[i][j][r];
        }
      }
  } else {
#pragma unroll
    for (int i = 0; i < 8; i++)
#pragma unroll
      for (int j = 0; j < 4; j++) {
        int col = bcol + wc + j * 16 + m16;
        float bv = bias[col];
        if (VOFF && col >= VOFF) {
          int hh = (col - VOFF) >> 6, dd = col & 63;
          int row0 = brow + wr + i * 16 + quad * 4;
          int bb = row0 >> 10, seq = row0 & 1023;
          bf16x4 pk;
#pragma unroll
          for (int r = 0; r < 4; r++) pk[r] = (bf16_t)(acc[i][j][r] + bv);
          *(bf16x4*)(Vt + (long)(bb * 16 + hh) * 65536 + dd * 1024 + seq) = pk;
        } else {
#pragma unroll
          for (int r = 0; r < 4; r++) {
            int row = brow + wr + i * 16 + quad * 4 + r;
            float v = acc[i][j][r] + bv;
            if (RELU) v = v > 0.f ? v : 0.f;
            C[(long)row * ldc + col] = (bf16_t)v;
          }
        }
      }
  }
}

// ---------------------------------------------------------------------------
// Split-K reduce (NPART partials) + bias (+resid) (+LayerNorm). 1 row/block.
// ---------------------------------------------------------------------------
template<int LN, int RESID, int OUTF, int OUTB, int NPART>
__global__ __launch_bounds__(256)
void k_reduceN(const bf16_t* __restrict__ p0, const bf16_t* __restrict__ p1,
               const bf16_t* __restrict__ p2, const bf16_t* __restrict__ p3,
               const float* __restrict__ bias, const float* __restrict__ resid,
               const float* __restrict__ gamma, const float* __restrict__ beta,
               float* __restrict__ outf, bf16_t* __restrict__ outb)
{
  constexpr int D = 1024;
  __shared__ float red[8];
  int row = blockIdx.x, tid = threadIdx.x;
  long off = (long)row * D + tid * 4;
  bf16x4 a0 = *(const bf16x4*)(p0 + off);
  bf16x4 a1 = *(const bf16x4*)(p1 + off);
  float4 bb4 = *(const float4*)(bias + tid * 4);
  float4 v;
  v.x = (float)a0[0] + (float)a1[0] + bb4.x;
  v.y = (float)a0[1] + (float)a1[1] + bb4.y;
  v.z = (float)a0[2] + (float)a1[2] + bb4.z;
  v.w = (float)a0[3] + (float)a1[3] + bb4.w;
  if (NPART == 4) {
    bf16x4 a2 = *(const bf16x4*)(p2 + off);
    bf16x4 a3 = *(const bf16x4*)(p3 + off);
    v.x += (float)a2[0] + (float)a3[0];
    v.y += (float)a2[1] + (float)a3[1];
    v.z += (float)a2[2] + (float)a3[2];
    v.w += (float)a2[3] + (float)a3[3];
  }
  if (RESID) {
    float4 q = *(const float4*)(resid + off);
    v.x += q.x; v.y += q.y; v.z += q.z; v.w += q.w;
  }
  float4 y = v;
  if (LN) {
    float s  = v.x + v.y + v.z + v.w;
    float sq = v.x * v.x + v.y * v.y + v.z * v.z + v.w * v.w;
#pragma unroll
    for (int o = 1; o < 64; o <<= 1) {
      s  += __shfl_xor(s, o, 64);
      sq += __shfl_xor(sq, o, 64);
    }
    int wave = tid >> 6, lane = tid & 63;
    if (lane == 0) { red[wave * 2] = s; red[wave * 2 + 1] = sq; }
    __syncthreads();
    float ts = red[0] + red[2] + red[4] + red[6];
    float tq = red[1] + red[3] + red[5] + red[7];
    float mu = ts * (1.f / D);
    float var = tq * (1.f / D) - mu * mu;
    float rstd = rsqrtf(var + 1e-5f);
    float4 g  = *(const float4*)(gamma + tid * 4);
    float4 be = *(const float4*)(beta + tid * 4);
    y.x = (v.x - mu) * rstd * g.x + be.x;
    y.y = (v.y - mu) * rstd * g.y + be.y;
    y.z = (v.z - mu) * rstd * g.z + be.z;
    y.w = (v.w - mu) * rstd * g.w + be.w;
  }
  if (OUTF) *(float4*)(outf + off) = y;
  if (OUTB) {
    bf16x4 o;
    o[0] = (bf16_t)y.x; o[1] = (bf16_t)y.y; o[2] = (bf16_t)y.z; o[3] = (bf16_t)y.w;
    *(bf16x4*)(outb + off) = o;
  }
}

// ---------------------------------------------------------------------------
// Flash attention. Round-8: CAUSAL LOAD-BALANCE SWIZZLE. Grid (8,64) = 512
// blocks at 2/CU; chunk count = 2*qt+2 in {2..16}. Under linear round-robin
// dispatch, block i and i+256 share a CU, and 256 = 8*32 => SAME qt: the 64
// qt=7 CUs carry 32 chunk-units while qt=0 CUs idle after 4 (makespan
// ~16/9 of balanced). Remap qt -> 7-qt for bh>=32: every CU's resident pair
// then sums to 18 chunk-units. Perf-only index bijection (each (qt,bh)
// computed exactly once); robust even if the assignment model is wrong —
// same-qt pairing is the worst case, any decorrelation is >= current.
// ---------------------------------------------------------------------------
template<int CAUSAL>
__global__ __launch_bounds__(256, 2)
void k_attn(const bf16_t* __restrict__ Q, int ldq,
            const bf16_t* __restrict__ Kp, int ldk,
            const bf16_t* __restrict__ Vt,
            bf16_t* __restrict__ O)
{
  constexpr int S = 1024;
  __shared__ bf16_t Kls[2][4096];
  __shared__ bf16_t Vls[2][4096];
  __shared__ bf16_t Pls[4][32 * 72];

  const int tid = threadIdx.x;
  const int wave = tid >> 6, lane = tid & 63;
  const int quad = lane >> 4, m16 = lane & 15;
  const int bh = blockIdx.y, b = bh >> 4, h = bh & 15;
  const int qt = (CAUSAL && (bh & 32)) ? ((int)gridDim.x - 1 - (int)blockIdx.x)
                                       : (int)blockIdx.x;
  const int qbase = qt * 128 + wave * 32;

  bf16x8 qf[2][2];
#pragma unroll
  for (int rh = 0; rh < 2; rh++) {
    const bf16_t* qp = Q + (long)(b * S + qbase + rh * 16 + m16) * ldq + h * 64 + quad * 8;
    qf[rh][0] = *(const bf16x8*)qp;
    qf[rh][1] = *(const bf16x8*)(qp + 32);
  }

  f32x4 o_acc[2][4];
#pragma unroll
  for (int rh = 0; rh < 2; rh++)
#pragma unroll
    for (int t = 0; t < 4; t++) o_acc[rh][t] = (f32x4){0.f, 0.f, 0.f, 0.f};
  float rsum[2][4];
#pragma unroll
  for (int rh = 0; rh < 2; rh++)
#pragma unroll
    for (int r = 0; r < 4; r++) rsum[rh][r] = 0.f;

  auto stage = [&](int c, int buf) {
#pragma unroll
    for (int i = 0; i < 2; i++) {
      int t2 = wave * 2 + i;
      int rg = t2 & 3, ph = t2 >> 2;
      async_ld16(Kp + (long)(b * S + c * 64 + rg * 16 + m16) * ldk + h * 64 + ph * 32 + quad * 8,
                 Kls[buf] + t2 * 512);
      async_ld16(Vt + (long)bh * 65536 + (rg * 16 + m16) * 1024 + c * 64 + ph * 32 + quad * 8,
                 Vls[buf] + t2 * 512);
    }
  };

  const int nch = CAUSAL ? (2 * qt + 2) : 16;
  stage(0, 0);

  for (int c = 0; c < nch; c++) {
    __syncthreads();
    const int cur = c & 1;
    if (c + 1 < nch) stage(c + 1, cur ^ 1);

    f32x4 s[2][4];
#pragma unroll
    for (int t = 0; t < 4; t++) {
      bf16x8 k0 = *(const bf16x8*)(Kls[cur] + (0 * 4 + t) * 512 + quad * 128 + m16 * 8);
      bf16x8 k1 = *(const bf16x8*)(Kls[cur] + (1 * 4 + t) * 512 + quad * 128 + m16 * 8);
      __builtin_amdgcn_s_setprio(1);
#pragma unroll
      for (int rh = 0; rh < 2; rh++) {
        f32x4 z = (f32x4){0.f, 0.f, 0.f, 0.f};
        z = __builtin_amdgcn_mfma_f32_16x16x32_bf16(qf[rh][0], k0, z, 0, 0, 0);
        z = __builtin_amdgcn_mfma_f32_16x16x32_bf16(qf[rh][1], k1, z, 0, 0, 0);
        s[rh][t] = z;
      }
      __builtin_amdgcn_s_setprio(0);
    }

    bf16_t* pw = Pls[wave];
#pragma unroll
    for (int rh = 0; rh < 2; rh++)
#pragma unroll
      for (int r = 0; r < 4; r++) {
        int qg = qbase + rh * 16 + quad * 4 + r;
#pragma unroll
        for (int t = 0; t < 4; t++) {
          float v = s[rh][t][r] * 0.125f;
          float p;
          if (CAUSAL) {
            int kvg = c * 64 + t * 16 + m16;
            p = (kvg <= qg) ? __expf(v) : 0.f;
          } else {
            p = __expf(v);
          }
          rsum[rh][r] += p;
          pw[(rh * 16 + quad * 4 + r) * 72 + t * 16 + m16] = (bf16_t)p;
        }
      }

    bf16x8 pf[2][2];
#pragma unroll
    for (int rh = 0; rh < 2; rh++)
#pragma unroll
      for (int kvh = 0; kvh < 2; kvh++)
        pf[rh][kvh] = *(const bf16x8*)(pw + (rh * 16 + m16) * 72 + kvh * 32 + quad * 8);
#pragma unroll
    for (int t = 0; t < 4; t++) {
      bf16x8 v0 = *(const bf16x8*)(Vls[cur] + (0 * 4 + t) * 512 + quad * 128 + m16 * 8);
      bf16x8 v1 = *(const bf16x8*)(Vls[cur] + (1 * 4 + t) * 512 + quad * 128 + m16 * 8);
      __builtin_amdgcn_s_setprio(1);
#pragma unroll
      for (int rh = 0; rh < 2; rh++) {
        o_acc[rh][t] = __builtin_amdgcn_mfma_f32_16x16x32_bf16(pf[rh][0], v0, o_acc[rh][t], 0, 0, 0);
        o_acc[rh][t] = __builtin_amdgcn_mfma_f32_16x16x32_bf16(pf[rh][1], v1, o_acc[rh][t], 0, 0, 0);
      }
      __builtin_amdgcn_s_setprio(0);
    }
  }

#pragma unroll
  for (int rh = 0; rh < 2; rh++)
#pragma unroll
    for (int r = 0; r < 4; r++) {
      float v = rsum[rh][r];
      v += __shfl_xor(v, 1, 64);
      v += __shfl_xor(v, 2, 64);
      v += __shfl_xor(v, 4, 64);
      v += __shfl_xor(v, 8, 64);
      rsum[rh][r] = 1.f / v;
    }
#pragma unroll
  for (int rh = 0; rh < 2; rh++)
#pragma unroll
    for (int t = 0; t < 4; t++)
#pragma unroll
      for (int r = 0; r < 4; r++) {
        int row = b * S + qbase + rh * 16 + quad * 4 + r;
        int col = h * 64 + t * 16 + m16;
        O[(long)row * 1024 + col] = (bf16_t)(o_acc[rh][t][r] * rsum[rh][r]);
      }
}

// ---------------------------------------------------------------------------
extern "C" void kernel_launch(void* const* d_in, const int* in_sizes, int n_in,
                              void* d_out, int out_size, void* d_ws, size_t ws_size,
                              hipStream_t stream)
{
  const float* x   = (const float*)d_in[0];
  const float* enc = (const float*)d_in[1];
  const float* WqS = (const float*)d_in[3];
  const float* bqS = (const float*)d_in[4];
  const float* WkS = (const float*)d_in[5];
  const float* bkS = (const float*)d_in[6];
  const float* WvS = (const float*)d_in[7];
  const float* bvS = (const float*)d_in[8];
  const float* WqX = (const float*)d_in[9];
  const float* bqX = (const float*)d_in[10];
  const float* WkX = (const float*)d_in[11];
  const float* bkX = (const float*)d_in[12];
  const float* WvX = (const float*)d_in[13];
  const float* bvX = (const float*)d_in[14];
  const float* Wo  = (const float*)d_in[15];
  const float* bo  = (const float*)d_in[16];
  const float* W1  = (const float*)d_in[17];
  const float* b1  = (const float*)d_in[18];
  const float* W2  = (const float*)d_in[19];
  const float* b2  = (const float*)d_in[20];
  const float* g1  = (const float*)d_in[21];
  const float* be1 = (const float*)d_in[22];
  const float* g2  = (const float*)d_in[23];
  const float* be2 = (const float*)d_in[24];
  const float* g3  = (const float*)d_in[25];
  const float* be3 = (const float*)d_in[26];

  char* ws = (char*)d_ws;
  const long MBy = 1048576;
  bf16_t* WqkvST = (bf16_t*)(ws + 0 * MBy);            // 6 MB
  bf16_t* WqXT   = (bf16_t*)(ws + 6 * MBy);            // 2 MB
  bf16_t* WkvXT  = (bf16_t*)(ws + 8 * MBy);            // 4 MB
  bf16_t* WoT    = (bf16_t*)(ws + 12 * MBy);           // 2 MB
  bf16_t* W1T    = (bf16_t*)(ws + 14 * MBy);           // 8 MB
  bf16_t* W2T    = (bf16_t*)(ws + 22 * MBy);           // 8 MB
  float*  bqkvS  = (float*)(ws + 30 * MBy);            // 12 KB
  float*  bkvX   = (float*)(ws + 30 * MBy + 16384);    // 8 KB
  bf16_t* xb     = (bf16_t*)(ws + 31 * MBy);           // 8 MB (P1) -> Qx (P2)
  bf16_t* Qx     = xb;
  bf16_t* encb   = (bf16_t*)(ws + 39 * MBy);           // 8 MB (until KVenc)
  float*  x1f    = (float*)(ws + 47 * MBy);            // 16 MB f32 (resid chain)
  bf16_t* x1b    = (bf16_t*)(ws + 63 * MBy);           // 8 MB (->x2b)
  bf16_t* Z      = (bf16_t*)(ws + 71 * MBy);           // 8 MB attn out
  bf16_t* QK     = (bf16_t*)(ws + 79 * MBy);           // 16 MB [4096][2048] (P1)
  bf16_t* Kenc   = (bf16_t*)(ws + 79 * MBy);           // 8 MB [4096][1024] (P2)
  bf16_t* Vt     = (bf16_t*)(ws + 95 * MBy);           // 8 MB [64][64][1024]
  // split-K partial arena: overlays Vt region when dead (z=2 -> only pa0/pa1)
  bf16_t* pa0 = (bf16_t*)(ws + 95 * MBy);
  bf16_t* pa1 = (bf16_t*)(ws + 103 * MBy);
  bf16_t* Hbuf = (bf16_t*)(ws + 95 * MBy);             // 32 MB (P3)
  // FFN2 partials over dead weight/input regions
  bf16_t* pf0 = (bf16_t*)(ws + 0 * MBy);
  bf16_t* pf1 = (bf16_t*)(ws + 8 * MBy);
  bf16_t* pf2 = (bf16_t*)(ws + 31 * MBy);
  bf16_t* pf3 = (bf16_t*)(ws + 39 * MBy);

  dim3 tb(256), tb512(512);

  // ---- fused prep (1 dispatch) ----
  PrepArgs pa;
  pa.WqS = WqS; pa.WkS = WkS; pa.WvS = WvS; pa.WqX = WqX; pa.WkX = WkX; pa.WvX = WvX;
  pa.Wo = Wo; pa.W1 = W1; pa.W2 = W2; pa.x = x; pa.enc = enc;
  pa.bqS = bqS; pa.bkS = bkS; pa.bvS = bvS; pa.bkX = bkX; pa.bvX = bvX;
  pa.WqkvST = WqkvST; pa.WqXT = WqXT; pa.WkvXT = WkvXT; pa.WoT = WoT;
  pa.W1T = W1T; pa.W2T = W2T; pa.xb = xb; pa.encb = encb;
  pa.bqkv = bqkvS; pa.bkvx = bkvX;
  k_prep<<<dim3(17413), tb, 0, stream>>>(pa);

  // ---- phase 1: self-attention ----
  k_gemm<0, 0, 2048><<<dim3(768, 1, 1), tb, 0, stream>>>(
      xb, 1024, WqkvST, 1024, bqkvS, QK, 2048, Vt,
      nullptr, nullptr, nullptr, nullptr, 1024, 24);
  k_attn<1><<<dim3(8, 64), tb, 0, stream>>>(QK, 2048, QK + 1024, 2048, Vt, Z);
  k_gemm<1, 0, 0><<<dim3(256, 1, 2), tb, 0, stream>>>(
      Z, 1024, WoT, 1024, nullptr, nullptr, 1024, nullptr,
      pa0, pa1, nullptr, nullptr, 1024, 8);
  k_reduceN<1, 1, 1, 1, 2><<<dim3(4096), tb, 0, stream>>>(
      pa0, pa1, nullptr, nullptr, bo, x, g1, be1, x1f, x1b);

  // ---- phase 2: cross-attention ----
  k_gemm<1, 0, 0><<<dim3(256, 1, 2), tb, 0, stream>>>(
      x1b, 1024, WqXT, 1024, nullptr, nullptr, 1024, nullptr,
      pa0, pa1, nullptr, nullptr, 1024, 8);
  k_reduceN<0, 0, 0, 1, 2><<<dim3(4096), tb, 0, stream>>>(
      pa0, pa1, nullptr, nullptr, bqX, nullptr, nullptr, nullptr, nullptr, Qx);
  k_gemm<0, 0, 1024><<<dim3(512, 1, 1), tb, 0, stream>>>(
      encb, 1024, WkvXT, 1024, bkvX, Kenc, 1024, Vt,
      nullptr, nullptr, nullptr, nullptr, 1024, 16);
  k_attn<0><<<dim3(8, 64), tb, 0, stream>>>(Qx, 1024, Kenc, 1024, Vt, Z);
  k_gemm<1, 0, 0><<<dim3(256, 1, 2), tb, 0, stream>>>(
      Z, 1024, WoT, 1024, nullptr, nullptr, 1024, nullptr,
      pa0, pa1, nullptr, nullptr, 1024, 8);
  k_reduceN<1, 1, 1, 1, 2><<<dim3(4096), tb, 0, stream>>>(
      pa0, pa1, nullptr, nullptr, bo, x1f, g2, be2, x1f, x1b);

  // ---- phase 3: FFN ----
  k_gemm256<0, 1, 0><<<dim3(256, 1, 1), tb512, 0, stream>>>(
      x1b, 1024, W1T, 1024, b1, Hbuf, 4096, nullptr,
      nullptr, nullptr, nullptr, nullptr, 1024, 16);
  k_gemm256<1, 0, 0><<<dim3(64, 1, 4), tb512, 0, stream>>>(
      Hbuf, 4096, W2T, 4096, nullptr, nullptr, 1024, nullptr,
      pf0, pf1, pf2, pf3, 4096, 4);
  k_reduceN<1, 1, 1, 0, 4><<<dim3(4096), tb, 0, stream>>>(
      pf0, pf1, pf2, pf3, b2, x1f, g3, be3, (float*)d_out, nullptr);
}

// Round 9
// 538.389 us; speedup vs baseline: 1.0432x; 1.0143x over previous
//
#include <hip/hip_runtime.h>
#include <cstdint>

typedef __bf16 bf16_t;
typedef bf16_t bf16x8 __attribute__((ext_vector_type(8)));
typedef bf16_t bf16x4 __attribute__((ext_vector_type(4)));
typedef float  f32x4  __attribute__((ext_vector_type(4)));

#define DEVI static __device__ __forceinline__

DEVI void async_ld16(const bf16_t* g, bf16_t* l) {
  __builtin_amdgcn_global_load_lds((const __attribute__((address_space(1))) void*)g,
                                   (__attribute__((address_space(3))) void*)l, 16, 0, 0);
}

// ---------------------------------------------------------------------------
// Fused prep: all weight transposes + bf16 converts + bias packs, one dispatch.
// Transpose path vectorized (round-7): float4 loads + bf16x4 stores.
// ---------------------------------------------------------------------------
struct PrepArgs {
  const float *WqS, *WkS, *WvS, *WqX, *WkX, *WvX, *Wo, *W1, *W2, *x, *enc;
  const float *bqS, *bkS, *bvS, *bkX, *bvX;
  bf16_t *WqkvST, *WqXT, *WkvXT, *WoT, *W1T, *W2T, *xb, *encb;
  float *bqkv, *bkvx;
};

__global__ __launch_bounds__(256)
void k_prep(PrepArgs a)
{
  __shared__ float tile[32][36];
  const int blk = blockIdx.x, tid = threadIdx.x;

  const float* src = nullptr;
  bf16_t* dst = nullptr;
  int srcLd = 0, dstLd = 0, m0 = 0, n0 = 0;
  bool do_tr = false;

  if (blk < 6144) {
    int j = blk >> 10, q = blk & 1023;
    src = j == 0 ? a.WqS : j == 1 ? a.WkS : j == 2 ? a.WvS : j == 3 ? a.WqX : j == 4 ? a.WkX : a.WvX;
    dst = j == 0 ? a.WqkvST : j == 1 ? a.WqkvST + 1048576 : j == 2 ? a.WqkvST + 2097152
        : j == 3 ? a.WqXT : j == 4 ? a.WkvXT : a.WkvXT + 1048576;
    int batch = q >> 6, rem = q & 63;
    src += (long)batch * 65536; dst += (long)batch * 65536;
    srcLd = 64; dstLd = 1024;
    n0 = (rem & 1) * 32; m0 = (rem >> 1) * 32;
    do_tr = true;
  } else if (blk < 7168) {
    int q = blk - 6144;
    src = a.Wo; dst = a.WoT; srcLd = 1024; dstLd = 1024;
    m0 = (q >> 5) * 32; n0 = (q & 31) * 32; do_tr = true;
  } else if (blk < 11264) {
    int q = blk - 7168;
    src = a.W1; dst = a.W1T; srcLd = 4096; dstLd = 1024;
    m0 = (q >> 7) * 32; n0 = (q & 127) * 32; do_tr = true;
  } else if (blk < 15360) {
    int q = blk - 11264;
    src = a.W2; dst = a.W2T; srcLd = 1024; dstLd = 4096;
    m0 = (q >> 5) * 32; n0 = (q & 31) * 32; do_tr = true;
  } else if (blk < 16384) {
    long base = (long)(blk - 15360) * 4096 + tid * 4;
#pragma unroll
    for (int u = 0; u < 4; u++) {
      float4 v = *(const float4*)(a.x + base + u * 1024);
      bf16x4 o; o[0] = (bf16_t)v.x; o[1] = (bf16_t)v.y; o[2] = (bf16_t)v.z; o[3] = (bf16_t)v.w;
      *(bf16x4*)(a.xb + base + u * 1024) = o;
    }
    return;
  } else if (blk < 17408) {
    long base = (long)(blk - 16384) * 4096 + tid * 4;
#pragma unroll
    for (int u = 0; u < 4; u++) {
      float4 v = *(const float4*)(a.enc + base + u * 1024);
      bf16x4 o; o[0] = (bf16_t)v.x; o[1] = (bf16_t)v.y; o[2] = (bf16_t)v.z; o[3] = (bf16_t)v.w;
      *(bf16x4*)(a.encb + base + u * 1024) = o;
    }
    return;
  } else {
    int gi = (blk - 17408) * 1024 + tid * 4;
#pragma unroll
    for (int j = 0; j < 4; j++) {
      int i = gi + j;
      if (i < 1024)      a.bqkv[i] = a.bqS[i];
      else if (i < 2048) a.bqkv[i] = a.bkS[i - 1024];
      else if (i < 3072) a.bqkv[i] = a.bvS[i - 2048];
      else if (i < 4096) a.bkvx[i - 3072] = a.bkX[i - 3072];
      else if (i < 5120) a.bkvx[i - 3072] = a.bvX[i - 4096];
    }
    return;
  }

  if (do_tr) {
    {
      int r = tid >> 3, c4 = (tid & 7) * 4;
      *(float4*)&tile[r][c4] = *(const float4*)(src + (long)(m0 + r) * srcLd + n0 + c4);
    }
    __syncthreads();
    {
      int nr = tid >> 3, mq = (tid & 7) * 4;
      bf16x4 o;
      o[0] = (bf16_t)tile[mq + 0][nr];
      o[1] = (bf16_t)tile[mq + 1][nr];
      o[2] = (bf16_t)tile[mq + 2][nr];
      o[3] = (bf16_t)tile[mq + 3][nr];
      *(bf16x4*)(dst + (long)(n0 + nr) * dstLd + m0 + mq) = o;
    }
  }
}

// ---------------------------------------------------------------------------
// GEMM 128x128 tile, BK=32, 2-phase double-buffered global_load_lds.
// (Known-good core — frozen. Used for Wo split-K2 only now.)
// ---------------------------------------------------------------------------
template<int OUT_MODE, int RELU, int VOFF>
__global__ __launch_bounds__(256, 2)
void k_gemm(const bf16_t* __restrict__ A, int lda,
            const bf16_t* __restrict__ Bt, int ldb,
            const float* __restrict__ bias,
            bf16_t* __restrict__ C, int ldc,
            bf16_t* __restrict__ Vt,
            bf16_t* __restrict__ p0, bf16_t* __restrict__ p1,
            bf16_t* __restrict__ p2, bf16_t* __restrict__ p3,
            int Ktot, int nx)
{
  __shared__ bf16_t As[2][128 * 32];
  __shared__ bf16_t Bs[2][128 * 32];
  const int tid  = threadIdx.x;
  const int wave = tid >> 6, lane = tid & 63;
  const int quad = lane >> 4, m16 = lane & 15;

  int lin = blockIdx.x;
  int perx = gridDim.x >> 3;
  int t = (lin & 7) * perx + (lin >> 3);
  const int bcol = (t % nx) * 128, brow = (t / nx) * 128;
  const int wr = (wave >> 1) * 64, wc = (wave & 1) * 64;

  const int Kper = Ktot / gridDim.z;
  const int k0 = blockIdx.z * Kper;

  f32x4 acc[4][4];
#pragma unroll
  for (int i = 0; i < 4; i++)
#pragma unroll
    for (int j = 0; j < 4; j++) acc[i][j] = (f32x4){0.f, 0.f, 0.f, 0.f};

  auto stage = [&](int kt, int buf) {
#pragma unroll
    for (int i = 0; i < 2; i++) {
      int rg = wave * 2 + i;
      async_ld16(A  + (long)(brow + rg * 16 + m16) * lda + kt + quad * 8, As[buf] + rg * 512);
      async_ld16(Bt + (long)(bcol + rg * 16 + m16) * ldb + kt + quad * 8, Bs[buf] + rg * 512);
    }
  };

  stage(k0, 0);
  __syncthreads();

  const int nIter = Kper >> 5;
  for (int it = 0; it < nIter; it++) {
    const int cur = it & 1;
    if (it + 1 < nIter) stage(k0 + (it + 1) * 32, cur ^ 1);

    bf16x8 af[4], bfr[4];
#pragma unroll
    for (int tt = 0; tt < 4; tt++) {
      af[tt]  = *(const bf16x8*)(As[cur] + ((wr + tt * 16) >> 4) * 512 + quad * 128 + m16 * 8);
      bfr[tt] = *(const bf16x8*)(Bs[cur] + ((wc + tt * 16) >> 4) * 512 + quad * 128 + m16 * 8);
    }
#pragma unroll
    for (int i = 0; i < 4; i++)
#pragma unroll
      for (int j = 0; j < 4; j++)
        acc[i][j] = __builtin_amdgcn_mfma_f32_16x16x32_bf16(af[i], bfr[j], acc[i][j], 0, 0, 0);

    __syncthreads();
  }

  if (OUT_MODE == 1) {
    bf16_t* P = blockIdx.z == 0 ? p0 : blockIdx.z == 1 ? p1 : blockIdx.z == 2 ? p2 : p3;
#pragma unroll
    for (int i = 0; i < 4; i++)
#pragma unroll
      for (int j = 0; j < 4; j++) {
        int col = bcol + wc + j * 16 + m16;
#pragma unroll
        for (int r = 0; r < 4; r++) {
          int row = brow + wr + i * 16 + quad * 4 + r;
          P[(long)row * ldc + col] = (bf16_t)acc[i][j][r];
        }
      }
  } else {
#pragma unroll
    for (int i = 0; i < 4; i++)
#pragma unroll
      for (int j = 0; j < 4; j++) {
        int col = bcol + wc + j * 16 + m16;
        float bv = bias[col];
        if (VOFF && col >= VOFF) {
          int hh = (col - VOFF) >> 6, dd = col & 63;
          int row0 = brow + wr + i * 16 + quad * 4;
          int bb = row0 >> 10, seq = row0 & 1023;
          bf16x4 pk;
#pragma unroll
          for (int r = 0; r < 4; r++) pk[r] = (bf16_t)(acc[i][j][r] + bv);
          *(bf16x4*)(Vt + (long)(bb * 16 + hh) * 65536 + dd * 1024 + seq) = pk;
        } else {
#pragma unroll
          for (int r = 0; r < 4; r++) {
            int row = brow + wr + i * 16 + quad * 4 + r;
            float v = acc[i][j][r] + bv;
            if (RELU) v = v > 0.f ? v : 0.f;
            C[(long)row * ldc + col] = (bf16_t)v;
          }
        }
      }
  }
}

// ---------------------------------------------------------------------------
// DUAL-ROLE 128x128 GEMM (round-9): fuses the phase-2 head into ONE dispatch.
// Role A (blocks [0,nblkA)): Qx = x1b @ WqXT + bqX, direct bf16 out (cols
// < 1024 so the VOFF redirect is inert) — replaces split-K2 + bias-reduce.
// Role B (blocks [nblkA, grid)): Kenc/Vt = encb @ WkvXT + bkvX (VOFF=1024).
// Both roles: K=1024, 32 iters, identical per-block duration; 768 blocks
// restores the 2-3 blk/CU cross-block overlap that a standalone 256-block
// direct Qx would lose. Body = k_gemm OUT_MODE0 verbatim; role-selected
// pointers only; per-role XCD swizzle (bijective).
// ---------------------------------------------------------------------------
__global__ __launch_bounds__(256, 2)
void k_gemm_dual(const bf16_t* __restrict__ Aa, const bf16_t* __restrict__ Bta,
                 const float* __restrict__ biasa, bf16_t* __restrict__ Ca,
                 int nxa, int nblkA,
                 const bf16_t* __restrict__ Ab, const bf16_t* __restrict__ Btb,
                 const float* __restrict__ biasb, bf16_t* __restrict__ Cb,
                 int nxb,
                 bf16_t* __restrict__ Vt)
{
  __shared__ bf16_t As[2][128 * 32];
  __shared__ bf16_t Bs[2][128 * 32];
  const int tid  = threadIdx.x;
  const int wave = tid >> 6, lane = tid & 63;
  const int quad = lane >> 4, m16 = lane & 15;

  const bool roleB = (int)blockIdx.x >= nblkA;
  const bf16_t* A    = roleB ? Ab    : Aa;
  const bf16_t* Bt   = roleB ? Btb   : Bta;
  const float*  bias = roleB ? biasb : biasa;
  bf16_t*       C    = roleB ? Cb    : Ca;
  const int nx   = roleB ? nxb : nxa;
  const int lin  = roleB ? ((int)blockIdx.x - nblkA) : (int)blockIdx.x;
  const int nblk = roleB ? ((int)gridDim.x - nblkA) : nblkA;
  const int perx = nblk >> 3;
  const int t = (lin & 7) * perx + (lin >> 3);
  const int bcol = (t % nx) * 128, brow = (t / nx) * 128;
  const int wr = (wave >> 1) * 64, wc = (wave & 1) * 64;
  const int lda = 1024, ldb = 1024, ldc = 1024;

  f32x4 acc[4][4];
#pragma unroll
  for (int i = 0; i < 4; i++)
#pragma unroll
    for (int j = 0; j < 4; j++) acc[i][j] = (f32x4){0.f, 0.f, 0.f, 0.f};

  auto stage = [&](int kt, int buf) {
#pragma unroll
    for (int i = 0; i < 2; i++) {
      int rg = wave * 2 + i;
      async_ld16(A  + (long)(brow + rg * 16 + m16) * lda + kt + quad * 8, As[buf] + rg * 512);
      async_ld16(Bt + (long)(bcol + rg * 16 + m16) * ldb + kt + quad * 8, Bs[buf] + rg * 512);
    }
  };

  stage(0, 0);
  __syncthreads();

  const int nIter = 32;                       // K = 1024, BK = 32
  for (int it = 0; it < nIter; it++) {
    const int cur = it & 1;
    if (it + 1 < nIter) stage((it + 1) * 32, cur ^ 1);

    bf16x8 af[4], bfr[4];
#pragma unroll
    for (int tt = 0; tt < 4; tt++) {
      af[tt]  = *(const bf16x8*)(As[cur] + ((wr + tt * 16) >> 4) * 512 + quad * 128 + m16 * 8);
      bfr[tt] = *(const bf16x8*)(Bs[cur] + ((wc + tt * 16) >> 4) * 512 + quad * 128 + m16 * 8);
    }
#pragma unroll
    for (int i = 0; i < 4; i++)
#pragma unroll
      for (int j = 0; j < 4; j++)
        acc[i][j] = __builtin_amdgcn_mfma_f32_16x16x32_bf16(af[i], bfr[j], acc[i][j], 0, 0, 0);

    __syncthreads();
  }

#pragma unroll
  for (int i = 0; i < 4; i++)
#pragma unroll
    for (int j = 0; j < 4; j++) {
      int col = bcol + wc + j * 16 + m16;
      float bv = bias[col];
      if (col >= 1024) {                      // only reachable in role B
        int hh = (col - 1024) >> 6, dd = col & 63;
        int row0 = brow + wr + i * 16 + quad * 4;
        int bb = row0 >> 10, seq = row0 & 1023;
        bf16x4 pk;
#pragma unroll
        for (int r = 0; r < 4; r++) pk[r] = (bf16_t)(acc[i][j][r] + bv);
        *(bf16x4*)(Vt + (long)(bb * 16 + hh) * 65536 + dd * 1024 + seq) = pk;
      } else {
#pragma unroll
        for (int r = 0; r < 4; r++) {
          int row = brow + wr + i * 16 + quad * 4 + r;
          C[(long)row * ldc + col] = (bf16_t)(acc[i][j][r] + bv);
        }
      }
    }
}

// ---------------------------------------------------------------------------
// GEMM 256x256 tile, BK=64, 2-phase double-buffer. ~570 TF ≈ 93% of the
// 2-phase structural ceiling (m233/m248); 8-phase port not reconstructible
// race-free from docs (m152) — structure frozen. Round-9: now also used for
// QKV (192 blocks, nx=12, VOFF=2048 — boundary-aligned 256-col tiles).
// (512,2): VGPR cap 256 ((512,4) spilled, round-3). LDS 128KB -> 1 blk/CU.
// ---------------------------------------------------------------------------
template<int OUT_MODE, int RELU, int VOFF>
__global__ __launch_bounds__(512, 2)
void k_gemm256(const bf16_t* __restrict__ A, int lda,
               const bf16_t* __restrict__ Bt, int ldb,
               const float* __restrict__ bias,
               bf16_t* __restrict__ C, int ldc,
               bf16_t* __restrict__ Vt,
               bf16_t* __restrict__ p0, bf16_t* __restrict__ p1,
               bf16_t* __restrict__ p2, bf16_t* __restrict__ p3,
               int Ktot, int nx)
{
  __shared__ bf16_t As[2][256 * 64];
  __shared__ bf16_t Bs[2][256 * 64];
  const int tid  = threadIdx.x;
  const int wave = tid >> 6, lane = tid & 63;
  const int quad = lane >> 4, m16 = lane & 15;

  int lin = blockIdx.x;
  int perx = gridDim.x >> 3;
  int t = (lin & 7) * perx + (lin >> 3);
  const int bcol = (t % nx) * 256, brow = (t / nx) * 256;
  const int wr = (wave >> 2) * 128, wc = (wave & 3) * 64;

  const int Kper = Ktot / gridDim.z;
  const int k0 = blockIdx.z * Kper;

  f32x4 acc[8][4];
#pragma unroll
  for (int i = 0; i < 8; i++)
#pragma unroll
    for (int j = 0; j < 4; j++) acc[i][j] = (f32x4){0.f, 0.f, 0.f, 0.f};

  auto stage = [&](int kt, int buf) {
#pragma unroll
    for (int i = 0; i < 2; i++) {
      int rg = wave * 2 + i;
#pragma unroll
      for (int ks = 0; ks < 2; ks++) {
        async_ld16(A  + (long)(brow + rg * 16 + m16) * lda + kt + ks * 32 + quad * 8,
                   As[buf] + (rg * 2 + ks) * 512);
        async_ld16(Bt + (long)(bcol + rg * 16 + m16) * ldb + kt + ks * 32 + quad * 8,
                   Bs[buf] + (rg * 2 + ks) * 512);
      }
    }
  };

  stage(k0, 0);
  __syncthreads();

  const int nIter = Kper >> 6;
  for (int it = 0; it < nIter; it++) {
    const int cur = it & 1;
    if (it + 1 < nIter) stage(k0 + (it + 1) * 64, cur ^ 1);

    const bf16_t* Ac = As[cur];
    const bf16_t* Bc = Bs[cur];
#pragma unroll
    for (int ks = 0; ks < 2; ks++) {
      bf16x8 af[8], bfr[4];
#pragma unroll
      for (int tt = 0; tt < 8; tt++)
        af[tt] = *(const bf16x8*)(Ac + (((wr + tt * 16) >> 4) * 2 + ks) * 512 + quad * 128 + m16 * 8);
#pragma unroll
      for (int j = 0; j < 4; j++)
        bfr[j] = *(const bf16x8*)(Bc + (((wc + j * 16) >> 4) * 2 + ks) * 512 + quad * 128 + m16 * 8);
      __builtin_amdgcn_s_setprio(1);
#pragma unroll
      for (int i = 0; i < 8; i++)
#pragma unroll
        for (int j = 0; j < 4; j++)
          acc[i][j] = __builtin_amdgcn_mfma_f32_16x16x32_bf16(af[i], bfr[j], acc[i][j], 0, 0, 0);
      __builtin_amdgcn_s_setprio(0);
    }

    __syncthreads();
  }

  if (OUT_MODE == 1) {
    bf16_t* P = blockIdx.z == 0 ? p0 : blockIdx.z == 1 ? p1 : blockIdx.z == 2 ? p2 : p3;
#pragma unroll
    for (int i = 0; i < 8; i++)
#pragma unroll
      for (int j = 0; j < 4; j++) {
        int col = bcol + wc + j * 16 + m16;
#pragma unroll
        for (int r = 0; r < 4; r++) {
          int row = brow + wr + i * 16 + quad * 4 + r;
          P[(long)row * ldc + col] = (bf16_t)acc[i][j][r];
        }
      }
  } else {
#pragma unroll
    for (int i = 0; i < 8; i++)
#pragma unroll
      for (int j = 0; j < 4; j++) {
        int col = bcol + wc + j * 16 + m16;
        float bv = bias[col];
        if (VOFF && col >= VOFF) {
          int hh = (col - VOFF) >> 6, dd = col & 63;
          int row0 = brow + wr + i * 16 + quad * 4;
          int bb = row0 >> 10, seq = row0 & 1023;
          bf16x4 pk;
#pragma unroll
          for (int r = 0; r < 4; r++) pk[r] = (bf16_t)(acc[i][j][r] + bv);
          *(bf16x4*)(Vt + (long)(bb * 16 + hh) * 65536 + dd * 1024 + seq) = pk;
        } else {
#pragma unroll
          for (int r = 0; r < 4; r++) {
            int row = brow + wr + i * 16 + quad * 4 + r;
            float v = acc[i][j][r] + bv;
            if (RELU) v = v > 0.f ? v : 0.f;
            C[(long)row * ldc + col] = (bf16_t)v;
          }
        }
      }
  }
}

// ---------------------------------------------------------------------------
// Split-K reduce (NPART partials) + bias (+resid) (+LayerNorm). 1 row/block.
// ---------------------------------------------------------------------------
template<int LN, int RESID, int OUTF, int OUTB, int NPART>
__global__ __launch_bounds__(256)
void k_reduceN(const bf16_t* __restrict__ p0, const bf16_t* __restrict__ p1,
               const bf16_t* __restrict__ p2, const bf16_t* __restrict__ p3,
               const float* __restrict__ bias, const float* __restrict__ resid,
               const float* __restrict__ gamma, const float* __restrict__ beta,
               float* __restrict__ outf, bf16_t* __restrict__ outb)
{
  constexpr int D = 1024;
  __shared__ float red[8];
  int row = blockIdx.x, tid = threadIdx.x;
  long off = (long)row * D + tid * 4;
  bf16x4 a0 = *(const bf16x4*)(p0 + off);
  bf16x4 a1 = *(const bf16x4*)(p1 + off);
  float4 bb4 = *(const float4*)(bias + tid * 4);
  float4 v;
  v.x = (float)a0[0] + (float)a1[0] + bb4.x;
  v.y = (float)a0[1] + (float)a1[1] + bb4.y;
  v.z = (float)a0[2] + (float)a1[2] + bb4.z;
  v.w = (float)a0[3] + (float)a1[3] + bb4.w;
  if (NPART == 4) {
    bf16x4 a2 = *(const bf16x4*)(p2 + off);
    bf16x4 a3 = *(const bf16x4*)(p3 + off);
    v.x += (float)a2[0] + (float)a3[0];
    v.y += (float)a2[1] + (float)a3[1];
    v.z += (float)a2[2] + (float)a3[2];
    v.w += (float)a2[3] + (float)a3[3];
  }
  if (RESID) {
    float4 q = *(const float4*)(resid + off);
    v.x += q.x; v.y += q.y; v.z += q.z; v.w += q.w;
  }
  float4 y = v;
  if (LN) {
    float s  = v.x + v.y + v.z + v.w;
    float sq = v.x * v.x + v.y * v.y + v.z * v.z + v.w * v.w;
#pragma unroll
    for (int o = 1; o < 64; o <<= 1) {
      s  += __shfl_xor(s, o, 64);
      sq += __shfl_xor(sq, o, 64);
    }
    int wave = tid >> 6, lane = tid & 63;
    if (lane == 0) { red[wave * 2] = s; red[wave * 2 + 1] = sq; }
    __syncthreads();
    float ts = red[0] + red[2] + red[4] + red[6];
    float tq = red[1] + red[3] + red[5] + red[7];
    float mu = ts * (1.f / D);
    float var = tq * (1.f / D) - mu * mu;
    float rstd = rsqrtf(var + 1e-5f);
    float4 g  = *(const float4*)(gamma + tid * 4);
    float4 be = *(const float4*)(beta + tid * 4);
    y.x = (v.x - mu) * rstd * g.x + be.x;
    y.y = (v.y - mu) * rstd * g.y + be.y;
    y.z = (v.z - mu) * rstd * g.z + be.z;
    y.w = (v.w - mu) * rstd * g.w + be.w;
  }
  if (OUTF) *(float4*)(outf + off) = y;
  if (OUTB) {
    bf16x4 o;
    o[0] = (bf16_t)y.x; o[1] = (bf16_t)y.y; o[2] = (bf16_t)y.z; o[3] = (bf16_t)y.w;
    *(bf16x4*)(outb + off) = o;
  }
}

// ---------------------------------------------------------------------------
// Flash attention. Causal load-balance swizzle (round-8, kept: >= baseline by
// construction). LDS double-buffered KV staging; setprio around MFMA.
// ---------------------------------------------------------------------------
template<int CAUSAL>
__global__ __launch_bounds__(256, 2)
void k_attn(const bf16_t* __restrict__ Q, int ldq,
            const bf16_t* __restrict__ Kp, int ldk,
            const bf16_t* __restrict__ Vt,
            bf16_t* __restrict__ O)
{
  constexpr int S = 1024;
  __shared__ bf16_t Kls[2][4096];
  __shared__ bf16_t Vls[2][4096];
  __shared__ bf16_t Pls[4][32 * 72];

  const int tid = threadIdx.x;
  const int wave = tid >> 6, lane = tid & 63;
  const int quad = lane >> 4, m16 = lane & 15;
  const int bh = blockIdx.y, b = bh >> 4, h = bh & 15;
  const int qt = (CAUSAL && (bh & 32)) ? ((int)gridDim.x - 1 - (int)blockIdx.x)
                                       : (int)blockIdx.x;
  const int qbase = qt * 128 + wave * 32;

  bf16x8 qf[2][2];
#pragma unroll
  for (int rh = 0; rh < 2; rh++) {
    const bf16_t* qp = Q + (long)(b * S + qbase + rh * 16 + m16) * ldq + h * 64 + quad * 8;
    qf[rh][0] = *(const bf16x8*)qp;
    qf[rh][1] = *(const bf16x8*)(qp + 32);
  }

  f32x4 o_acc[2][4];
#pragma unroll
  for (int rh = 0; rh < 2; rh++)
#pragma unroll
    for (int t = 0; t < 4; t++) o_acc[rh][t] = (f32x4){0.f, 0.f, 0.f, 0.f};
  float rsum[2][4];
#pragma unroll
  for (int rh = 0; rh < 2; rh++)
#pragma unroll
    for (int r = 0; r < 4; r++) rsum[rh][r] = 0.f;

  auto stage = [&](int c, int buf) {
#pragma unroll
    for (int i = 0; i < 2; i++) {
      int t2 = wave * 2 + i;
      int rg = t2 & 3, ph = t2 >> 2;
      async_ld16(Kp + (long)(b * S + c * 64 + rg * 16 + m16) * ldk + h * 64 + ph * 32 + quad * 8,
                 Kls[buf] + t2 * 512);
      async_ld16(Vt + (long)bh * 65536 + (rg * 16 + m16) * 1024 + c * 64 + ph * 32 + quad * 8,
                 Vls[buf] + t2 * 512);
    }
  };

  const int nch = CAUSAL ? (2 * qt + 2) : 16;
  stage(0, 0);

  for (int c = 0; c < nch; c++) {
    __syncthreads();
    const int cur = c & 1;
    if (c + 1 < nch) stage(c + 1, cur ^ 1);

    f32x4 s[2][4];
#pragma unroll
    for (int t = 0; t < 4; t++) {
      bf16x8 k0 = *(const bf16x8*)(Kls[cur] + (0 * 4 + t) * 512 + quad * 128 + m16 * 8);
      bf16x8 k1 = *(const bf16x8*)(Kls[cur] + (1 * 4 + t) * 512 + quad * 128 + m16 * 8);
      __builtin_amdgcn_s_setprio(1);
#pragma unroll
      for (int rh = 0; rh < 2; rh++) {
        f32x4 z = (f32x4){0.f, 0.f, 0.f, 0.f};
        z = __builtin_amdgcn_mfma_f32_16x16x32_bf16(qf[rh][0], k0, z, 0, 0, 0);
        z = __builtin_amdgcn_mfma_f32_16x16x32_bf16(qf[rh][1], k1, z, 0, 0, 0);
        s[rh][t] = z;
      }
      __builtin_amdgcn_s_setprio(0);
    }

    bf16_t* pw = Pls[wave];
#pragma unroll
    for (int rh = 0; rh < 2; rh++)
#pragma unroll
      for (int r = 0; r < 4; r++) {
        int qg = qbase + rh * 16 + quad * 4 + r;
#pragma unroll
        for (int t = 0; t < 4; t++) {
          float v = s[rh][t][r] * 0.125f;
          float p;
          if (CAUSAL) {
            int kvg = c * 64 + t * 16 + m16;
            p = (kvg <= qg) ? __expf(v) : 0.f;
          } else {
            p = __expf(v);
          }
          rsum[rh][r] += p;
          pw[(rh * 16 + quad * 4 + r) * 72 + t * 16 + m16] = (bf16_t)p;
        }
      }

    bf16x8 pf[2][2];
#pragma unroll
    for (int rh = 0; rh < 2; rh++)
#pragma unroll
      for (int kvh = 0; kvh < 2; kvh++)
        pf[rh][kvh] = *(const bf16x8*)(pw + (rh * 16 + m16) * 72 + kvh * 32 + quad * 8);
#pragma unroll
    for (int t = 0; t < 4; t++) {
      bf16x8 v0 = *(const bf16x8*)(Vls[cur] + (0 * 4 + t) * 512 + quad * 128 + m16 * 8);
      bf16x8 v1 = *(const bf16x8*)(Vls[cur] + (1 * 4 + t) * 512 + quad * 128 + m16 * 8);
      __builtin_amdgcn_s_setprio(1);
#pragma unroll
      for (int rh = 0; rh < 2; rh++) {
        o_acc[rh][t] = __builtin_amdgcn_mfma_f32_16x16x32_bf16(pf[rh][0], v0, o_acc[rh][t], 0, 0, 0);
        o_acc[rh][t] = __builtin_amdgcn_mfma_f32_16x16x32_bf16(pf[rh][1], v1, o_acc[rh][t], 0, 0, 0);
      }
      __builtin_amdgcn_s_setprio(0);
    }
  }

#pragma unroll
  for (int rh = 0; rh < 2; rh++)
#pragma unroll
    for (int r = 0; r < 4; r++) {
      float v = rsum[rh][r];
      v += __shfl_xor(v, 1, 64);
      v += __shfl_xor(v, 2, 64);
      v += __shfl_xor(v, 4, 64);
      v += __shfl_xor(v, 8, 64);
      rsum[rh][r] = 1.f / v;
    }
#pragma unroll
  for (int rh = 0; rh < 2; rh++)
#pragma unroll
    for (int t = 0; t < 4; t++)
#pragma unroll
      for (int r = 0; r < 4; r++) {
        int row = b * S + qbase + rh * 16 + quad * 4 + r;
        int col = h * 64 + t * 16 + m16;
        O[(long)row * 1024 + col] = (bf16_t)(o_acc[rh][t][r] * rsum[rh][r]);
      }
}

// ---------------------------------------------------------------------------
extern "C" void kernel_launch(void* const* d_in, const int* in_sizes, int n_in,
                              void* d_out, int out_size, void* d_ws, size_t ws_size,
                              hipStream_t stream)
{
  const float* x   = (const float*)d_in[0];
  const float* enc = (const float*)d_in[1];
  const float* WqS = (const float*)d_in[3];
  const float* bqS = (const float*)d_in[4];
  const float* WkS = (const float*)d_in[5];
  const float* bkS = (const float*)d_in[6];
  const float* WvS = (const float*)d_in[7];
  const float* bvS = (const float*)d_in[8];
  const float* WqX = (const float*)d_in[9];
  const float* bqX = (const float*)d_in[10];
  const float* WkX = (const float*)d_in[11];
  const float* bkX = (const float*)d_in[12];
  const float* WvX = (const float*)d_in[13];
  const float* bvX = (const float*)d_in[14];
  const float* Wo  = (const float*)d_in[15];
  const float* bo  = (const float*)d_in[16];
  const float* W1  = (const float*)d_in[17];
  const float* b1  = (const float*)d_in[18];
  const float* W2  = (const float*)d_in[19];
  const float* b2  = (const float*)d_in[20];
  const float* g1  = (const float*)d_in[21];
  const float* be1 = (const float*)d_in[22];
  const float* g2  = (const float*)d_in[23];
  const float* be2 = (const float*)d_in[24];
  const float* g3  = (const float*)d_in[25];
  const float* be3 = (const float*)d_in[26];

  char* ws = (char*)d_ws;
  const long MBy = 1048576;
  bf16_t* WqkvST = (bf16_t*)(ws + 0 * MBy);            // 6 MB
  bf16_t* WqXT   = (bf16_t*)(ws + 6 * MBy);            // 2 MB
  bf16_t* WkvXT  = (bf16_t*)(ws + 8 * MBy);            // 4 MB
  bf16_t* WoT    = (bf16_t*)(ws + 12 * MBy);           // 2 MB
  bf16_t* W1T    = (bf16_t*)(ws + 14 * MBy);           // 8 MB
  bf16_t* W2T    = (bf16_t*)(ws + 22 * MBy);           // 8 MB
  float*  bqkvS  = (float*)(ws + 30 * MBy);            // 12 KB
  float*  bkvX   = (float*)(ws + 30 * MBy + 16384);    // 8 KB
  bf16_t* xb     = (bf16_t*)(ws + 31 * MBy);           // 8 MB (P1) -> Qx (P2)
  bf16_t* Qx     = xb;
  bf16_t* encb   = (bf16_t*)(ws + 39 * MBy);           // 8 MB (until KVenc)
  float*  x1f    = (float*)(ws + 47 * MBy);            // 16 MB f32 (resid chain)
  bf16_t* x1b    = (bf16_t*)(ws + 63 * MBy);           // 8 MB (->x2b)
  bf16_t* Z      = (bf16_t*)(ws + 71 * MBy);           // 8 MB attn out
  bf16_t* QK     = (bf16_t*)(ws + 79 * MBy);           // 16 MB [4096][2048] (P1)
  bf16_t* Kenc   = (bf16_t*)(ws + 79 * MBy);           // 8 MB [4096][1024] (P2)
  bf16_t* Vt     = (bf16_t*)(ws + 95 * MBy);           // 8 MB [64][64][1024]
  // split-K partial arena: overlays Vt region when dead (z=2 -> only pa0/pa1)
  bf16_t* pa0 = (bf16_t*)(ws + 95 * MBy);
  bf16_t* pa1 = (bf16_t*)(ws + 103 * MBy);
  bf16_t* Hbuf = (bf16_t*)(ws + 95 * MBy);             // 32 MB (P3)
  // FFN2 partials over dead weight/input regions
  bf16_t* pf0 = (bf16_t*)(ws + 0 * MBy);
  bf16_t* pf1 = (bf16_t*)(ws + 8 * MBy);
  bf16_t* pf2 = (bf16_t*)(ws + 31 * MBy);
  bf16_t* pf3 = (bf16_t*)(ws + 39 * MBy);

  dim3 tb(256), tb512(512);

  // ---- fused prep (1 dispatch) ----
  PrepArgs pa;
  pa.WqS = WqS; pa.WkS = WkS; pa.WvS = WvS; pa.WqX = WqX; pa.WkX = WkX; pa.WvX = WvX;
  pa.Wo = Wo; pa.W1 = W1; pa.W2 = W2; pa.x = x; pa.enc = enc;
  pa.bqS = bqS; pa.bkS = bkS; pa.bvS = bvS; pa.bkX = bkX; pa.bvX = bvX;
  pa.WqkvST = WqkvST; pa.WqXT = WqXT; pa.WkvXT = WkvXT; pa.WoT = WoT;
  pa.W1T = W1T; pa.W2T = W2T; pa.xb = xb; pa.encb = encb;
  pa.bqkv = bqkvS; pa.bkvx = bkvX;
  k_prep<<<dim3(17413), tb, 0, stream>>>(pa);

  // ---- phase 1: self-attention ----
  k_gemm256<0, 0, 2048><<<dim3(192, 1, 1), tb512, 0, stream>>>(
      xb, 1024, WqkvST, 1024, bqkvS, QK, 2048, Vt,
      nullptr, nullptr, nullptr, nullptr, 1024, 12);
  k_attn<1><<<dim3(8, 64), tb, 0, stream>>>(QK, 2048, QK + 1024, 2048, Vt, Z);
  k_gemm<1, 0, 0><<<dim3(256, 1, 2), tb, 0, stream>>>(
      Z, 1024, WoT, 1024, nullptr, nullptr, 1024, nullptr,
      pa0, pa1, nullptr, nullptr, 1024, 8);
  k_reduceN<1, 1, 1, 1, 2><<<dim3(4096), tb, 0, stream>>>(
      pa0, pa1, nullptr, nullptr, bo, x, g1, be1, x1f, x1b);

  // ---- phase 2: cross-attention ----
  // one dual-role dispatch: Qx (direct, bias fused) + Kenc/Vt
  k_gemm_dual<<<dim3(768), tb, 0, stream>>>(
      x1b, WqXT, bqX, Qx, 8, 256,
      encb, WkvXT, bkvX, Kenc, 16, Vt);
  k_attn<0><<<dim3(8, 64), tb, 0, stream>>>(Qx, 1024, Kenc, 1024, Vt, Z);
  k_gemm<1, 0, 0><<<dim3(256, 1, 2), tb, 0, stream>>>(
      Z, 1024, WoT, 1024, nullptr, nullptr, 1024, nullptr,
      pa0, pa1, nullptr, nullptr, 1024, 8);
  k_reduceN<1, 1, 1, 1, 2><<<dim3(4096), tb, 0, stream>>>(
      pa0, pa1, nullptr, nullptr, bo, x1f, g2, be2, x1f, x1b);

  // ---- phase 3: FFN ----
  k_gemm256<0, 1, 0><<<dim3(256, 1, 1), tb512, 0, stream>>>(
      x1b, 1024, W1T, 1024, b1, Hbuf, 4096, nullptr,
      nullptr, nullptr, nullptr, nullptr, 1024, 16);
  k_gemm256<1, 0, 0><<<dim3(64, 1, 4), tb512, 0, stream>>>(
      Hbuf, 4096, W2T, 4096, nullptr, nullptr, 1024, nullptr,
      pf0, pf1, pf2, pf3, 4096, 4);
  k_reduceN<1, 1, 1, 0, 4><<<dim3(4096), tb, 0, stream>>>(
      pf0, pf1, pf2, pf3, b2, x1f, g3, be3, (float*)d_out, nullptr);
}

// Round 10
// 525.140 us; speedup vs baseline: 1.0695x; 1.0252x over previous
//
#include <hip/hip_runtime.h>
#include <cstdint>

typedef __bf16 bf16_t;
typedef bf16_t bf16x8 __attribute__((ext_vector_type(8)));
typedef bf16_t bf16x4 __attribute__((ext_vector_type(4)));
typedef float  f32x4  __attribute__((ext_vector_type(4)));

#define DEVI static __device__ __forceinline__

DEVI void async_ld16(const bf16_t* g, bf16_t* l) {
  __builtin_amdgcn_global_load_lds((const __attribute__((address_space(1))) void*)g,
                                   (__attribute__((address_space(3))) void*)l, 16, 0, 0);
}

// ---------------------------------------------------------------------------
// Fused prep: all weight transposes + bf16 converts + bias packs, one dispatch.
// Transpose path vectorized (round-7): float4 loads + bf16x4 stores.
// ---------------------------------------------------------------------------
struct PrepArgs {
  const float *WqS, *WkS, *WvS, *WqX, *WkX, *WvX, *Wo, *W1, *W2, *x, *enc;
  const float *bqS, *bkS, *bvS, *bkX, *bvX;
  bf16_t *WqkvST, *WqXT, *WkvXT, *WoT, *W1T, *W2T, *xb, *encb;
  float *bqkv, *bkvx;
};

__global__ __launch_bounds__(256)
void k_prep(PrepArgs a)
{
  __shared__ float tile[32][36];
  const int blk = blockIdx.x, tid = threadIdx.x;

  const float* src = nullptr;
  bf16_t* dst = nullptr;
  int srcLd = 0, dstLd = 0, m0 = 0, n0 = 0;
  bool do_tr = false;

  if (blk < 6144) {
    int j = blk >> 10, q = blk & 1023;
    src = j == 0 ? a.WqS : j == 1 ? a.WkS : j == 2 ? a.WvS : j == 3 ? a.WqX : j == 4 ? a.WkX : a.WvX;
    dst = j == 0 ? a.WqkvST : j == 1 ? a.WqkvST + 1048576 : j == 2 ? a.WqkvST + 2097152
        : j == 3 ? a.WqXT : j == 4 ? a.WkvXT : a.WkvXT + 1048576;
    int batch = q >> 6, rem = q & 63;
    src += (long)batch * 65536; dst += (long)batch * 65536;
    srcLd = 64; dstLd = 1024;
    n0 = (rem & 1) * 32; m0 = (rem >> 1) * 32;
    do_tr = true;
  } else if (blk < 7168) {
    int q = blk - 6144;
    src = a.Wo; dst = a.WoT; srcLd = 1024; dstLd = 1024;
    m0 = (q >> 5) * 32; n0 = (q & 31) * 32; do_tr = true;
  } else if (blk < 11264) {
    int q = blk - 7168;
    src = a.W1; dst = a.W1T; srcLd = 4096; dstLd = 1024;
    m0 = (q >> 7) * 32; n0 = (q & 127) * 32; do_tr = true;
  } else if (blk < 15360) {
    int q = blk - 11264;
    src = a.W2; dst = a.W2T; srcLd = 1024; dstLd = 4096;
    m0 = (q >> 5) * 32; n0 = (q & 31) * 32; do_tr = true;
  } else if (blk < 16384) {
    long base = (long)(blk - 15360) * 4096 + tid * 4;
#pragma unroll
    for (int u = 0; u < 4; u++) {
      float4 v = *(const float4*)(a.x + base + u * 1024);
      bf16x4 o; o[0] = (bf16_t)v.x; o[1] = (bf16_t)v.y; o[2] = (bf16_t)v.z; o[3] = (bf16_t)v.w;
      *(bf16x4*)(a.xb + base + u * 1024) = o;
    }
    return;
  } else if (blk < 17408) {
    long base = (long)(blk - 16384) * 4096 + tid * 4;
#pragma unroll
    for (int u = 0; u < 4; u++) {
      float4 v = *(const float4*)(a.enc + base + u * 1024);
      bf16x4 o; o[0] = (bf16_t)v.x; o[1] = (bf16_t)v.y; o[2] = (bf16_t)v.z; o[3] = (bf16_t)v.w;
      *(bf16x4*)(a.encb + base + u * 1024) = o;
    }
    return;
  } else {
    int gi = (blk - 17408) * 1024 + tid * 4;
#pragma unroll
    for (int j = 0; j < 4; j++) {
      int i = gi + j;
      if (i < 1024)      a.bqkv[i] = a.bqS[i];
      else if (i < 2048) a.bqkv[i] = a.bkS[i - 1024];
      else if (i < 3072) a.bqkv[i] = a.bvS[i - 2048];
      else if (i < 4096) a.bkvx[i - 3072] = a.bkX[i - 3072];
      else if (i < 5120) a.bkvx[i - 3072] = a.bvX[i - 4096];
    }
    return;
  }

  if (do_tr) {
    {
      int r = tid >> 3, c4 = (tid & 7) * 4;
      *(float4*)&tile[r][c4] = *(const float4*)(src + (long)(m0 + r) * srcLd + n0 + c4);
    }
    __syncthreads();
    {
      int nr = tid >> 3, mq = (tid & 7) * 4;
      bf16x4 o;
      o[0] = (bf16_t)tile[mq + 0][nr];
      o[1] = (bf16_t)tile[mq + 1][nr];
      o[2] = (bf16_t)tile[mq + 2][nr];
      o[3] = (bf16_t)tile[mq + 3][nr];
      *(bf16x4*)(dst + (long)(n0 + nr) * dstLd + m0 + mq) = o;
    }
  }
}

// ---------------------------------------------------------------------------
// GEMM 128x128 tile, BK=32, 2-phase double-buffered global_load_lds.
// (Known-good core — frozen. Used for Wo split-K2 only now.)
// ---------------------------------------------------------------------------
template<int OUT_MODE, int RELU, int VOFF>
__global__ __launch_bounds__(256, 2)
void k_gemm(const bf16_t* __restrict__ A, int lda,
            const bf16_t* __restrict__ Bt, int ldb,
            const float* __restrict__ bias,
            bf16_t* __restrict__ C, int ldc,
            bf16_t* __restrict__ Vt,
            bf16_t* __restrict__ p0, bf16_t* __restrict__ p1,
            bf16_t* __restrict__ p2, bf16_t* __restrict__ p3,
            int Ktot, int nx)
{
  __shared__ bf16_t As[2][128 * 32];
  __shared__ bf16_t Bs[2][128 * 32];
  const int tid  = threadIdx.x;
  const int wave = tid >> 6, lane = tid & 63;
  const int quad = lane >> 4, m16 = lane & 15;

  int lin = blockIdx.x;
  int perx = gridDim.x >> 3;
  int t = (lin & 7) * perx + (lin >> 3);
  const int bcol = (t % nx) * 128, brow = (t / nx) * 128;
  const int wr = (wave >> 1) * 64, wc = (wave & 1) * 64;

  const int Kper = Ktot / gridDim.z;
  const int k0 = blockIdx.z * Kper;

  f32x4 acc[4][4];
#pragma unroll
  for (int i = 0; i < 4; i++)
#pragma unroll
    for (int j = 0; j < 4; j++) acc[i][j] = (f32x4){0.f, 0.f, 0.f, 0.f};

  auto stage = [&](int kt, int buf) {
#pragma unroll
    for (int i = 0; i < 2; i++) {
      int rg = wave * 2 + i;
      async_ld16(A  + (long)(brow + rg * 16 + m16) * lda + kt + quad * 8, As[buf] + rg * 512);
      async_ld16(Bt + (long)(bcol + rg * 16 + m16) * ldb + kt + quad * 8, Bs[buf] + rg * 512);
    }
  };

  stage(k0, 0);
  __syncthreads();

  const int nIter = Kper >> 5;
  for (int it = 0; it < nIter; it++) {
    const int cur = it & 1;
    if (it + 1 < nIter) stage(k0 + (it + 1) * 32, cur ^ 1);

    bf16x8 af[4], bfr[4];
#pragma unroll
    for (int tt = 0; tt < 4; tt++) {
      af[tt]  = *(const bf16x8*)(As[cur] + ((wr + tt * 16) >> 4) * 512 + quad * 128 + m16 * 8);
      bfr[tt] = *(const bf16x8*)(Bs[cur] + ((wc + tt * 16) >> 4) * 512 + quad * 128 + m16 * 8);
    }
#pragma unroll
    for (int i = 0; i < 4; i++)
#pragma unroll
      for (int j = 0; j < 4; j++)
        acc[i][j] = __builtin_amdgcn_mfma_f32_16x16x32_bf16(af[i], bfr[j], acc[i][j], 0, 0, 0);

    __syncthreads();
  }

  if (OUT_MODE == 1) {
    bf16_t* P = blockIdx.z == 0 ? p0 : blockIdx.z == 1 ? p1 : blockIdx.z == 2 ? p2 : p3;
#pragma unroll
    for (int i = 0; i < 4; i++)
#pragma unroll
      for (int j = 0; j < 4; j++) {
        int col = bcol + wc + j * 16 + m16;
#pragma unroll
        for (int r = 0; r < 4; r++) {
          int row = brow + wr + i * 16 + quad * 4 + r;
          P[(long)row * ldc + col] = (bf16_t)acc[i][j][r];
        }
      }
  } else {
#pragma unroll
    for (int i = 0; i < 4; i++)
#pragma unroll
      for (int j = 0; j < 4; j++) {
        int col = bcol + wc + j * 16 + m16;
        float bv = bias[col];
        if (VOFF && col >= VOFF) {
          int hh = (col - VOFF) >> 6, dd = col & 63;
          int row0 = brow + wr + i * 16 + quad * 4;
          int bb = row0 >> 10, seq = row0 & 1023;
          bf16x4 pk;
#pragma unroll
          for (int r = 0; r < 4; r++) pk[r] = (bf16_t)(acc[i][j][r] + bv);
          *(bf16x4*)(Vt + (long)(bb * 16 + hh) * 65536 + dd * 1024 + seq) = pk;
        } else {
#pragma unroll
          for (int r = 0; r < 4; r++) {
            int row = brow + wr + i * 16 + quad * 4 + r;
            float v = acc[i][j][r] + bv;
            if (RELU) v = v > 0.f ? v : 0.f;
            C[(long)row * ldc + col] = (bf16_t)v;
          }
        }
      }
  }
}

// ---------------------------------------------------------------------------
// DUAL-ROLE 128x128 GEMM (round-9, kept): phase-2 head in one dispatch.
// Role A: Qx direct (bias fused). Role B: Kenc/Vt (VOFF=1024).
// ---------------------------------------------------------------------------
__global__ __launch_bounds__(256, 2)
void k_gemm_dual(const bf16_t* __restrict__ Aa, const bf16_t* __restrict__ Bta,
                 const float* __restrict__ biasa, bf16_t* __restrict__ Ca,
                 int nxa, int nblkA,
                 const bf16_t* __restrict__ Ab, const bf16_t* __restrict__ Btb,
                 const float* __restrict__ biasb, bf16_t* __restrict__ Cb,
                 int nxb,
                 bf16_t* __restrict__ Vt)
{
  __shared__ bf16_t As[2][128 * 32];
  __shared__ bf16_t Bs[2][128 * 32];
  const int tid  = threadIdx.x;
  const int wave = tid >> 6, lane = tid & 63;
  const int quad = lane >> 4, m16 = lane & 15;

  const bool roleB = (int)blockIdx.x >= nblkA;
  const bf16_t* A    = roleB ? Ab    : Aa;
  const bf16_t* Bt   = roleB ? Btb   : Bta;
  const float*  bias = roleB ? biasb : biasa;
  bf16_t*       C    = roleB ? Cb    : Ca;
  const int nx   = roleB ? nxb : nxa;
  const int lin  = roleB ? ((int)blockIdx.x - nblkA) : (int)blockIdx.x;
  const int nblk = roleB ? ((int)gridDim.x - nblkA) : nblkA;
  const int perx = nblk >> 3;
  const int t = (lin & 7) * perx + (lin >> 3);
  const int bcol = (t % nx) * 128, brow = (t / nx) * 128;
  const int wr = (wave >> 1) * 64, wc = (wave & 1) * 64;
  const int lda = 1024, ldb = 1024, ldc = 1024;

  f32x4 acc[4][4];
#pragma unroll
  for (int i = 0; i < 4; i++)
#pragma unroll
    for (int j = 0; j < 4; j++) acc[i][j] = (f32x4){0.f, 0.f, 0.f, 0.f};

  auto stage = [&](int kt, int buf) {
#pragma unroll
    for (int i = 0; i < 2; i++) {
      int rg = wave * 2 + i;
      async_ld16(A  + (long)(brow + rg * 16 + m16) * lda + kt + quad * 8, As[buf] + rg * 512);
      async_ld16(Bt + (long)(bcol + rg * 16 + m16) * ldb + kt + quad * 8, Bs[buf] + rg * 512);
    }
  };

  stage(0, 0);
  __syncthreads();

  const int nIter = 32;                       // K = 1024, BK = 32
  for (int it = 0; it < nIter; it++) {
    const int cur = it & 1;
    if (it + 1 < nIter) stage((it + 1) * 32, cur ^ 1);

    bf16x8 af[4], bfr[4];
#pragma unroll
    for (int tt = 0; tt < 4; tt++) {
      af[tt]  = *(const bf16x8*)(As[cur] + ((wr + tt * 16) >> 4) * 512 + quad * 128 + m16 * 8);
      bfr[tt] = *(const bf16x8*)(Bs[cur] + ((wc + tt * 16) >> 4) * 512 + quad * 128 + m16 * 8);
    }
#pragma unroll
    for (int i = 0; i < 4; i++)
#pragma unroll
      for (int j = 0; j < 4; j++)
        acc[i][j] = __builtin_amdgcn_mfma_f32_16x16x32_bf16(af[i], bfr[j], acc[i][j], 0, 0, 0);

    __syncthreads();
  }

#pragma unroll
  for (int i = 0; i < 4; i++)
#pragma unroll
    for (int j = 0; j < 4; j++) {
      int col = bcol + wc + j * 16 + m16;
      float bv = bias[col];
      if (col >= 1024) {                      // only reachable in role B
        int hh = (col - 1024) >> 6, dd = col & 63;
        int row0 = brow + wr + i * 16 + quad * 4;
        int bb = row0 >> 10, seq = row0 & 1023;
        bf16x4 pk;
#pragma unroll
        for (int r = 0; r < 4; r++) pk[r] = (bf16_t)(acc[i][j][r] + bv);
        *(bf16x4*)(Vt + (long)(bb * 16 + hh) * 65536 + dd * 1024 + seq) = pk;
      } else {
#pragma unroll
        for (int r = 0; r < 4; r++) {
          int row = brow + wr + i * 16 + quad * 4 + r;
          C[(long)row * ldc + col] = (bf16_t)(acc[i][j][r] + bv);
        }
      }
    }
}

// ---------------------------------------------------------------------------
// GEMM 256x256 tile, BK=64, 2-phase double-buffer — FFN1 + FFN2 (frozen at
// ~93% of the 2-phase structural ceiling; 8-phase not reconstructible
// race-free headlessly, m152).
// ---------------------------------------------------------------------------
template<int OUT_MODE, int RELU, int VOFF>
__global__ __launch_bounds__(512, 2)
void k_gemm256(const bf16_t* __restrict__ A, int lda,
               const bf16_t* __restrict__ Bt, int ldb,
               const float* __restrict__ bias,
               bf16_t* __restrict__ C, int ldc,
               bf16_t* __restrict__ Vt,
               bf16_t* __restrict__ p0, bf16_t* __restrict__ p1,
               bf16_t* __restrict__ p2, bf16_t* __restrict__ p3,
               int Ktot, int nx)
{
  __shared__ bf16_t As[2][256 * 64];
  __shared__ bf16_t Bs[2][256 * 64];
  const int tid  = threadIdx.x;
  const int wave = tid >> 6, lane = tid & 63;
  const int quad = lane >> 4, m16 = lane & 15;

  int lin = blockIdx.x;
  int perx = gridDim.x >> 3;
  int t = (lin & 7) * perx + (lin >> 3);
  const int bcol = (t % nx) * 256, brow = (t / nx) * 256;
  const int wr = (wave >> 2) * 128, wc = (wave & 3) * 64;

  const int Kper = Ktot / gridDim.z;
  const int k0 = blockIdx.z * Kper;

  f32x4 acc[8][4];
#pragma unroll
  for (int i = 0; i < 8; i++)
#pragma unroll
    for (int j = 0; j < 4; j++) acc[i][j] = (f32x4){0.f, 0.f, 0.f, 0.f};

  auto stage = [&](int kt, int buf) {
#pragma unroll
    for (int i = 0; i < 2; i++) {
      int rg = wave * 2 + i;
#pragma unroll
      for (int ks = 0; ks < 2; ks++) {
        async_ld16(A  + (long)(brow + rg * 16 + m16) * lda + kt + ks * 32 + quad * 8,
                   As[buf] + (rg * 2 + ks) * 512);
        async_ld16(Bt + (long)(bcol + rg * 16 + m16) * ldb + kt + ks * 32 + quad * 8,
                   Bs[buf] + (rg * 2 + ks) * 512);
      }
    }
  };

  stage(k0, 0);
  __syncthreads();

  const int nIter = Kper >> 6;
  for (int it = 0; it < nIter; it++) {
    const int cur = it & 1;
    if (it + 1 < nIter) stage(k0 + (it + 1) * 64, cur ^ 1);

    const bf16_t* Ac = As[cur];
    const bf16_t* Bc = Bs[cur];
#pragma unroll
    for (int ks = 0; ks < 2; ks++) {
      bf16x8 af[8], bfr[4];
#pragma unroll
      for (int tt = 0; tt < 8; tt++)
        af[tt] = *(const bf16x8*)(Ac + (((wr + tt * 16) >> 4) * 2 + ks) * 512 + quad * 128 + m16 * 8);
#pragma unroll
      for (int j = 0; j < 4; j++)
        bfr[j] = *(const bf16x8*)(Bc + (((wc + j * 16) >> 4) * 2 + ks) * 512 + quad * 128 + m16 * 8);
      __builtin_amdgcn_s_setprio(1);
#pragma unroll
      for (int i = 0; i < 8; i++)
#pragma unroll
        for (int j = 0; j < 4; j++)
          acc[i][j] = __builtin_amdgcn_mfma_f32_16x16x32_bf16(af[i], bfr[j], acc[i][j], 0, 0, 0);
      __builtin_amdgcn_s_setprio(0);
    }

    __syncthreads();
  }

  if (OUT_MODE == 1) {
    bf16_t* P = blockIdx.z == 0 ? p0 : blockIdx.z == 1 ? p1 : blockIdx.z == 2 ? p2 : p3;
#pragma unroll
    for (int i = 0; i < 8; i++)
#pragma unroll
      for (int j = 0; j < 4; j++) {
        int col = bcol + wc + j * 16 + m16;
#pragma unroll
        for (int r = 0; r < 4; r++) {
          int row = brow + wr + i * 16 + quad * 4 + r;
          P[(long)row * ldc + col] = (bf16_t)acc[i][j][r];
        }
      }
  } else {
#pragma unroll
    for (int i = 0; i < 8; i++)
#pragma unroll
      for (int j = 0; j < 4; j++) {
        int col = bcol + wc + j * 16 + m16;
        float bv = bias[col];
        if (VOFF && col >= VOFF) {
          int hh = (col - VOFF) >> 6, dd = col & 63;
          int row0 = brow + wr + i * 16 + quad * 4;
          int bb = row0 >> 10, seq = row0 & 1023;
          bf16x4 pk;
#pragma unroll
          for (int r = 0; r < 4; r++) pk[r] = (bf16_t)(acc[i][j][r] + bv);
          *(bf16x4*)(Vt + (long)(bb * 16 + hh) * 65536 + dd * 1024 + seq) = pk;
        } else {
#pragma unroll
          for (int r = 0; r < 4; r++) {
            int row = brow + wr + i * 16 + quad * 4 + r;
            float v = acc[i][j][r] + bv;
            if (RELU) v = v > 0.f ? v : 0.f;
            C[(long)row * ldc + col] = (bf16_t)v;
          }
        }
      }
  }
}

// ---------------------------------------------------------------------------
// GEMM 256x192 tile, BK=64 (round-10): QKV-shaped variant of k_gemm256.
// QKV output is 4096x3072: 256^2 gives 192 blocks = 75% CU utilization
// (round-9 counters: 439 TF vs FFN1's 603 at the same per-block engine).
// 256x192 -> grid 16x16 = 256 blocks = exactly 1/CU. Wave-tile 128x48
// (acc 8x3, 48 MFMA/wave/iter). LDS 64+48=112KB -> 1 blk/CU. Staging:
// 32 A-subtiles + 24 B-subtiles = 56 = exactly 7 loads/wave (uniform).
// Per-element col>=VOFF check handles the 2048 boundary mid-tile.
// ---------------------------------------------------------------------------
template<int VOFF>
__global__ __launch_bounds__(512, 2)
void k_gemm256x192(const bf16_t* __restrict__ A, int lda,
                   const bf16_t* __restrict__ Bt, int ldb,
                   const float* __restrict__ bias,
                   bf16_t* __restrict__ C, int ldc,
                   bf16_t* __restrict__ Vt,
                   int Ktot, int nx)
{
  __shared__ bf16_t As[2][256 * 64];
  __shared__ bf16_t Bs[2][192 * 64];
  const int tid  = threadIdx.x;
  const int wave = tid >> 6, lane = tid & 63;
  const int quad = lane >> 4, m16 = lane & 15;

  int lin = blockIdx.x;
  int perx = gridDim.x >> 3;
  int t = (lin & 7) * perx + (lin >> 3);
  const int bcol = (t % nx) * 192, brow = (t / nx) * 256;
  const int wr = (wave >> 2) * 128, wc = (wave & 3) * 48;

  f32x4 acc[8][3];
#pragma unroll
  for (int i = 0; i < 8; i++)
#pragma unroll
    for (int j = 0; j < 3; j++) acc[i][j] = (f32x4){0.f, 0.f, 0.f, 0.f};

  // 56 subtiles: ids [0,32) = A (rg=id>>1, ks=id&1), [32,56) = B. 7/wave.
  auto stage = [&](int kt, int buf) {
#pragma unroll
    for (int i = 0; i < 7; i++) {
      int id = wave * 7 + i;
      if (id < 32) {
        int rg = id >> 1, ks = id & 1;
        async_ld16(A + (long)(brow + rg * 16 + m16) * lda + kt + ks * 32 + quad * 8,
                   As[buf] + id * 512);
      } else {
        int bid = id - 32;
        int rg = bid >> 1, ks = bid & 1;
        async_ld16(Bt + (long)(bcol + rg * 16 + m16) * ldb + kt + ks * 32 + quad * 8,
                   Bs[buf] + bid * 512);
      }
    }
  };

  stage(0, 0);
  __syncthreads();

  const int nIter = Ktot >> 6;
  for (int it = 0; it < nIter; it++) {
    const int cur = it & 1;
    if (it + 1 < nIter) stage((it + 1) * 64, cur ^ 1);

    const bf16_t* Ac = As[cur];
    const bf16_t* Bc = Bs[cur];
#pragma unroll
    for (int ks = 0; ks < 2; ks++) {
      bf16x8 af[8], bfr[3];
#pragma unroll
      for (int tt = 0; tt < 8; tt++)
        af[tt] = *(const bf16x8*)(Ac + (((wr + tt * 16) >> 4) * 2 + ks) * 512 + quad * 128 + m16 * 8);
#pragma unroll
      for (int j = 0; j < 3; j++)
        bfr[j] = *(const bf16x8*)(Bc + (((wc + j * 16) >> 4) * 2 + ks) * 512 + quad * 128 + m16 * 8);
      __builtin_amdgcn_s_setprio(1);
#pragma unroll
      for (int i = 0; i < 8; i++)
#pragma unroll
        for (int j = 0; j < 3; j++)
          acc[i][j] = __builtin_amdgcn_mfma_f32_16x16x32_bf16(af[i], bfr[j], acc[i][j], 0, 0, 0);
      __builtin_amdgcn_s_setprio(0);
    }

    __syncthreads();
  }

#pragma unroll
  for (int i = 0; i < 8; i++)
#pragma unroll
    for (int j = 0; j < 3; j++) {
      int col = bcol + wc + j * 16 + m16;
      float bv = bias[col];
      if (VOFF && col >= VOFF) {
        int hh = (col - VOFF) >> 6, dd = col & 63;
        int row0 = brow + wr + i * 16 + quad * 4;
        int bb = row0 >> 10, seq = row0 & 1023;
        bf16x4 pk;
#pragma unroll
        for (int r = 0; r < 4; r++) pk[r] = (bf16_t)(acc[i][j][r] + bv);
        *(bf16x4*)(Vt + (long)(bb * 16 + hh) * 65536 + dd * 1024 + seq) = pk;
      } else {
#pragma unroll
        for (int r = 0; r < 4; r++) {
          int row = brow + wr + i * 16 + quad * 4 + r;
          C[(long)row * ldc + col] = (bf16_t)(acc[i][j][r] + bv);
        }
      }
    }
}

// ---------------------------------------------------------------------------
// Split-K reduce (NPART partials) + bias (+resid) (+LayerNorm). 1 row/block.
// ---------------------------------------------------------------------------
template<int LN, int RESID, int OUTF, int OUTB, int NPART>
__global__ __launch_bounds__(256)
void k_reduceN(const bf16_t* __restrict__ p0, const bf16_t* __restrict__ p1,
               const bf16_t* __restrict__ p2, const bf16_t* __restrict__ p3,
               const float* __restrict__ bias, const float* __restrict__ resid,
               const float* __restrict__ gamma, const float* __restrict__ beta,
               float* __restrict__ outf, bf16_t* __restrict__ outb)
{
  constexpr int D = 1024;
  __shared__ float red[8];
  int row = blockIdx.x, tid = threadIdx.x;
  long off = (long)row * D + tid * 4;
  bf16x4 a0 = *(const bf16x4*)(p0 + off);
  bf16x4 a1 = *(const bf16x4*)(p1 + off);
  float4 bb4 = *(const float4*)(bias + tid * 4);
  float4 v;
  v.x = (float)a0[0] + (float)a1[0] + bb4.x;
  v.y = (float)a0[1] + (float)a1[1] + bb4.y;
  v.z = (float)a0[2] + (float)a1[2] + bb4.z;
  v.w = (float)a0[3] + (float)a1[3] + bb4.w;
  if (NPART == 4) {
    bf16x4 a2 = *(const bf16x4*)(p2 + off);
    bf16x4 a3 = *(const bf16x4*)(p3 + off);
    v.x += (float)a2[0] + (float)a3[0];
    v.y += (float)a2[1] + (float)a3[1];
    v.z += (float)a2[2] + (float)a3[2];
    v.w += (float)a2[3] + (float)a3[3];
  }
  if (RESID) {
    float4 q = *(const float4*)(resid + off);
    v.x += q.x; v.y += q.y; v.z += q.z; v.w += q.w;
  }
  float4 y = v;
  if (LN) {
    float s  = v.x + v.y + v.z + v.w;
    float sq = v.x * v.x + v.y * v.y + v.z * v.z + v.w * v.w;
#pragma unroll
    for (int o = 1; o < 64; o <<= 1) {
      s  += __shfl_xor(s, o, 64);
      sq += __shfl_xor(sq, o, 64);
    }
    int wave = tid >> 6, lane = tid & 63;
    if (lane == 0) { red[wave * 2] = s; red[wave * 2 + 1] = sq; }
    __syncthreads();
    float ts = red[0] + red[2] + red[4] + red[6];
    float tq = red[1] + red[3] + red[5] + red[7];
    float mu = ts * (1.f / D);
    float var = tq * (1.f / D) - mu * mu;
    float rstd = rsqrtf(var + 1e-5f);
    float4 g  = *(const float4*)(gamma + tid * 4);
    float4 be = *(const float4*)(beta + tid * 4);
    y.x = (v.x - mu) * rstd * g.x + be.x;
    y.y = (v.y - mu) * rstd * g.y + be.y;
    y.z = (v.z - mu) * rstd * g.z + be.z;
    y.w = (v.w - mu) * rstd * g.w + be.w;
  }
  if (OUTF) *(float4*)(outf + off) = y;
  if (OUTB) {
    bf16x4 o;
    o[0] = (bf16_t)y.x; o[1] = (bf16_t)y.y; o[2] = (bf16_t)y.z; o[3] = (bf16_t)y.w;
    *(bf16x4*)(outb + off) = o;
  }
}

// ---------------------------------------------------------------------------
// Flash attention. Causal load-balance swizzle (round-8, kept). LDS
// double-buffered KV staging; setprio around MFMA.
// ---------------------------------------------------------------------------
template<int CAUSAL>
__global__ __launch_bounds__(256, 2)
void k_attn(const bf16_t* __restrict__ Q, int ldq,
            const bf16_t* __restrict__ Kp, int ldk,
            const bf16_t* __restrict__ Vt,
            bf16_t* __restrict__ O)
{
  constexpr int S = 1024;
  __shared__ bf16_t Kls[2][4096];
  __shared__ bf16_t Vls[2][4096];
  __shared__ bf16_t Pls[4][32 * 72];

  const int tid = threadIdx.x;
  const int wave = tid >> 6, lane = tid & 63;
  const int quad = lane >> 4, m16 = lane & 15;
  const int bh = blockIdx.y, b = bh >> 4, h = bh & 15;
  const int qt = (CAUSAL && (bh & 32)) ? ((int)gridDim.x - 1 - (int)blockIdx.x)
                                       : (int)blockIdx.x;
  const int qbase = qt * 128 + wave * 32;

  bf16x8 qf[2][2];
#pragma unroll
  for (int rh = 0; rh < 2; rh++) {
    const bf16_t* qp = Q + (long)(b * S + qbase + rh * 16 + m16) * ldq + h * 64 + quad * 8;
    qf[rh][0] = *(const bf16x8*)qp;
    qf[rh][1] = *(const bf16x8*)(qp + 32);
  }

  f32x4 o_acc[2][4];
#pragma unroll
  for (int rh = 0; rh < 2; rh++)
#pragma unroll
    for (int t = 0; t < 4; t++) o_acc[rh][t] = (f32x4){0.f, 0.f, 0.f, 0.f};
  float rsum[2][4];
#pragma unroll
  for (int rh = 0; rh < 2; rh++)
#pragma unroll
    for (int r = 0; r < 4; r++) rsum[rh][r] = 0.f;

  auto stage = [&](int c, int buf) {
#pragma unroll
    for (int i = 0; i < 2; i++) {
      int t2 = wave * 2 + i;
      int rg = t2 & 3, ph = t2 >> 2;
      async_ld16(Kp + (long)(b * S + c * 64 + rg * 16 + m16) * ldk + h * 64 + ph * 32 + quad * 8,
                 Kls[buf] + t2 * 512);
      async_ld16(Vt + (long)bh * 65536 + (rg * 16 + m16) * 1024 + c * 64 + ph * 32 + quad * 8,
                 Vls[buf] + t2 * 512);
    }
  };

  const int nch = CAUSAL ? (2 * qt + 2) : 16;
  stage(0, 0);

  for (int c = 0; c < nch; c++) {
    __syncthreads();
    const int cur = c & 1;
    if (c + 1 < nch) stage(c + 1, cur ^ 1);

    f32x4 s[2][4];
#pragma unroll
    for (int t = 0; t < 4; t++) {
      bf16x8 k0 = *(const bf16x8*)(Kls[cur] + (0 * 4 + t) * 512 + quad * 128 + m16 * 8);
      bf16x8 k1 = *(const bf16x8*)(Kls[cur] + (1 * 4 + t) * 512 + quad * 128 + m16 * 8);
      __builtin_amdgcn_s_setprio(1);
#pragma unroll
      for (int rh = 0; rh < 2; rh++) {
        f32x4 z = (f32x4){0.f, 0.f, 0.f, 0.f};
        z = __builtin_amdgcn_mfma_f32_16x16x32_bf16(qf[rh][0], k0, z, 0, 0, 0);
        z = __builtin_amdgcn_mfma_f32_16x16x32_bf16(qf[rh][1], k1, z, 0, 0, 0);
        s[rh][t] = z;
      }
      __builtin_amdgcn_s_setprio(0);
    }

    bf16_t* pw = Pls[wave];
#pragma unroll
    for (int rh = 0; rh < 2; rh++)
#pragma unroll
      for (int r = 0; r < 4; r++) {
        int qg = qbase + rh * 16 + quad * 4 + r;
#pragma unroll
        for (int t = 0; t < 4; t++) {
          float v = s[rh][t][r] * 0.125f;
          float p;
          if (CAUSAL) {
            int kvg = c * 64 + t * 16 + m16;
            p = (kvg <= qg) ? __expf(v) : 0.f;
          } else {
            p = __expf(v);
          }
          rsum[rh][r] += p;
          pw[(rh * 16 + quad * 4 + r) * 72 + t * 16 + m16] = (bf16_t)p;
        }
      }

    bf16x8 pf[2][2];
#pragma unroll
    for (int rh = 0; rh < 2; rh++)
#pragma unroll
      for (int kvh = 0; kvh < 2; kvh++)
        pf[rh][kvh] = *(const bf16x8*)(pw + (rh * 16 + m16) * 72 + kvh * 32 + quad * 8);
#pragma unroll
    for (int t = 0; t < 4; t++) {
      bf16x8 v0 = *(const bf16x8*)(Vls[cur] + (0 * 4 + t) * 512 + quad * 128 + m16 * 8);
      bf16x8 v1 = *(const bf16x8*)(Vls[cur] + (1 * 4 + t) * 512 + quad * 128 + m16 * 8);
      __builtin_amdgcn_s_setprio(1);
#pragma unroll
      for (int rh = 0; rh < 2; rh++) {
        o_acc[rh][t] = __builtin_amdgcn_mfma_f32_16x16x32_bf16(pf[rh][0], v0, o_acc[rh][t], 0, 0, 0);
        o_acc[rh][t] = __builtin_amdgcn_mfma_f32_16x16x32_bf16(pf[rh][1], v1, o_acc[rh][t], 0, 0, 0);
      }
      __builtin_amdgcn_s_setprio(0);
    }
  }

#pragma unroll
  for (int rh = 0; rh < 2; rh++)
#pragma unroll
    for (int r = 0; r < 4; r++) {
      float v = rsum[rh][r];
      v += __shfl_xor(v, 1, 64);
      v += __shfl_xor(v, 2, 64);
      v += __shfl_xor(v, 4, 64);
      v += __shfl_xor(v, 8, 64);
      rsum[rh][r] = 1.f / v;
    }
#pragma unroll
  for (int rh = 0; rh < 2; rh++)
#pragma unroll
    for (int t = 0; t < 4; t++)
#pragma unroll
      for (int r = 0; r < 4; r++) {
        int row = b * S + qbase + rh * 16 + quad * 4 + r;
        int col = h * 64 + t * 16 + m16;
        O[(long)row * 1024 + col] = (bf16_t)(o_acc[rh][t][r] * rsum[rh][r]);
      }
}

// ---------------------------------------------------------------------------
extern "C" void kernel_launch(void* const* d_in, const int* in_sizes, int n_in,
                              void* d_out, int out_size, void* d_ws, size_t ws_size,
                              hipStream_t stream)
{
  const float* x   = (const float*)d_in[0];
  const float* enc = (const float*)d_in[1];
  const float* WqS = (const float*)d_in[3];
  const float* bqS = (const float*)d_in[4];
  const float* WkS = (const float*)d_in[5];
  const float* bkS = (const float*)d_in[6];
  const float* WvS = (const float*)d_in[7];
  const float* bvS = (const float*)d_in[8];
  const float* WqX = (const float*)d_in[9];
  const float* bqX = (const float*)d_in[10];
  const float* WkX = (const float*)d_in[11];
  const float* bkX = (const float*)d_in[12];
  const float* WvX = (const float*)d_in[13];
  const float* bvX = (const float*)d_in[14];
  const float* Wo  = (const float*)d_in[15];
  const float* bo  = (const float*)d_in[16];
  const float* W1  = (const float*)d_in[17];
  const float* b1  = (const float*)d_in[18];
  const float* W2  = (const float*)d_in[19];
  const float* b2  = (const float*)d_in[20];
  const float* g1  = (const float*)d_in[21];
  const float* be1 = (const float*)d_in[22];
  const float* g2  = (const float*)d_in[23];
  const float* be2 = (const float*)d_in[24];
  const float* g3  = (const float*)d_in[25];
  const float* be3 = (const float*)d_in[26];

  char* ws = (char*)d_ws;
  const long MBy = 1048576;
  bf16_t* WqkvST = (bf16_t*)(ws + 0 * MBy);            // 6 MB
  bf16_t* WqXT   = (bf16_t*)(ws + 6 * MBy);            // 2 MB
  bf16_t* WkvXT  = (bf16_t*)(ws + 8 * MBy);            // 4 MB
  bf16_t* WoT    = (bf16_t*)(ws + 12 * MBy);           // 2 MB
  bf16_t* W1T    = (bf16_t*)(ws + 14 * MBy);           // 8 MB
  bf16_t* W2T    = (bf16_t*)(ws + 22 * MBy);           // 8 MB
  float*  bqkvS  = (float*)(ws + 30 * MBy);            // 12 KB
  float*  bkvX   = (float*)(ws + 30 * MBy + 16384);    // 8 KB
  bf16_t* xb     = (bf16_t*)(ws + 31 * MBy);           // 8 MB (P1) -> Qx (P2)
  bf16_t* Qx     = xb;
  bf16_t* encb   = (bf16_t*)(ws + 39 * MBy);           // 8 MB (until KVenc)
  float*  x1f    = (float*)(ws + 47 * MBy);            // 16 MB f32 (resid chain)
  bf16_t* x1b    = (bf16_t*)(ws + 63 * MBy);           // 8 MB (->x2b)
  bf16_t* Z      = (bf16_t*)(ws + 71 * MBy);           // 8 MB attn out
  bf16_t* QK     = (bf16_t*)(ws + 79 * MBy);           // 16 MB [4096][2048] (P1)
  bf16_t* Kenc   = (bf16_t*)(ws + 79 * MBy);           // 8 MB [4096][1024] (P2)
  bf16_t* Vt     = (bf16_t*)(ws + 95 * MBy);           // 8 MB [64][64][1024]
  // split-K partial arena: overlays Vt region when dead (z=2 -> only pa0/pa1)
  bf16_t* pa0 = (bf16_t*)(ws + 95 * MBy);
  bf16_t* pa1 = (bf16_t*)(ws + 103 * MBy);
  bf16_t* Hbuf = (bf16_t*)(ws + 95 * MBy);             // 32 MB (P3)
  // FFN2 partials over dead weight/input regions
  bf16_t* pf0 = (bf16_t*)(ws + 0 * MBy);
  bf16_t* pf1 = (bf16_t*)(ws + 8 * MBy);
  bf16_t* pf2 = (bf16_t*)(ws + 31 * MBy);
  bf16_t* pf3 = (bf16_t*)(ws + 39 * MBy);

  dim3 tb(256), tb512(512);

  // ---- fused prep (1 dispatch) ----
  PrepArgs pa;
  pa.WqS = WqS; pa.WkS = WkS; pa.WvS = WvS; pa.WqX = WqX; pa.WkX = WkX; pa.WvX = WvX;
  pa.Wo = Wo; pa.W1 = W1; pa.W2 = W2; pa.x = x; pa.enc = enc;
  pa.bqS = bqS; pa.bkS = bkS; pa.bvS = bvS; pa.bkX = bkX; pa.bvX = bvX;
  pa.WqkvST = WqkvST; pa.WqXT = WqXT; pa.WkvXT = WkvXT; pa.WoT = WoT;
  pa.W1T = W1T; pa.W2T = W2T; pa.xb = xb; pa.encb = encb;
  pa.bqkv = bqkvS; pa.bkvx = bkvX;
  k_prep<<<dim3(17413), tb, 0, stream>>>(pa);

  // ---- phase 1: self-attention ----
  k_gemm256x192<2048><<<dim3(256, 1, 1), tb512, 0, stream>>>(
      xb, 1024, WqkvST, 1024, bqkvS, QK, 2048, Vt, 1024, 16);
  k_attn<1><<<dim3(8, 64), tb, 0, stream>>>(QK, 2048, QK + 1024, 2048, Vt, Z);
  k_gemm<1, 0, 0><<<dim3(256, 1, 2), tb, 0, stream>>>(
      Z, 1024, WoT, 1024, nullptr, nullptr, 1024, nullptr,
      pa0, pa1, nullptr, nullptr, 1024, 8);
  k_reduceN<1, 1, 1, 1, 2><<<dim3(4096), tb, 0, stream>>>(
      pa0, pa1, nullptr, nullptr, bo, x, g1, be1, x1f, x1b);

  // ---- phase 2: cross-attention ----
  // one dual-role dispatch: Qx (direct, bias fused) + Kenc/Vt
  k_gemm_dual<<<dim3(768), tb, 0, stream>>>(
      x1b, WqXT, bqX, Qx, 8, 256,
      encb, WkvXT, bkvX, Kenc, 16, Vt);
  k_attn<0><<<dim3(8, 64), tb, 0, stream>>>(Qx, 1024, Kenc, 1024, Vt, Z);
  k_gemm<1, 0, 0><<<dim3(256, 1, 2), tb, 0, stream>>>(
      Z, 1024, WoT, 1024, nullptr, nullptr, 1024, nullptr,
      pa0, pa1, nullptr, nullptr, 1024, 8);
  k_reduceN<1, 1, 1, 1, 2><<<dim3(4096), tb, 0, stream>>>(
      pa0, pa1, nullptr, nullptr, bo, x1f, g2, be2, x1f, x1b);

  // ---- phase 3: FFN ----
  k_gemm256<0, 1, 0><<<dim3(256, 1, 1), tb512, 0, stream>>>(
      x1b, 1024, W1T, 1024, b1, Hbuf, 4096, nullptr,
      nullptr, nullptr, nullptr, nullptr, 1024, 16);
  k_gemm256<1, 0, 0><<<dim3(64, 1, 4), tb512, 0, stream>>>(
      Hbuf, 4096, W2T, 4096, nullptr, nullptr, 1024, nullptr,
      pf0, pf1, pf2, pf3, 4096, 4);
  k_reduceN<1, 1, 1, 0, 4><<<dim3(4096), tb, 0, stream>>>(
      pf0, pf1, pf2, pf3, b2, x1f, g3, be3, (float*)d_out, nullptr);
}